// Round 1
// baseline (1446.351 us; speedup 1.0000x reference)
//
#include <hip/hip_runtime.h>
#include <math.h>

#define BB   128
#define NPTS 256
#define NP1  257
#define DD   512
#define HH   512
#define G4   2048
#define TP1  9
#define NEGF -1e18f

__device__ __forceinline__ float sigm(float x) { return 1.0f / (1.0f + expf(-x)); }

// ---------------------------------------------------------------- stop @ wm
__global__ void k_stopm(const float* __restrict__ stop,
                        const float* __restrict__ wmh,
                        const float* __restrict__ wma,
                        float* __restrict__ smh,
                        float* __restrict__ sma)
{
    int g = blockIdx.x * 256 + threadIdx.x;       // 0..1023
    const float* wm = (g < HH) ? wmh : wma;
    float* out      = (g < HH) ? smh : sma;
    int h = g & (HH - 1);
    float acc = 0.f;
    for (int k = 0; k < DD; ++k) acc += stop[k] * wm[k * HH + h];
    out[h] = acc;
}

// ------------------------------------------------- feat = mem @ wm  (fused)
// C[b*257+n, h] = (n<256 ? attn_mem[b,n,:]@wm[:,h] : 0) + (n==msz[b])*stopm[h]
// M = 128*257 = 32896 (divisible by 128), N = 512, K = 512
__global__ __launch_bounds__(256)
void k_feat(const float* __restrict__ Amem,
            const float* __restrict__ Wm,
            const float* __restrict__ stopm,
            const int* __restrict__ msz,
            float* __restrict__ Cout)
{
    __shared__ float As[16][132];
    __shared__ float Bs[16][132];
    const int tid = threadIdx.x;
    const int m0 = blockIdx.x * 128;
    const int n0 = blockIdx.y * 128;
    const int lak = tid & 15, lar = tid >> 4;     // A loader: k, row-base
    const int lbc = tid & 127, lbr = tid >> 7;    // B loader: col, k-base

    // hoist row mapping out of the K loop
    const float* arow[8];
#pragma unroll
    for (int s = 0; s < 8; ++s) {
        int m = m0 + lar + 16 * s;
        int b = m / NP1;
        int n = m - b * NP1;
        arow[s] = (n < NPTS) ? (Amem + ((size_t)((b << 8) + n)) * DD) : nullptr;
    }

    float acc[8][8];
#pragma unroll
    for (int i = 0; i < 8; ++i)
#pragma unroll
        for (int j = 0; j < 8; ++j) acc[i][j] = 0.f;

    for (int kt = 0; kt < DD; kt += 16) {
#pragma unroll
        for (int s = 0; s < 8; ++s)
            As[lak][lar + 16 * s] = arow[s] ? arow[s][kt + lak] : 0.f;
#pragma unroll
        for (int s = 0; s < 8; ++s)
            Bs[lbr + 2 * s][lbc] = Wm[(size_t)(kt + lbr + 2 * s) * HH + n0 + lbc];
        __syncthreads();
        const int ty = tid >> 4, tx = tid & 15;
#pragma unroll
        for (int k = 0; k < 16; ++k) {
            float a[8], bv[8];
#pragma unroll
            for (int i = 0; i < 8; ++i) a[i] = As[k][ty * 8 + i];
#pragma unroll
            for (int j = 0; j < 8; ++j) bv[j] = Bs[k][tx * 8 + j];
#pragma unroll
            for (int i = 0; i < 8; ++i)
#pragma unroll
                for (int j = 0; j < 8; ++j) acc[i][j] += a[i] * bv[j];
        }
        __syncthreads();
    }
    const int ty = tid >> 4, tx = tid & 15;
#pragma unroll
    for (int i = 0; i < 8; ++i) {
        int m = m0 + ty * 8 + i;
        int b = m / NP1;
        int n = m - b * NP1;
        bool addstop = (n == msz[b]);
#pragma unroll
        for (int j = 0; j < 8; ++j) {
            int h = n0 + tx * 8 + j;
            float v = acc[i][j];
            if (addstop) v += stopm[h];
            Cout[(size_t)m * HH + h] = v;
        }
    }
}

// -------------------------------------- gates_x = x @ w_ih^T + b_ih + b_hh
// M = 128*9 = 1152 rows (b*9+t), N = 2048, K = 512; row t==0 -> init_i
__global__ __launch_bounds__(256)
void k_xgates(const float* __restrict__ lstm_in,
              const float* __restrict__ init_i,
              const float* __restrict__ w_ih,
              const float* __restrict__ b_ih,
              const float* __restrict__ b_hh,
              float* __restrict__ out)
{
    __shared__ float As[16][68];
    __shared__ float Bs[16][68];
    const int tid = threadIdx.x;
    const int m0 = blockIdx.x * 64;
    const int n0 = blockIdx.y * 64;
    const int lak = tid & 15, lar = tid >> 4;
    const float* arow[4];
#pragma unroll
    for (int s = 0; s < 4; ++s) {
        int m = m0 + lar + 16 * s;
        int b = m / TP1;
        int t = m - b * TP1;
        arow[s] = (t == 0) ? init_i : (lstm_in + (size_t)(b * 8 + (t - 1)) * DD);
    }
    float acc[4][4] = {};
    for (int kt = 0; kt < DD; kt += 16) {
#pragma unroll
        for (int s = 0; s < 4; ++s) {
            As[lak][lar + 16 * s] = arow[s][kt + lak];
            Bs[lak][lar + 16 * s] = w_ih[(size_t)(n0 + lar + 16 * s) * DD + kt + lak];
        }
        __syncthreads();
        const int ty = tid >> 4, tx = tid & 15;
#pragma unroll
        for (int k = 0; k < 16; ++k) {
            float a[4], bv[4];
#pragma unroll
            for (int i = 0; i < 4; ++i) a[i] = As[k][ty * 4 + i];
#pragma unroll
            for (int j = 0; j < 4; ++j) bv[j] = Bs[k][tx * 4 + j];
#pragma unroll
            for (int i = 0; i < 4; ++i)
#pragma unroll
                for (int j = 0; j < 4; ++j) acc[i][j] += a[i] * bv[j];
        }
        __syncthreads();
    }
    const int ty = tid >> 4, tx = tid & 15;
#pragma unroll
    for (int i = 0; i < 4; ++i) {
        int m = m0 + ty * 4 + i;
#pragma unroll
        for (int j = 0; j < 4; ++j) {
            int n = n0 + tx * 4 + j;
            out[(size_t)m * G4 + n] = acc[i][j] + b_ih[n] + b_hh[n];
        }
    }
}

// ------------------------------------------------------------- init h, c
__global__ void k_init(const float* __restrict__ ih, const float* __restrict__ ic,
                       float* __restrict__ h, float* __restrict__ c)
{
    int idx = blockIdx.x * 256 + threadIdx.x;     // B*H
    int i = idx & (HH - 1);
    h[idx] = ih[i];
    c[idx] = ic[i];
}

// ------------------------------------ g = gates_x[:,t,:] + h @ w_hh^T
// M = 128, N = 2048, K = 512
__global__ __launch_bounds__(256)
void k_step(const float* __restrict__ h, const float* __restrict__ w_hh,
            const float* __restrict__ gx, float* __restrict__ g, int t)
{
    __shared__ float As[16][68];
    __shared__ float Bs[16][68];
    const int tid = threadIdx.x;
    const int m0 = blockIdx.x * 64;
    const int n0 = blockIdx.y * 64;
    const int lak = tid & 15, lar = tid >> 4;
    float acc[4][4] = {};
    for (int kt = 0; kt < HH; kt += 16) {
#pragma unroll
        for (int s = 0; s < 4; ++s) {
            As[lak][lar + 16 * s] = h[(size_t)(m0 + lar + 16 * s) * HH + kt + lak];
            Bs[lak][lar + 16 * s] = w_hh[(size_t)(n0 + lar + 16 * s) * HH + kt + lak];
        }
        __syncthreads();
        const int ty = tid >> 4, tx = tid & 15;
#pragma unroll
        for (int k = 0; k < 16; ++k) {
            float a[4], bv[4];
#pragma unroll
            for (int i = 0; i < 4; ++i) a[i] = As[k][ty * 4 + i];
#pragma unroll
            for (int j = 0; j < 4; ++j) bv[j] = Bs[k][tx * 4 + j];
#pragma unroll
            for (int i = 0; i < 4; ++i)
#pragma unroll
                for (int j = 0; j < 4; ++j) acc[i][j] += a[i] * bv[j];
        }
        __syncthreads();
    }
    const int ty = tid >> 4, tx = tid & 15;
#pragma unroll
    for (int i = 0; i < 4; ++i) {
        int b = m0 + ty * 4 + i;
#pragma unroll
        for (int j = 0; j < 4; ++j) {
            int n = n0 + tx * 4 + j;
            g[(size_t)b * G4 + n] = acc[i][j] + gx[((size_t)b * TP1 + t) * G4 + n];
        }
    }
}

// ---------------------------------------------------------- LSTM cell
__global__ void k_cell(const float* __restrict__ g, float* __restrict__ h,
                       float* __restrict__ c, float* __restrict__ query, int t)
{
    int idx = blockIdx.x * 256 + threadIdx.x;     // B*H
    int b = idx >> 9;
    int i = idx & (HH - 1);
    const float* gb = g + (size_t)b * G4;
    float ig = sigm(gb[i]);
    float fg = sigm(gb[512 + i]);
    float gg = tanhf(gb[1024 + i]);
    float og = sigm(gb[1536 + i]);
    float cv = fg * c[idx] + ig * gg;
    float hv = og * tanhf(cv);
    c[idx] = cv;
    h[idx] = hv;
    query[((size_t)b * TP1 + t) * HH + i] = hv;
}

// ------------------------------------------------ qw = query @ wq (NN)
// M = 1152, N = 512, K = 512
__global__ __launch_bounds__(256)
void k_qw(const float* __restrict__ A, const float* __restrict__ Wq,
          float* __restrict__ C)
{
    __shared__ float As[16][68];
    __shared__ float Bs[16][68];
    const int tid = threadIdx.x;
    const int m0 = blockIdx.x * 64;
    const int n0 = blockIdx.y * 64;
    const int lak = tid & 15, lar = tid >> 4;
    const int lbc = tid & 63, lbr = tid >> 6;
    float acc[4][4] = {};
    for (int kt = 0; kt < HH; kt += 16) {
#pragma unroll
        for (int s = 0; s < 4; ++s) {
            As[lak][lar + 16 * s] = A[(size_t)(m0 + lar + 16 * s) * HH + kt + lak];
            Bs[lbr + 4 * s][lbc] = Wq[(size_t)(kt + lbr + 4 * s) * HH + n0 + lbc];
        }
        __syncthreads();
        const int ty = tid >> 4, tx = tid & 15;
#pragma unroll
        for (int k = 0; k < 16; ++k) {
            float a[4], bv[4];
#pragma unroll
            for (int i = 0; i < 4; ++i) a[i] = As[k][ty * 4 + i];
#pragma unroll
            for (int j = 0; j < 4; ++j) bv[j] = Bs[k][tx * 4 + j];
#pragma unroll
            for (int i = 0; i < 4; ++i)
#pragma unroll
                for (int j = 0; j < 4; ++j) acc[i][j] += a[i] * bv[j];
        }
        __syncthreads();
    }
    const int ty = tid >> 4, tx = tid & 15;
#pragma unroll
    for (int i = 0; i < 4; ++i)
#pragma unroll
        for (int j = 0; j < 4; ++j)
            C[(size_t)(m0 + ty * 4 + i) * HH + n0 + tx * 4 + j] = acc[i][j];
}

// -------------------- score[b,q,n] = sum_h v[h]*tanh(feat[b,n,h]+qw[b,q,h])
// block = (n, b); feat row kept in registers across the 9 queries
__global__ __launch_bounds__(256)
void k_score(const float* __restrict__ feat, const float* __restrict__ qw,
             const float* __restrict__ v, const int* __restrict__ msz,
             float* __restrict__ score, int masked)
{
    const int n = blockIdx.x;
    const int b = blockIdx.y;
    const int tid = threadIdx.x;
    __shared__ float wsum[4];
    const float* frow = feat + ((size_t)b * NP1 + n) * HH;
    float f0 = frow[tid], f1 = frow[tid + 256];
    float v0 = v[tid], v1 = v[tid + 256];
    int m = msz[b];
    for (int q = 0; q < TP1; ++q) {
        const float* qrow = qw + ((size_t)b * TP1 + q) * HH;
        float part = v0 * tanhf(f0 + qrow[tid]) + v1 * tanhf(f1 + qrow[tid + 256]);
#pragma unroll
        for (int off = 32; off; off >>= 1) part += __shfl_down(part, off);
        if ((tid & 63) == 0) wsum[tid >> 6] = part;
        __syncthreads();
        if (tid == 0) {
            float s = wsum[0] + wsum[1] + wsum[2] + wsum[3];
            if (masked && n > m) s = NEGF;
            score[((size_t)b * TP1 + q) * NP1 + n] = s;
        }
        __syncthreads();
    }
}

// ---------------- softmax over n (257) then query2 = p @ feat; block = (q,b)
__global__ __launch_bounds__(256)
void k_softpv(const float* __restrict__ score, const float* __restrict__ feat,
              float* __restrict__ outq)
{
    const int q = blockIdx.x;
    const int b = blockIdx.y;
    const int tid = threadIdx.x;
    __shared__ float p[NP1];
    __shared__ float red[4];
    const float* srow = score + ((size_t)b * TP1 + q) * NP1;
    float mx = NEGF;
    for (int n = tid; n < NP1; n += 256) mx = fmaxf(mx, srow[n]);
#pragma unroll
    for (int off = 32; off; off >>= 1) mx = fmaxf(mx, __shfl_down(mx, off));
    if ((tid & 63) == 0) red[tid >> 6] = mx;
    __syncthreads();
    mx = fmaxf(fmaxf(red[0], red[1]), fmaxf(red[2], red[3]));
    __syncthreads();
    float lsum = 0.f;
    for (int n = tid; n < NP1; n += 256) {
        float e = expf(srow[n] - mx);
        p[n] = e;
        lsum += e;
    }
#pragma unroll
    for (int off = 32; off; off >>= 1) lsum += __shfl_down(lsum, off);
    if ((tid & 63) == 0) red[tid >> 6] = lsum;
    __syncthreads();
    float inv = 1.f / (red[0] + red[1] + red[2] + red[3]);
    const float* fb = feat + (size_t)b * NP1 * HH;
    float acc0 = 0.f, acc1 = 0.f;
    for (int n = 0; n < NP1; ++n) {
        float pn = p[n] * inv;
        acc0 += pn * fb[(size_t)n * HH + tid];
        acc1 += pn * fb[(size_t)n * HH + tid + 256];
    }
    outq[((size_t)b * TP1 + q) * HH + tid] = acc0;
    outq[((size_t)b * TP1 + q) * HH + tid + 256] = acc1;
}

// ===========================================================================
extern "C" void kernel_launch(void* const* d_in, const int* in_sizes, int n_in,
                              void* d_out, int out_size, void* d_ws, size_t ws_size,
                              hipStream_t stream)
{
    const float* attn_mem  = (const float*)d_in[0];
    const float* lstm_in   = (const float*)d_in[1];
    const int*   mem_sizes = (const int*)d_in[2];
    const float* init_h    = (const float*)d_in[3];
    const float* init_c    = (const float*)d_in[4];
    const float* init_i    = (const float*)d_in[5];
    const float* stop      = (const float*)d_in[6];
    const float* w_ih      = (const float*)d_in[7];
    const float* w_hh      = (const float*)d_in[8];
    const float* b_ih      = (const float*)d_in[9];
    const float* b_hh      = (const float*)d_in[10];
    const float* attn_wm   = (const float*)d_in[11];
    const float* attn_wq   = (const float*)d_in[12];
    const float* attn_v    = (const float*)d_in[13];
    const float* hop_wm    = (const float*)d_in[14];
    const float* hop_wq    = (const float*)d_in[15];
    const float* hop_v     = (const float*)d_in[16];
    float* out = (float*)d_out;

    float* ws = (float*)d_ws;
    float* feat    = ws;                                     // 128*257*512
    float* gatesx  = feat + (size_t)BB * NP1 * HH;           // 128*9*2048
    float* query   = gatesx + (size_t)BB * TP1 * G4;         // 128*9*512
    float* query2  = query + (size_t)BB * TP1 * HH;          // 128*9*512
    float* qw      = query2 + (size_t)BB * TP1 * HH;         // 128*9*512
    float* score   = qw + (size_t)BB * TP1 * HH;             // 128*9*257
    float* hbuf    = score + (size_t)BB * TP1 * NP1;         // 128*512
    float* cbuf    = hbuf + (size_t)BB * HH;                 // 128*512
    float* gbuf    = cbuf + (size_t)BB * HH;                 // 128*2048
    float* stopm_h = gbuf + (size_t)BB * G4;                 // 512
    float* stopm_a = stopm_h + HH;                           // 512

    k_stopm<<<dim3(4), dim3(256), 0, stream>>>(stop, hop_wm, attn_wm, stopm_h, stopm_a);

    // hop_feat into shared feat buffer
    k_feat<<<dim3(257, 4), dim3(256), 0, stream>>>(attn_mem, hop_wm, stopm_h, mem_sizes, feat);

    // LSTM
    k_xgates<<<dim3(18, 32), dim3(256), 0, stream>>>(lstm_in, init_i, w_ih, b_ih, b_hh, gatesx);
    k_init<<<dim3(256), dim3(256), 0, stream>>>(init_h, init_c, hbuf, cbuf);
    for (int t = 0; t < TP1; ++t) {
        k_step<<<dim3(2, 32), dim3(256), 0, stream>>>(hbuf, w_hh, gatesx, gbuf, t);
        k_cell<<<dim3(256), dim3(256), 0, stream>>>(gbuf, hbuf, cbuf, query, t);
    }

    // hop attention (masked) -> query2
    k_qw<<<dim3(18, 8), dim3(256), 0, stream>>>(query, hop_wq, qw);
    k_score<<<dim3(257, 128), dim3(256), 0, stream>>>(feat, qw, hop_v, mem_sizes, score, 1);
    k_softpv<<<dim3(9, 128), dim3(256), 0, stream>>>(score, feat, query2);

    // final pointer scores (unmasked) -> d_out
    k_qw<<<dim3(18, 8), dim3(256), 0, stream>>>(query2, attn_wq, qw);
    k_feat<<<dim3(257, 4), dim3(256), 0, stream>>>(attn_mem, attn_wm, stopm_a, mem_sizes, feat);
    k_score<<<dim3(257, 128), dim3(256), 0, stream>>>(feat, qw, attn_v, mem_sizes, out, 0);
}

// Round 2
// 890.794 us; speedup vs baseline: 1.6237x; 1.6237x over previous
//
#include <hip/hip_runtime.h>
#include <hip/hip_bf16.h>
#include <math.h>

#define BB   128
#define NPTS 256
#define NP1  257
#define DD   512
#define HH   512
#define G4   2048
#define TP1  9
#define NEGF -1e18f
#define MTOT (BB * NP1)   // 32896

typedef __attribute__((ext_vector_type(8))) short bf16x8;
typedef __attribute__((ext_vector_type(4))) float f32x4;

__device__ __forceinline__ float sigm(float x) { return 1.0f / (1.0f + expf(-x)); }

__device__ __forceinline__ void gl_lds16(const __hip_bfloat16* g, __hip_bfloat16* l)
{
    __builtin_amdgcn_global_load_lds(
        (const __attribute__((address_space(1))) void*)g,
        (__attribute__((address_space(3))) void*)l, 16, 0, 0);
}

// ---------------------------------------------------------------- stop @ wm
__global__ void k_stopm(const float* __restrict__ stop,
                        const float* __restrict__ wmh,
                        const float* __restrict__ wma,
                        float* __restrict__ smh,
                        float* __restrict__ sma)
{
    int g = blockIdx.x * 256 + threadIdx.x;       // 0..1023
    const float* wm = (g < HH) ? wmh : wma;
    float* out      = (g < HH) ? smh : sma;
    int h = g & (HH - 1);
    float acc = 0.f;
    for (int k = 0; k < DD; ++k) acc += stop[k] * wm[k * HH + h];
    out[h] = acc;
}

// ------------------------------------- attn_mem (+zero stop row) -> bf16
// Abf[b*257+n][k] = bf16(attn_mem[b,n,k]) for n<256, 0 for n==256
__global__ void k_cvtA(const float* __restrict__ Amem,
                       __hip_bfloat16* __restrict__ Abf)
{
    const int m = blockIdx.x;                 // 0..32895
    const int b = m / NP1;
    const int n = m - b * NP1;
    const int t = threadIdx.x;                // 0..255, 2 cols each
    float2 v = make_float2(0.f, 0.f);
    if (n < NPTS)
        v = *(const float2*)(Amem + ((size_t)(b * NPTS + n)) * DD + 2 * t);
    __hip_bfloat16* o = Abf + (size_t)m * DD + 2 * t;
    o[0] = __float2bfloat16(v.x);
    o[1] = __float2bfloat16(v.y);
}

// ------------------------------------- Wt[n][k] = bf16(W[k][n]) for 2 weights
__global__ void k_cvtW(const float* __restrict__ Wh, const float* __restrict__ Wa,
                       __hip_bfloat16* __restrict__ WtH, __hip_bfloat16* __restrict__ WtA)
{
    const float* W = blockIdx.y ? Wa : Wh;
    __hip_bfloat16* O = blockIdx.y ? WtA : WtH;
    const int n = blockIdx.x;                 // 0..511
    const int t = threadIdx.x;                // 0..255
    O[(size_t)n * DD + t]       = __float2bfloat16(W[(size_t)t * HH + n]);
    O[(size_t)n * DD + t + 256] = __float2bfloat16(W[(size_t)(t + 256) * HH + n]);
}

// ---------------------------------------------- feat = Abf @ WtT  (MFMA bf16)
// C[m][h] = sum_k Abf[m][k] * Wt[h][k]  (+ stopm[h] where n==msz[b])
// M = 32896 (257 tiles), N = 512 (4 tiles), K = 512 (8 steps of 64)
__global__ __launch_bounds__(256)
void k_feat_mfma(const __hip_bfloat16* __restrict__ A,
                 const __hip_bfloat16* __restrict__ Bt,
                 const float* __restrict__ stopm,
                 const int* __restrict__ msz,
                 float* __restrict__ C)
{
    __shared__ __align__(16) __hip_bfloat16 As[128 * 64];
    __shared__ __align__(16) __hip_bfloat16 Bs[128 * 64];
    const int tid  = threadIdx.x;
    const int lane = tid & 63;
    const int wid  = tid >> 6;
    const int m0 = blockIdx.x * 128;
    const int n0 = blockIdx.y * 128;
    const int wr = (wid >> 1) * 64;           // wave quadrant
    const int wc = (wid & 1) * 64;

    // staging: per wave 4 insts for A tile + 4 for B tile, 1KB each.
    // LDS dest is linear; global source is pre-swizzled: chunk ^= row&7
    const __hip_bfloat16* aptr[4];
    const __hip_bfloat16* bptr[4];
    int ldsoff[4];
#pragma unroll
    for (int s = 0; s < 4; ++s) {
        const int si = wid * 4 + s;
        const int o = si * 1024 + lane * 16;  // byte offset within 16KB tile
        const int row = o >> 7;               // 128B per row (64 bf16)
        const int chunk = (o >> 4) & 7;
        const int sch = chunk ^ (row & 7);    // involutive source swizzle
        aptr[s] = A + (size_t)(m0 + row) * DD + sch * 8;
        bptr[s] = Bt + (size_t)(n0 + row) * DD + sch * 8;
        ldsoff[s] = si * 512;                 // element offset (1KB chunks)
    }

    f32x4 acc[4][4];
#pragma unroll
    for (int i = 0; i < 4; ++i)
#pragma unroll
        for (int j = 0; j < 4; ++j) acc[i][j] = (f32x4){0.f, 0.f, 0.f, 0.f};

    const int rA = lane & 15;
    const int kgrp = lane >> 4;               // 0..3

    for (int kt = 0; kt < DD; kt += 64) {
#pragma unroll
        for (int s = 0; s < 4; ++s) gl_lds16(aptr[s] + kt, As + ldsoff[s]);
#pragma unroll
        for (int s = 0; s < 4; ++s) gl_lds16(bptr[s] + kt, Bs + ldsoff[s]);
        __syncthreads();                      // drains vmcnt before LDS reads

#pragma unroll
        for (int ks = 0; ks < 2; ++ks) {
            bf16x8 af[4], bfr[4];
#pragma unroll
            for (int fi = 0; fi < 4; ++fi) {
                const int r = wr + fi * 16 + rA;
                const int ch = (ks * 4 + kgrp) ^ (r & 7);
                af[fi] = *(const bf16x8*)(As + r * 64 + ch * 8);
            }
#pragma unroll
            for (int fj = 0; fj < 4; ++fj) {
                const int r = wc + fj * 16 + rA;
                const int ch = (ks * 4 + kgrp) ^ (r & 7);
                bfr[fj] = *(const bf16x8*)(Bs + r * 64 + ch * 8);
            }
#pragma unroll
            for (int fi = 0; fi < 4; ++fi)
#pragma unroll
                for (int fj = 0; fj < 4; ++fj)
                    acc[fi][fj] = __builtin_amdgcn_mfma_f32_16x16x32_bf16(
                        af[fi], bfr[fj], acc[fi][fj], 0, 0, 0);
        }
        __syncthreads();
    }

    // epilogue: C/D layout col=lane&15, row=(lane>>4)*4+reg
#pragma unroll
    for (int fi = 0; fi < 4; ++fi) {
#pragma unroll
        for (int r = 0; r < 4; ++r) {
            const int m = m0 + wr + fi * 16 + (lane >> 4) * 4 + r;
            const int b = m / NP1;
            const int n = m - b * NP1;
            const bool addstop = (n == msz[b]);
#pragma unroll
            for (int fj = 0; fj < 4; ++fj) {
                const int h = n0 + wc + fj * 16 + (lane & 15);
                float v = acc[fi][fj][r];
                if (addstop) v += stopm[h];
                C[(size_t)m * HH + h] = v;
            }
        }
    }
}

// -------------------------------------- gates_x = x @ w_ih^T + b_ih + b_hh
__global__ __launch_bounds__(256)
void k_xgates(const float* __restrict__ lstm_in,
              const float* __restrict__ init_i,
              const float* __restrict__ w_ih,
              const float* __restrict__ b_ih,
              const float* __restrict__ b_hh,
              float* __restrict__ out)
{
    __shared__ float As[16][68];
    __shared__ float Bs[16][68];
    const int tid = threadIdx.x;
    const int m0 = blockIdx.x * 64;
    const int n0 = blockIdx.y * 64;
    const int lak = tid & 15, lar = tid >> 4;
    const float* arow[4];
#pragma unroll
    for (int s = 0; s < 4; ++s) {
        int m = m0 + lar + 16 * s;
        int b = m / TP1;
        int t = m - b * TP1;
        arow[s] = (t == 0) ? init_i : (lstm_in + (size_t)(b * 8 + (t - 1)) * DD);
    }
    float acc[4][4] = {};
    for (int kt = 0; kt < DD; kt += 16) {
#pragma unroll
        for (int s = 0; s < 4; ++s) {
            As[lak][lar + 16 * s] = arow[s][kt + lak];
            Bs[lak][lar + 16 * s] = w_ih[(size_t)(n0 + lar + 16 * s) * DD + kt + lak];
        }
        __syncthreads();
        const int ty = tid >> 4, tx = tid & 15;
#pragma unroll
        for (int k = 0; k < 16; ++k) {
            float a[4], bv[4];
#pragma unroll
            for (int i = 0; i < 4; ++i) a[i] = As[k][ty * 4 + i];
#pragma unroll
            for (int j = 0; j < 4; ++j) bv[j] = Bs[k][tx * 4 + j];
#pragma unroll
            for (int i = 0; i < 4; ++i)
#pragma unroll
                for (int j = 0; j < 4; ++j) acc[i][j] += a[i] * bv[j];
        }
        __syncthreads();
    }
    const int ty = tid >> 4, tx = tid & 15;
#pragma unroll
    for (int i = 0; i < 4; ++i) {
        int m = m0 + ty * 4 + i;
#pragma unroll
        for (int j = 0; j < 4; ++j) {
            int n = n0 + tx * 4 + j;
            out[(size_t)m * G4 + n] = acc[i][j] + b_ih[n] + b_hh[n];
        }
    }
}

// ------------------------------------------------------------- init h, c
__global__ void k_init(const float* __restrict__ ih, const float* __restrict__ ic,
                       float* __restrict__ h, float* __restrict__ c)
{
    int idx = blockIdx.x * 256 + threadIdx.x;     // B*H
    int i = idx & (HH - 1);
    h[idx] = ih[i];
    c[idx] = ic[i];
}

// ------------------------------------ g = gates_x[:,t,:] + h @ w_hh^T
__global__ __launch_bounds__(256)
void k_step(const float* __restrict__ h, const float* __restrict__ w_hh,
            const float* __restrict__ gx, float* __restrict__ g, int t)
{
    __shared__ float As[16][68];
    __shared__ float Bs[16][68];
    const int tid = threadIdx.x;
    const int m0 = blockIdx.x * 64;
    const int n0 = blockIdx.y * 64;
    const int lak = tid & 15, lar = tid >> 4;
    float acc[4][4] = {};
    for (int kt = 0; kt < HH; kt += 16) {
#pragma unroll
        for (int s = 0; s < 4; ++s) {
            As[lak][lar + 16 * s] = h[(size_t)(m0 + lar + 16 * s) * HH + kt + lak];
            Bs[lak][lar + 16 * s] = w_hh[(size_t)(n0 + lar + 16 * s) * HH + kt + lak];
        }
        __syncthreads();
        const int ty = tid >> 4, tx = tid & 15;
#pragma unroll
        for (int k = 0; k < 16; ++k) {
            float a[4], bv[4];
#pragma unroll
            for (int i = 0; i < 4; ++i) a[i] = As[k][ty * 4 + i];
#pragma unroll
            for (int j = 0; j < 4; ++j) bv[j] = Bs[k][tx * 4 + j];
#pragma unroll
            for (int i = 0; i < 4; ++i)
#pragma unroll
                for (int j = 0; j < 4; ++j) acc[i][j] += a[i] * bv[j];
        }
        __syncthreads();
    }
    const int ty = tid >> 4, tx = tid & 15;
#pragma unroll
    for (int i = 0; i < 4; ++i) {
        int b = m0 + ty * 4 + i;
#pragma unroll
        for (int j = 0; j < 4; ++j) {
            int n = n0 + tx * 4 + j;
            g[(size_t)b * G4 + n] = acc[i][j] + gx[((size_t)b * TP1 + t) * G4 + n];
        }
    }
}

// ---------------------------------------------------------- LSTM cell
__global__ void k_cell(const float* __restrict__ g, float* __restrict__ h,
                       float* __restrict__ c, float* __restrict__ query, int t)
{
    int idx = blockIdx.x * 256 + threadIdx.x;     // B*H
    int b = idx >> 9;
    int i = idx & (HH - 1);
    const float* gb = g + (size_t)b * G4;
    float ig = sigm(gb[i]);
    float fg = sigm(gb[512 + i]);
    float gg = tanhf(gb[1024 + i]);
    float og = sigm(gb[1536 + i]);
    float cv = fg * c[idx] + ig * gg;
    float hv = og * tanhf(cv);
    c[idx] = cv;
    h[idx] = hv;
    query[((size_t)b * TP1 + t) * HH + i] = hv;
}

// ------------------------------------------------ qw = query @ wq (NN)
__global__ __launch_bounds__(256)
void k_qw(const float* __restrict__ A, const float* __restrict__ Wq,
          float* __restrict__ C)
{
    __shared__ float As[16][68];
    __shared__ float Bs[16][68];
    const int tid = threadIdx.x;
    const int m0 = blockIdx.x * 64;
    const int n0 = blockIdx.y * 64;
    const int lak = tid & 15, lar = tid >> 4;
    const int lbc = tid & 63, lbr = tid >> 6;
    float acc[4][4] = {};
    for (int kt = 0; kt < HH; kt += 16) {
#pragma unroll
        for (int s = 0; s < 4; ++s) {
            As[lak][lar + 16 * s] = A[(size_t)(m0 + lar + 16 * s) * HH + kt + lak];
            Bs[lbr + 4 * s][lbc] = Wq[(size_t)(kt + lbr + 4 * s) * HH + n0 + lbc];
        }
        __syncthreads();
        const int ty = tid >> 4, tx = tid & 15;
#pragma unroll
        for (int k = 0; k < 16; ++k) {
            float a[4], bv[4];
#pragma unroll
            for (int i = 0; i < 4; ++i) a[i] = As[k][ty * 4 + i];
#pragma unroll
            for (int j = 0; j < 4; ++j) bv[j] = Bs[k][tx * 4 + j];
#pragma unroll
            for (int i = 0; i < 4; ++i)
#pragma unroll
                for (int j = 0; j < 4; ++j) acc[i][j] += a[i] * bv[j];
        }
        __syncthreads();
    }
    const int ty = tid >> 4, tx = tid & 15;
#pragma unroll
    for (int i = 0; i < 4; ++i)
#pragma unroll
        for (int j = 0; j < 4; ++j)
            C[(size_t)(m0 + ty * 4 + i) * HH + n0 + tx * 4 + j] = acc[i][j];
}

// -------------------- score[b,q,n] = sum_h v[h]*tanh(feat[b,n,h]+qw[b,q,h])
__global__ __launch_bounds__(256)
void k_score(const float* __restrict__ feat, const float* __restrict__ qw,
             const float* __restrict__ v, const int* __restrict__ msz,
             float* __restrict__ score, int masked)
{
    const int n = blockIdx.x;
    const int b = blockIdx.y;
    const int tid = threadIdx.x;
    __shared__ float wsum[4];
    const float* frow = feat + ((size_t)b * NP1 + n) * HH;
    float f0 = frow[tid], f1 = frow[tid + 256];
    float v0 = v[tid], v1 = v[tid + 256];
    int m = msz[b];
    for (int q = 0; q < TP1; ++q) {
        const float* qrow = qw + ((size_t)b * TP1 + q) * HH;
        float part = v0 * tanhf(f0 + qrow[tid]) + v1 * tanhf(f1 + qrow[tid + 256]);
#pragma unroll
        for (int off = 32; off; off >>= 1) part += __shfl_down(part, off);
        if ((tid & 63) == 0) wsum[tid >> 6] = part;
        __syncthreads();
        if (tid == 0) {
            float s = wsum[0] + wsum[1] + wsum[2] + wsum[3];
            if (masked && n > m) s = NEGF;
            score[((size_t)b * TP1 + q) * NP1 + n] = s;
        }
        __syncthreads();
    }
}

// ---------------- softmax over n (257) then query2 = p @ feat; block = (q,b)
__global__ __launch_bounds__(256)
void k_softpv(const float* __restrict__ score, const float* __restrict__ feat,
              float* __restrict__ outq)
{
    const int q = blockIdx.x;
    const int b = blockIdx.y;
    const int tid = threadIdx.x;
    __shared__ float p[NP1];
    __shared__ float red[4];
    const float* srow = score + ((size_t)b * TP1 + q) * NP1;
    float mx = NEGF;
    for (int n = tid; n < NP1; n += 256) mx = fmaxf(mx, srow[n]);
#pragma unroll
    for (int off = 32; off; off >>= 1) mx = fmaxf(mx, __shfl_down(mx, off));
    if ((tid & 63) == 0) red[tid >> 6] = mx;
    __syncthreads();
    mx = fmaxf(fmaxf(red[0], red[1]), fmaxf(red[2], red[3]));
    __syncthreads();
    float lsum = 0.f;
    for (int n = tid; n < NP1; n += 256) {
        float e = expf(srow[n] - mx);
        p[n] = e;
        lsum += e;
    }
#pragma unroll
    for (int off = 32; off; off >>= 1) lsum += __shfl_down(lsum, off);
    if ((tid & 63) == 0) red[tid >> 6] = lsum;
    __syncthreads();
    float inv = 1.f / (red[0] + red[1] + red[2] + red[3]);
    const float* fb = feat + (size_t)b * NP1 * HH;
    float acc0 = 0.f, acc1 = 0.f;
    for (int n = 0; n < NP1; ++n) {
        float pn = p[n] * inv;
        acc0 += pn * fb[(size_t)n * HH + tid];
        acc1 += pn * fb[(size_t)n * HH + tid + 256];
    }
    outq[((size_t)b * TP1 + q) * HH + tid] = acc0;
    outq[((size_t)b * TP1 + q) * HH + tid + 256] = acc1;
}

// ===========================================================================
extern "C" void kernel_launch(void* const* d_in, const int* in_sizes, int n_in,
                              void* d_out, int out_size, void* d_ws, size_t ws_size,
                              hipStream_t stream)
{
    const float* attn_mem  = (const float*)d_in[0];
    const float* lstm_in   = (const float*)d_in[1];
    const int*   mem_sizes = (const int*)d_in[2];
    const float* init_h    = (const float*)d_in[3];
    const float* init_c    = (const float*)d_in[4];
    const float* init_i    = (const float*)d_in[5];
    const float* stop      = (const float*)d_in[6];
    const float* w_ih      = (const float*)d_in[7];
    const float* w_hh      = (const float*)d_in[8];
    const float* b_ih      = (const float*)d_in[9];
    const float* b_hh      = (const float*)d_in[10];
    const float* attn_wm   = (const float*)d_in[11];
    const float* attn_wq   = (const float*)d_in[12];
    const float* attn_v    = (const float*)d_in[13];
    const float* hop_wm    = (const float*)d_in[14];
    const float* hop_wq    = (const float*)d_in[15];
    const float* hop_v     = (const float*)d_in[16];
    float* out = (float*)d_out;

    char* w = (char*)d_ws;
    __hip_bfloat16* Abf = (__hip_bfloat16*)w;  w += (size_t)MTOT * DD * 2;   // 33.7 MB
    __hip_bfloat16* WtH = (__hip_bfloat16*)w;  w += (size_t)DD * HH * 2;     // 0.5 MB
    __hip_bfloat16* WtA = (__hip_bfloat16*)w;  w += (size_t)DD * HH * 2;     // 0.5 MB
    float* feat    = (float*)w;  w += (size_t)MTOT * HH * 4;                 // 67.4 MB
    float* gatesx  = (float*)w;  w += (size_t)BB * TP1 * G4 * 4;             // 9.4 MB
    float* query   = (float*)w;  w += (size_t)BB * TP1 * HH * 4;
    float* query2  = (float*)w;  w += (size_t)BB * TP1 * HH * 4;
    float* qw      = (float*)w;  w += (size_t)BB * TP1 * HH * 4;
    float* score   = (float*)w;  w += (size_t)BB * TP1 * NP1 * 4;
    float* hbuf    = (float*)w;  w += (size_t)BB * HH * 4;
    float* cbuf    = (float*)w;  w += (size_t)BB * HH * 4;
    float* gbuf    = (float*)w;  w += (size_t)BB * G4 * 4;
    float* stopm_h = (float*)w;  w += HH * 4;
    float* stopm_a = (float*)w;  w += HH * 4;

    // precompute: bf16 operands + stop projections
    k_cvtA<<<dim3(MTOT), dim3(256), 0, stream>>>(attn_mem, Abf);
    k_cvtW<<<dim3(512, 2), dim3(256), 0, stream>>>(hop_wm, attn_wm, WtH, WtA);
    k_stopm<<<dim3(4), dim3(256), 0, stream>>>(stop, hop_wm, attn_wm, stopm_h, stopm_a);

    // hop_feat (MFMA)
    k_feat_mfma<<<dim3(257, 4), dim3(256), 0, stream>>>(Abf, WtH, stopm_h, mem_sizes, feat);

    // LSTM
    k_xgates<<<dim3(18, 32), dim3(256), 0, stream>>>(lstm_in, init_i, w_ih, b_ih, b_hh, gatesx);
    k_init<<<dim3(256), dim3(256), 0, stream>>>(init_h, init_c, hbuf, cbuf);
    for (int t = 0; t < TP1; ++t) {
        k_step<<<dim3(2, 32), dim3(256), 0, stream>>>(hbuf, w_hh, gatesx, gbuf, t);
        k_cell<<<dim3(256), dim3(256), 0, stream>>>(gbuf, hbuf, cbuf, query, t);
    }

    // hop attention (masked) -> query2
    k_qw<<<dim3(18, 8), dim3(256), 0, stream>>>(query, hop_wq, qw);
    k_score<<<dim3(257, 128), dim3(256), 0, stream>>>(feat, qw, hop_v, mem_sizes, score, 1);
    k_softpv<<<dim3(9, 128), dim3(256), 0, stream>>>(score, feat, query2);

    // final pointer scores (unmasked) -> d_out
    k_qw<<<dim3(18, 8), dim3(256), 0, stream>>>(query2, attn_wq, qw);
    k_feat_mfma<<<dim3(257, 4), dim3(256), 0, stream>>>(Abf, WtA, stopm_a, mem_sizes, feat);
    k_score<<<dim3(257, 128), dim3(256), 0, stream>>>(feat, qw, attn_v, mem_sizes, out, 0);
}

// Round 3
// 551.433 us; speedup vs baseline: 2.6229x; 1.6154x over previous
//
#include <hip/hip_runtime.h>
#include <hip/hip_bf16.h>
#include <math.h>

#define BB   128
#define NPTS 256
#define NP1  257
#define DD   512
#define HH   512
#define G4   2048
#define TP1  9
#define NEGF -1e18f
#define MTOT (BB * NP1)   // 32896

typedef __attribute__((ext_vector_type(8))) short bf16x8;
typedef __attribute__((ext_vector_type(4))) float f32x4;

__device__ __forceinline__ float sigm(float x) { return 1.0f / (1.0f + expf(-x)); }

// tanh(x) = 1 - 2/(e^{2x}+1) via v_exp_f32: ~5 VALU ops, exact at +-inf
__device__ __forceinline__ float fast_tanh(float x)
{
    float e = __builtin_amdgcn_exp2f(x * 2.8853900817779268f);  // 2*log2(e)
    return 1.0f - 2.0f * __builtin_amdgcn_rcpf(e + 1.0f);
}

__device__ __forceinline__ void gl_lds16(const __hip_bfloat16* g, __hip_bfloat16* l)
{
    __builtin_amdgcn_global_load_lds(
        (const __attribute__((address_space(1))) void*)g,
        (__attribute__((address_space(3))) void*)l, 16, 0, 0);
}

// ---------------------------------------------------------------- stop @ wm
__global__ void k_stopm(const float* __restrict__ stop,
                        const float* __restrict__ wmh,
                        const float* __restrict__ wma,
                        float* __restrict__ smh,
                        float* __restrict__ sma)
{
    int g = blockIdx.x * 256 + threadIdx.x;       // 0..1023
    const float* wm = (g < HH) ? wmh : wma;
    float* out      = (g < HH) ? smh : sma;
    int h = g & (HH - 1);
    float acc = 0.f;
    for (int k = 0; k < DD; ++k) acc += stop[k] * wm[k * HH + h];
    out[h] = acc;
}

// ------------------------------------- attn_mem (+zero stop row) -> bf16
__global__ void k_cvtA(const float* __restrict__ Amem,
                       __hip_bfloat16* __restrict__ Abf)
{
    const int m = blockIdx.x;                 // 0..32895
    const int b = m / NP1;
    const int n = m - b * NP1;
    const int t = threadIdx.x;                // 0..255, 2 cols each
    float2 v = make_float2(0.f, 0.f);
    if (n < NPTS)
        v = *(const float2*)(Amem + ((size_t)(b * NPTS + n)) * DD + 2 * t);
    __hip_bfloat16* o = Abf + (size_t)m * DD + 2 * t;
    o[0] = __float2bfloat16(v.x);
    o[1] = __float2bfloat16(v.y);
}

// ------------------------------------- Wt[n][k] = bf16(W[k][n]) for 2 weights
__global__ void k_cvtW(const float* __restrict__ Wh, const float* __restrict__ Wa,
                       __hip_bfloat16* __restrict__ WtH, __hip_bfloat16* __restrict__ WtA)
{
    const float* W = blockIdx.y ? Wa : Wh;
    __hip_bfloat16* O = blockIdx.y ? WtA : WtH;
    const int n = blockIdx.x;                 // 0..511
    const int t = threadIdx.x;                // 0..255
    O[(size_t)n * DD + t]       = __float2bfloat16(W[(size_t)t * HH + n]);
    O[(size_t)n * DD + t + 256] = __float2bfloat16(W[(size_t)(t + 256) * HH + n]);
}

// ------------------------------------- w_hh [2048][512] -> bf16 (no transpose)
__global__ void k_cvtWhh(const float* __restrict__ w, __hip_bfloat16* __restrict__ o)
{
    int idx = blockIdx.x * 256 + threadIdx.x;     // 1048576 total
    o[idx] = __float2bfloat16(w[idx]);
}

// ---------------------------------------------- feat = Abf @ WtT  (MFMA bf16)
__global__ __launch_bounds__(256)
void k_feat_mfma(const __hip_bfloat16* __restrict__ A,
                 const __hip_bfloat16* __restrict__ Bt,
                 const float* __restrict__ stopm,
                 const int* __restrict__ msz,
                 float* __restrict__ C)
{
    __shared__ __align__(16) __hip_bfloat16 As[128 * 64];
    __shared__ __align__(16) __hip_bfloat16 Bs[128 * 64];
    const int tid  = threadIdx.x;
    const int lane = tid & 63;
    const int wid  = tid >> 6;
    const int m0 = blockIdx.x * 128;
    const int n0 = blockIdx.y * 128;
    const int wr = (wid >> 1) * 64;
    const int wc = (wid & 1) * 64;

    const __hip_bfloat16* aptr[4];
    const __hip_bfloat16* bptr[4];
    int ldsoff[4];
#pragma unroll
    for (int s = 0; s < 4; ++s) {
        const int si = wid * 4 + s;
        const int o = si * 1024 + lane * 16;
        const int row = o >> 7;
        const int chunk = (o >> 4) & 7;
        const int sch = chunk ^ (row & 7);
        aptr[s] = A + (size_t)(m0 + row) * DD + sch * 8;
        bptr[s] = Bt + (size_t)(n0 + row) * DD + sch * 8;
        ldsoff[s] = si * 512;
    }

    f32x4 acc[4][4];
#pragma unroll
    for (int i = 0; i < 4; ++i)
#pragma unroll
        for (int j = 0; j < 4; ++j) acc[i][j] = (f32x4){0.f, 0.f, 0.f, 0.f};

    const int rA = lane & 15;
    const int kgrp = lane >> 4;

    for (int kt = 0; kt < DD; kt += 64) {
#pragma unroll
        for (int s = 0; s < 4; ++s) gl_lds16(aptr[s] + kt, As + ldsoff[s]);
#pragma unroll
        for (int s = 0; s < 4; ++s) gl_lds16(bptr[s] + kt, Bs + ldsoff[s]);
        __syncthreads();

#pragma unroll
        for (int ks = 0; ks < 2; ++ks) {
            bf16x8 af[4], bfr[4];
#pragma unroll
            for (int fi = 0; fi < 4; ++fi) {
                const int r = wr + fi * 16 + rA;
                const int ch = (ks * 4 + kgrp) ^ (r & 7);
                af[fi] = *(const bf16x8*)(As + r * 64 + ch * 8);
            }
#pragma unroll
            for (int fj = 0; fj < 4; ++fj) {
                const int r = wc + fj * 16 + rA;
                const int ch = (ks * 4 + kgrp) ^ (r & 7);
                bfr[fj] = *(const bf16x8*)(Bs + r * 64 + ch * 8);
            }
#pragma unroll
            for (int fi = 0; fi < 4; ++fi)
#pragma unroll
                for (int fj = 0; fj < 4; ++fj)
                    acc[fi][fj] = __builtin_amdgcn_mfma_f32_16x16x32_bf16(
                        af[fi], bfr[fj], acc[fi][fj], 0, 0, 0);
        }
        __syncthreads();
    }

#pragma unroll
    for (int fi = 0; fi < 4; ++fi) {
#pragma unroll
        for (int r = 0; r < 4; ++r) {
            const int m = m0 + wr + fi * 16 + (lane >> 4) * 4 + r;
            const int b = m / NP1;
            const int n = m - b * NP1;
            const bool addstop = (n == msz[b]);
#pragma unroll
            for (int fj = 0; fj < 4; ++fj) {
                const int h = n0 + wc + fj * 16 + (lane & 15);
                float v = acc[fi][fj][r];
                if (addstop) v += stopm[h];
                C[(size_t)m * HH + h] = v;
            }
        }
    }
}

// -------------------------------------- gates_x = x @ w_ih^T + b_ih + b_hh
__global__ __launch_bounds__(256)
void k_xgates(const float* __restrict__ lstm_in,
              const float* __restrict__ init_i,
              const float* __restrict__ w_ih,
              const float* __restrict__ b_ih,
              const float* __restrict__ b_hh,
              float* __restrict__ out)
{
    __shared__ float As[16][68];
    __shared__ float Bs[16][68];
    const int tid = threadIdx.x;
    const int m0 = blockIdx.x * 64;
    const int n0 = blockIdx.y * 64;
    const int lak = tid & 15, lar = tid >> 4;
    const float* arow[4];
#pragma unroll
    for (int s = 0; s < 4; ++s) {
        int m = m0 + lar + 16 * s;
        int b = m / TP1;
        int t = m - b * TP1;
        arow[s] = (t == 0) ? init_i : (lstm_in + (size_t)(b * 8 + (t - 1)) * DD);
    }
    float acc[4][4] = {};
    for (int kt = 0; kt < DD; kt += 16) {
#pragma unroll
        for (int s = 0; s < 4; ++s) {
            As[lak][lar + 16 * s] = arow[s][kt + lak];
            Bs[lak][lar + 16 * s] = w_ih[(size_t)(n0 + lar + 16 * s) * DD + kt + lak];
        }
        __syncthreads();
        const int ty = tid >> 4, tx = tid & 15;
#pragma unroll
        for (int k = 0; k < 16; ++k) {
            float a[4], bv[4];
#pragma unroll
            for (int i = 0; i < 4; ++i) a[i] = As[k][ty * 4 + i];
#pragma unroll
            for (int j = 0; j < 4; ++j) bv[j] = Bs[k][tx * 4 + j];
#pragma unroll
            for (int i = 0; i < 4; ++i)
#pragma unroll
                for (int j = 0; j < 4; ++j) acc[i][j] += a[i] * bv[j];
        }
        __syncthreads();
    }
    const int ty = tid >> 4, tx = tid & 15;
#pragma unroll
    for (int i = 0; i < 4; ++i) {
        int m = m0 + ty * 4 + i;
#pragma unroll
        for (int j = 0; j < 4; ++j) {
            int n = n0 + tx * 4 + j;
            out[(size_t)m * G4 + n] = acc[i][j] + b_ih[n] + b_hh[n];
        }
    }
}

// ------------------------------------------------------------- init h, c
__global__ void k_init(const float* __restrict__ ih, const float* __restrict__ ic,
                       __hip_bfloat16* __restrict__ h, float* __restrict__ c)
{
    int idx = blockIdx.x * 256 + threadIdx.x;     // B*H
    int i = idx & (HH - 1);
    h[idx] = __float2bfloat16(ih[i]);
    c[idx] = ic[i];
}

// ---------------- fused LSTM step: g = h@w_hh^T (MFMA) + gx; cell; h out
// grid 16: block z owns h-cols hc0 = z*32 (gate cols {g*512+hc0+j}); M = 128.
__global__ __launch_bounds__(256)
void k_lstm(const __hip_bfloat16* __restrict__ hin,   // [128][512]
            const __hip_bfloat16* __restrict__ whh,   // [2048][512]
            const float* __restrict__ gx,             // [1152][2048]
            float* __restrict__ cbuf,                 // [128][512]
            __hip_bfloat16* __restrict__ hout,        // [128][512]
            float* __restrict__ query,                // [1152][512]
            int t)
{
    __shared__ __align__(16) __hip_bfloat16 As[128 * 64];
    __shared__ __align__(16) __hip_bfloat16 Bs[128 * 64];
    __shared__ float Gs[128][132];                    // padded: conflict-free
    const int tid  = threadIdx.x;
    const int lane = tid & 63;
    const int wid  = tid >> 6;
    const int hc0  = blockIdx.x * 32;
    const int wr = (wid >> 1) * 64;
    const int wc = (wid & 1) * 64;

    const __hip_bfloat16* aptr[4];
    const __hip_bfloat16* bptr[4];
    int ldsoff[4];
#pragma unroll
    for (int s = 0; s < 4; ++s) {
        const int si = wid * 4 + s;
        const int o = si * 1024 + lane * 16;
        const int row = o >> 7;                       // LDS tile row 0..127
        const int chunk = (o >> 4) & 7;
        const int sch = chunk ^ (row & 7);
        aptr[s] = hin + (size_t)row * HH + sch * 8;
        const int brow = (row >> 5) * 512 + hc0 + (row & 31);  // gate strips
        bptr[s] = whh + (size_t)brow * HH + sch * 8;
        ldsoff[s] = si * 512;
    }

    f32x4 acc[4][4];
#pragma unroll
    for (int i = 0; i < 4; ++i)
#pragma unroll
        for (int j = 0; j < 4; ++j) acc[i][j] = (f32x4){0.f, 0.f, 0.f, 0.f};

    const int rA = lane & 15;
    const int kgrp = lane >> 4;

    for (int kt = 0; kt < HH; kt += 64) {
#pragma unroll
        for (int s = 0; s < 4; ++s) gl_lds16(aptr[s] + kt, As + ldsoff[s]);
#pragma unroll
        for (int s = 0; s < 4; ++s) gl_lds16(bptr[s] + kt, Bs + ldsoff[s]);
        __syncthreads();
#pragma unroll
        for (int ks = 0; ks < 2; ++ks) {
            bf16x8 af[4], bfr[4];
#pragma unroll
            for (int fi = 0; fi < 4; ++fi) {
                const int r = wr + fi * 16 + rA;
                const int ch = (ks * 4 + kgrp) ^ (r & 7);
                af[fi] = *(const bf16x8*)(As + r * 64 + ch * 8);
            }
#pragma unroll
            for (int fj = 0; fj < 4; ++fj) {
                const int r = wc + fj * 16 + rA;
                const int ch = (ks * 4 + kgrp) ^ (r & 7);
                bfr[fj] = *(const bf16x8*)(Bs + r * 64 + ch * 8);
            }
#pragma unroll
            for (int fi = 0; fi < 4; ++fi)
#pragma unroll
                for (int fj = 0; fj < 4; ++fj)
                    acc[fi][fj] = __builtin_amdgcn_mfma_f32_16x16x32_bf16(
                        af[fi], bfr[fj], acc[fi][fj], 0, 0, 0);
        }
        __syncthreads();
    }

    // dump accumulators to LDS: row = batch, col = gate*32 + j
#pragma unroll
    for (int fi = 0; fi < 4; ++fi)
#pragma unroll
        for (int fj = 0; fj < 4; ++fj)
#pragma unroll
            for (int r = 0; r < 4; ++r)
                Gs[wr + fi * 16 + (lane >> 4) * 4 + r][wc + fj * 16 + (lane & 15)]
                    = acc[fi][fj][r];
    __syncthreads();

    // gate phase: thread -> (j, row group); 16 rows each
    const int j  = tid & 31;
    const int mg = tid >> 5;
#pragma unroll
    for (int mi = 0; mi < 16; ++mi) {
        const int m = mg * 16 + mi;                   // batch index
        const float* gxr = gx + ((size_t)m * TP1 + t) * G4 + hc0 + j;
        float iv = sigm(Gs[m][j]       + gxr[0]);
        float fv = sigm(Gs[m][32 + j]  + gxr[512]);
        float gv = fast_tanh(Gs[m][64 + j] + gxr[1024]);
        float ov = sigm(Gs[m][96 + j]  + gxr[1536]);
        const int ci = m * HH + hc0 + j;
        float cv = fv * cbuf[ci] + iv * gv;
        float hv = ov * fast_tanh(cv);
        cbuf[ci] = cv;
        hout[ci] = __float2bfloat16(hv);
        query[((size_t)m * TP1 + t) * HH + hc0 + j] = hv;
    }
}

// ------------------------------------------------ qw = query @ wq (NN)
__global__ __launch_bounds__(256)
void k_qw(const float* __restrict__ A, const float* __restrict__ Wq,
          float* __restrict__ C)
{
    __shared__ float As[16][68];
    __shared__ float Bs[16][68];
    const int tid = threadIdx.x;
    const int m0 = blockIdx.x * 64;
    const int n0 = blockIdx.y * 64;
    const int lak = tid & 15, lar = tid >> 4;
    const int lbc = tid & 63, lbr = tid >> 6;
    float acc[4][4] = {};
    for (int kt = 0; kt < HH; kt += 16) {
#pragma unroll
        for (int s = 0; s < 4; ++s) {
            As[lak][lar + 16 * s] = A[(size_t)(m0 + lar + 16 * s) * HH + kt + lak];
            Bs[lbr + 4 * s][lbc] = Wq[(size_t)(kt + lbr + 4 * s) * HH + n0 + lbc];
        }
        __syncthreads();
        const int ty = tid >> 4, tx = tid & 15;
#pragma unroll
        for (int k = 0; k < 16; ++k) {
            float a[4], bv[4];
#pragma unroll
            for (int i = 0; i < 4; ++i) a[i] = As[k][ty * 4 + i];
#pragma unroll
            for (int j = 0; j < 4; ++j) bv[j] = Bs[k][tx * 4 + j];
#pragma unroll
            for (int i = 0; i < 4; ++i)
#pragma unroll
                for (int j = 0; j < 4; ++j) acc[i][j] += a[i] * bv[j];
        }
        __syncthreads();
    }
    const int ty = tid >> 4, tx = tid & 15;
#pragma unroll
    for (int i = 0; i < 4; ++i)
#pragma unroll
        for (int j = 0; j < 4; ++j)
            C[(size_t)(m0 + ty * 4 + i) * HH + n0 + tx * 4 + j] = acc[i][j];
}

// -------------------- score[b,q,n] = sum_h v[h]*tanh(feat[b,n,h]+qw[b,q,h])
// wave-per-n: lane owns 8 h; butterfly reduce; no barriers
__global__ __launch_bounds__(256)
void k_score(const float* __restrict__ feat, const float* __restrict__ qw,
             const float* __restrict__ v, const int* __restrict__ msz,
             float* __restrict__ score, int masked)
{
    const int wid  = threadIdx.x >> 6;
    const int lane = threadIdx.x & 63;
    const int n = blockIdx.x * 4 + wid;
    const int b = blockIdx.y;
    if (n >= NP1) return;
    const float4* f4 = (const float4*)(feat + ((size_t)b * NP1 + n) * HH);
    const float4* v4 = (const float4*)v;
    const float4 fa = f4[lane * 2], fb = f4[lane * 2 + 1];
    const float4 va = v4[lane * 2], vb = v4[lane * 2 + 1];
    const bool nmask = masked && (n > msz[b]);
    for (int q = 0; q < TP1; ++q) {
        const float4* q4 = (const float4*)(qw + ((size_t)b * TP1 + q) * HH);
        const float4 qa = q4[lane * 2], qb = q4[lane * 2 + 1];
        float s = va.x * fast_tanh(fa.x + qa.x) + va.y * fast_tanh(fa.y + qa.y)
                + va.z * fast_tanh(fa.z + qa.z) + va.w * fast_tanh(fa.w + qa.w)
                + vb.x * fast_tanh(fb.x + qb.x) + vb.y * fast_tanh(fb.y + qb.y)
                + vb.z * fast_tanh(fb.z + qb.z) + vb.w * fast_tanh(fb.w + qb.w);
#pragma unroll
        for (int off = 32; off; off >>= 1) s += __shfl_down(s, off);
        if (lane == 0)
            score[((size_t)b * TP1 + q) * NP1 + n] = nmask ? NEGF : s;
    }
}

// ---------------- softmax over n (257) then query2 = p @ feat; block = (q,b)
__global__ __launch_bounds__(256)
void k_softpv(const float* __restrict__ score, const float* __restrict__ feat,
              float* __restrict__ outq)
{
    const int q = blockIdx.x;
    const int b = blockIdx.y;
    const int tid = threadIdx.x;
    __shared__ float p[NP1];
    __shared__ float red[4];
    const float* srow = score + ((size_t)b * TP1 + q) * NP1;
    float mx = NEGF;
    for (int n = tid; n < NP1; n += 256) mx = fmaxf(mx, srow[n]);
#pragma unroll
    for (int off = 32; off; off >>= 1) mx = fmaxf(mx, __shfl_down(mx, off));
    if ((tid & 63) == 0) red[tid >> 6] = mx;
    __syncthreads();
    mx = fmaxf(fmaxf(red[0], red[1]), fmaxf(red[2], red[3]));
    __syncthreads();
    float lsum = 0.f;
    for (int n = tid; n < NP1; n += 256) {
        float e = expf(srow[n] - mx);
        p[n] = e;
        lsum += e;
    }
#pragma unroll
    for (int off = 32; off; off >>= 1) lsum += __shfl_down(lsum, off);
    if ((tid & 63) == 0) red[tid >> 6] = lsum;
    __syncthreads();
    float inv = 1.f / (red[0] + red[1] + red[2] + red[3]);
    const float* fb = feat + (size_t)b * NP1 * HH;
    float acc0 = 0.f, acc1 = 0.f;
    for (int n = 0; n < NP1; ++n) {
        float pn = p[n] * inv;
        acc0 += pn * fb[(size_t)n * HH + tid];
        acc1 += pn * fb[(size_t)n * HH + tid + 256];
    }
    outq[((size_t)b * TP1 + q) * HH + tid] = acc0;
    outq[((size_t)b * TP1 + q) * HH + tid + 256] = acc1;
}

// ===========================================================================
extern "C" void kernel_launch(void* const* d_in, const int* in_sizes, int n_in,
                              void* d_out, int out_size, void* d_ws, size_t ws_size,
                              hipStream_t stream)
{
    const float* attn_mem  = (const float*)d_in[0];
    const float* lstm_in   = (const float*)d_in[1];
    const int*   mem_sizes = (const int*)d_in[2];
    const float* init_h    = (const float*)d_in[3];
    const float* init_c    = (const float*)d_in[4];
    const float* init_i    = (const float*)d_in[5];
    const float* stop      = (const float*)d_in[6];
    const float* w_ih      = (const float*)d_in[7];
    const float* w_hh      = (const float*)d_in[8];
    const float* b_ih      = (const float*)d_in[9];
    const float* b_hh      = (const float*)d_in[10];
    const float* attn_wm   = (const float*)d_in[11];
    const float* attn_wq   = (const float*)d_in[12];
    const float* attn_v    = (const float*)d_in[13];
    const float* hop_wm    = (const float*)d_in[14];
    const float* hop_wq    = (const float*)d_in[15];
    const float* hop_v     = (const float*)d_in[16];
    float* out = (float*)d_out;

    char* w = (char*)d_ws;
    __hip_bfloat16* Abf    = (__hip_bfloat16*)w;  w += (size_t)MTOT * DD * 2;
    __hip_bfloat16* WtH    = (__hip_bfloat16*)w;  w += (size_t)DD * HH * 2;
    __hip_bfloat16* WtA    = (__hip_bfloat16*)w;  w += (size_t)DD * HH * 2;
    __hip_bfloat16* whh_bf = (__hip_bfloat16*)w;  w += (size_t)G4 * HH * 2;
    __hip_bfloat16* h_a    = (__hip_bfloat16*)w;  w += (size_t)BB * HH * 2;
    __hip_bfloat16* h_b    = (__hip_bfloat16*)w;  w += (size_t)BB * HH * 2;
    float* feat    = (float*)w;  w += (size_t)MTOT * HH * 4;
    float* gatesx  = (float*)w;  w += (size_t)BB * TP1 * G4 * 4;
    float* query   = (float*)w;  w += (size_t)BB * TP1 * HH * 4;
    float* query2  = (float*)w;  w += (size_t)BB * TP1 * HH * 4;
    float* qw      = (float*)w;  w += (size_t)BB * TP1 * HH * 4;
    float* score   = (float*)w;  w += (size_t)BB * TP1 * NP1 * 4;
    float* cbuf    = (float*)w;  w += (size_t)BB * HH * 4;
    float* stopm_h = (float*)w;  w += HH * 4;
    float* stopm_a = (float*)w;  w += HH * 4;

    // precompute: bf16 operands + stop projections
    k_cvtA<<<dim3(MTOT), dim3(256), 0, stream>>>(attn_mem, Abf);
    k_cvtW<<<dim3(512, 2), dim3(256), 0, stream>>>(hop_wm, attn_wm, WtH, WtA);
    k_cvtWhh<<<dim3(4096), dim3(256), 0, stream>>>(w_hh, whh_bf);
    k_stopm<<<dim3(4), dim3(256), 0, stream>>>(stop, hop_wm, attn_wm, stopm_h, stopm_a);

    // hop_feat (MFMA)
    k_feat_mfma<<<dim3(257, 4), dim3(256), 0, stream>>>(Abf, WtH, stopm_h, mem_sizes, feat);

    // LSTM: hoisted input gates + 9 fused MFMA steps (h ping-pong bf16)
    k_xgates<<<dim3(18, 32), dim3(256), 0, stream>>>(lstm_in, init_i, w_ih, b_ih, b_hh, gatesx);
    k_init<<<dim3(256), dim3(256), 0, stream>>>(init_h, init_c, h_a, cbuf);
    for (int t = 0; t < TP1; ++t) {
        const __hip_bfloat16* hin = (t & 1) ? h_b : h_a;
        __hip_bfloat16*      hout = (t & 1) ? h_a : h_b;
        k_lstm<<<dim3(16), dim3(256), 0, stream>>>(hin, whh_bf, gatesx, cbuf, hout, query, t);
    }

    // hop attention (masked) -> query2
    k_qw<<<dim3(18, 8), dim3(256), 0, stream>>>(query, hop_wq, qw);
    k_score<<<dim3(65, 128), dim3(256), 0, stream>>>(feat, qw, hop_v, mem_sizes, score, 1);
    k_softpv<<<dim3(9, 128), dim3(256), 0, stream>>>(score, feat, query2);

    // final pointer scores (unmasked) -> d_out
    k_qw<<<dim3(18, 8), dim3(256), 0, stream>>>(query2, attn_wq, qw);
    k_feat_mfma<<<dim3(257, 4), dim3(256), 0, stream>>>(Abf, WtA, stopm_a, mem_sizes, feat);
    k_score<<<dim3(65, 128), dim3(256), 0, stream>>>(feat, qw, attn_v, mem_sizes, out, 0);
}

// Round 4
// 438.897 us; speedup vs baseline: 3.2954x; 1.2564x over previous
//
#include <hip/hip_runtime.h>
#include <hip/hip_bf16.h>
#include <math.h>

#define BB   128
#define NPTS 256
#define NP1  257
#define DD   512
#define HH   512
#define G4   2048
#define TP1  9
#define NEGF -1e18f
#define MTOT (BB * NP1)   // 32896

typedef __attribute__((ext_vector_type(8))) short bf16x8;
typedef __attribute__((ext_vector_type(8))) unsigned short u16x8;
typedef __attribute__((ext_vector_type(4))) float f32x4;

__device__ __forceinline__ float bf2f(unsigned short u)
{
    union { unsigned int i; float f; } x;
    x.i = (unsigned int)u << 16;
    return x.f;
}

__device__ __forceinline__ float sigm(float x)
{
    return __builtin_amdgcn_rcpf(1.0f + __builtin_amdgcn_exp2f(-x * 1.4426950408889634f));
}

// tanh(x) = 1 - 2/(e^{2x}+1) via v_exp_f32: ~5 VALU ops, exact at +-inf
__device__ __forceinline__ float fast_tanh(float x)
{
    float e = __builtin_amdgcn_exp2f(x * 2.8853900817779268f);  // 2*log2(e)
    return 1.0f - 2.0f * __builtin_amdgcn_rcpf(e + 1.0f);
}

__device__ __forceinline__ void gl_lds16(const __hip_bfloat16* g, __hip_bfloat16* l)
{
    __builtin_amdgcn_global_load_lds(
        (const __attribute__((address_space(1))) void*)g,
        (__attribute__((address_space(3))) void*)l, 16, 0, 0);
}

// ---------------------------------------------------------------- stop @ wm
__global__ void k_stopm(const float* __restrict__ stop,
                        const float* __restrict__ wmh,
                        const float* __restrict__ wma,
                        float* __restrict__ smh,
                        float* __restrict__ sma)
{
    int g = blockIdx.x * 256 + threadIdx.x;       // 0..1023
    const float* wm = (g < HH) ? wmh : wma;
    float* out      = (g < HH) ? smh : sma;
    int h = g & (HH - 1);
    float acc = 0.f;
    for (int k = 0; k < DD; ++k) acc += stop[k] * wm[k * HH + h];
    out[h] = acc;
}

// ---------------------------------------------------------------- bias sum
__global__ void k_bias(const float* __restrict__ b_ih, const float* __restrict__ b_hh,
                       float* __restrict__ bsum)
{
    int i = blockIdx.x * 256 + threadIdx.x;       // 2048
    bsum[i] = b_ih[i] + b_hh[i];
}

// ------------------------------------- attn_mem (+zero stop row) -> bf16
__global__ void k_cvtA(const float* __restrict__ Amem,
                       __hip_bfloat16* __restrict__ Abf)
{
    const int m = blockIdx.x;                 // 0..32895
    const int b = m / NP1;
    const int n = m - b * NP1;
    const int t = threadIdx.x;                // 0..255, 2 cols each
    float2 v = make_float2(0.f, 0.f);
    if (n < NPTS)
        v = *(const float2*)(Amem + ((size_t)(b * NPTS + n)) * DD + 2 * t);
    __hip_bfloat16* o = Abf + (size_t)m * DD + 2 * t;
    o[0] = __float2bfloat16(v.x);
    o[1] = __float2bfloat16(v.y);
}

// ------------------------------------- x rows (init_i / lstm_in) -> bf16
__global__ void k_cvtX(const float* __restrict__ lstm_in,
                       const float* __restrict__ init_i,
                       __hip_bfloat16* __restrict__ Xbf)
{
    const int m = blockIdx.x;                 // 0..1151 (b*9+t)
    const int b = m / TP1;
    const int t = m - b * TP1;
    const float* src = (t == 0) ? init_i : (lstm_in + (size_t)(b * 8 + (t - 1)) * DD);
    const int tid = threadIdx.x;
    float2 v = *(const float2*)(src + 2 * tid);
    __hip_bfloat16* o = Xbf + (size_t)m * DD + 2 * tid;
    o[0] = __float2bfloat16(v.x);
    o[1] = __float2bfloat16(v.y);
}

// ------------------------------------- Wt[n][k] = bf16(W[k][n]) for 2 weights
__global__ void k_cvtW(const float* __restrict__ Wh, const float* __restrict__ Wa,
                       __hip_bfloat16* __restrict__ WtH, __hip_bfloat16* __restrict__ WtA)
{
    const float* W = blockIdx.y ? Wa : Wh;
    __hip_bfloat16* O = blockIdx.y ? WtA : WtH;
    const int n = blockIdx.x;                 // 0..511
    const int t = threadIdx.x;                // 0..255
    O[(size_t)n * DD + t]       = __float2bfloat16(W[(size_t)t * HH + n]);
    O[(size_t)n * DD + t + 256] = __float2bfloat16(W[(size_t)(t + 256) * HH + n]);
}

// ------------------------------------- row-major fp32 -> bf16 (1M elems)
__global__ void k_cvt1m(const float* __restrict__ w, __hip_bfloat16* __restrict__ o)
{
    int idx = blockIdx.x * 256 + threadIdx.x;
    o[idx] = __float2bfloat16(w[idx]);
}

// ---------------------------------------------- feat = Abf @ WtT  (MFMA bf16)
// out bf16; stop row add in epilogue
__global__ __launch_bounds__(256)
void k_feat_mfma(const __hip_bfloat16* __restrict__ A,
                 const __hip_bfloat16* __restrict__ Bt,
                 const float* __restrict__ stopm,
                 const int* __restrict__ msz,
                 __hip_bfloat16* __restrict__ C)
{
    __shared__ __align__(16) __hip_bfloat16 As[128 * 64];
    __shared__ __align__(16) __hip_bfloat16 Bs[128 * 64];
    const int tid  = threadIdx.x;
    const int lane = tid & 63;
    const int wid  = tid >> 6;
    const int m0 = blockIdx.x * 128;
    const int n0 = blockIdx.y * 128;
    const int wr = (wid >> 1) * 64;
    const int wc = (wid & 1) * 64;

    const __hip_bfloat16* aptr[4];
    const __hip_bfloat16* bptr[4];
    int ldsoff[4];
#pragma unroll
    for (int s = 0; s < 4; ++s) {
        const int si = wid * 4 + s;
        const int o = si * 1024 + lane * 16;
        const int row = o >> 7;
        const int chunk = (o >> 4) & 7;
        const int sch = chunk ^ (row & 7);
        aptr[s] = A + (size_t)(m0 + row) * DD + sch * 8;
        bptr[s] = Bt + (size_t)(n0 + row) * DD + sch * 8;
        ldsoff[s] = si * 512;
    }

    f32x4 acc[4][4];
#pragma unroll
    for (int i = 0; i < 4; ++i)
#pragma unroll
        for (int j = 0; j < 4; ++j) acc[i][j] = (f32x4){0.f, 0.f, 0.f, 0.f};

    const int rA = lane & 15;
    const int kgrp = lane >> 4;

    for (int kt = 0; kt < DD; kt += 64) {
#pragma unroll
        for (int s = 0; s < 4; ++s) gl_lds16(aptr[s] + kt, As + ldsoff[s]);
#pragma unroll
        for (int s = 0; s < 4; ++s) gl_lds16(bptr[s] + kt, Bs + ldsoff[s]);
        __syncthreads();

#pragma unroll
        for (int ks = 0; ks < 2; ++ks) {
            bf16x8 af[4], bfr[4];
#pragma unroll
            for (int fi = 0; fi < 4; ++fi) {
                const int r = wr + fi * 16 + rA;
                const int ch = (ks * 4 + kgrp) ^ (r & 7);
                af[fi] = *(const bf16x8*)(As + r * 64 + ch * 8);
            }
#pragma unroll
            for (int fj = 0; fj < 4; ++fj) {
                const int r = wc + fj * 16 + rA;
                const int ch = (ks * 4 + kgrp) ^ (r & 7);
                bfr[fj] = *(const bf16x8*)(Bs + r * 64 + ch * 8);
            }
#pragma unroll
            for (int fi = 0; fi < 4; ++fi)
#pragma unroll
                for (int fj = 0; fj < 4; ++fj)
                    acc[fi][fj] = __builtin_amdgcn_mfma_f32_16x16x32_bf16(
                        af[fi], bfr[fj], acc[fi][fj], 0, 0, 0);
        }
        __syncthreads();
    }

#pragma unroll
    for (int fi = 0; fi < 4; ++fi) {
#pragma unroll
        for (int r = 0; r < 4; ++r) {
            const int m = m0 + wr + fi * 16 + (lane >> 4) * 4 + r;
            const int b = m / NP1;
            const int n = m - b * NP1;
            const bool addstop = (n == msz[b]);
#pragma unroll
            for (int fj = 0; fj < 4; ++fj) {
                const int h = n0 + wc + fj * 16 + (lane & 15);
                float v = acc[fi][fj][r];
                if (addstop) v += stopm[h];
                C[(size_t)m * HH + h] = __float2bfloat16(v);
            }
        }
    }
}

// ---------------------------- generic C = A @ Bt^T (MFMA bf16, fp32 out)
// A [M][512] bf16, Bt [N][512] bf16, C [M][ldc] fp32 (+ optional bias[h])
__global__ __launch_bounds__(256)
void k_gemm_bt(const __hip_bfloat16* __restrict__ A,
               const __hip_bfloat16* __restrict__ Bt,
               const float* __restrict__ bias,
               float* __restrict__ C, int ldc)
{
    __shared__ __align__(16) __hip_bfloat16 As[128 * 64];
    __shared__ __align__(16) __hip_bfloat16 Bs[128 * 64];
    const int tid  = threadIdx.x;
    const int lane = tid & 63;
    const int wid  = tid >> 6;
    const int m0 = blockIdx.x * 128;
    const int n0 = blockIdx.y * 128;
    const int wr = (wid >> 1) * 64;
    const int wc = (wid & 1) * 64;

    const __hip_bfloat16* aptr[4];
    const __hip_bfloat16* bptr[4];
    int ldsoff[4];
#pragma unroll
    for (int s = 0; s < 4; ++s) {
        const int si = wid * 4 + s;
        const int o = si * 1024 + lane * 16;
        const int row = o >> 7;
        const int chunk = (o >> 4) & 7;
        const int sch = chunk ^ (row & 7);
        aptr[s] = A + (size_t)(m0 + row) * DD + sch * 8;
        bptr[s] = Bt + (size_t)(n0 + row) * DD + sch * 8;
        ldsoff[s] = si * 512;
    }

    f32x4 acc[4][4];
#pragma unroll
    for (int i = 0; i < 4; ++i)
#pragma unroll
        for (int j = 0; j < 4; ++j) acc[i][j] = (f32x4){0.f, 0.f, 0.f, 0.f};

    const int rA = lane & 15;
    const int kgrp = lane >> 4;

    for (int kt = 0; kt < DD; kt += 64) {
#pragma unroll
        for (int s = 0; s < 4; ++s) gl_lds16(aptr[s] + kt, As + ldsoff[s]);
#pragma unroll
        for (int s = 0; s < 4; ++s) gl_lds16(bptr[s] + kt, Bs + ldsoff[s]);
        __syncthreads();
#pragma unroll
        for (int ks = 0; ks < 2; ++ks) {
            bf16x8 af[4], bfr[4];
#pragma unroll
            for (int fi = 0; fi < 4; ++fi) {
                const int r = wr + fi * 16 + rA;
                const int ch = (ks * 4 + kgrp) ^ (r & 7);
                af[fi] = *(const bf16x8*)(As + r * 64 + ch * 8);
            }
#pragma unroll
            for (int fj = 0; fj < 4; ++fj) {
                const int r = wc + fj * 16 + rA;
                const int ch = (ks * 4 + kgrp) ^ (r & 7);
                bfr[fj] = *(const bf16x8*)(Bs + r * 64 + ch * 8);
            }
#pragma unroll
            for (int fi = 0; fi < 4; ++fi)
#pragma unroll
                for (int fj = 0; fj < 4; ++fj)
                    acc[fi][fj] = __builtin_amdgcn_mfma_f32_16x16x32_bf16(
                        af[fi], bfr[fj], acc[fi][fj], 0, 0, 0);
        }
        __syncthreads();
    }

#pragma unroll
    for (int fi = 0; fi < 4; ++fi) {
#pragma unroll
        for (int r = 0; r < 4; ++r) {
            const int m = m0 + wr + fi * 16 + (lane >> 4) * 4 + r;
#pragma unroll
            for (int fj = 0; fj < 4; ++fj) {
                const int h = n0 + wc + fj * 16 + (lane & 15);
                float v = acc[fi][fj][r];
                if (bias) v += bias[h];
                C[(size_t)m * ldc + h] = v;
            }
        }
    }
}

// ------------------------------------------------------------- init h, c
__global__ void k_init(const float* __restrict__ ih, const float* __restrict__ ic,
                       __hip_bfloat16* __restrict__ h, float* __restrict__ c)
{
    int idx = blockIdx.x * 256 + threadIdx.x;     // B*H
    int i = idx & (HH - 1);
    h[idx] = __float2bfloat16(ih[i]);
    c[idx] = ic[i];
}

// ---------------- fused LSTM step: g = h@w_hh^T (MFMA) + gx; cell; h out
__global__ __launch_bounds__(256)
void k_lstm(const __hip_bfloat16* __restrict__ hin,   // [128][512]
            const __hip_bfloat16* __restrict__ whh,   // [2048][512]
            const float* __restrict__ gx,             // [1152][2048]
            float* __restrict__ cbuf,                 // [128][512]
            __hip_bfloat16* __restrict__ hout,        // [128][512]
            __hip_bfloat16* __restrict__ query,       // [1152][512] bf16
            int t)
{
    __shared__ __align__(16) __hip_bfloat16 As[128 * 64];
    __shared__ __align__(16) __hip_bfloat16 Bs[128 * 64];
    __shared__ float Gs[128][132];
    const int tid  = threadIdx.x;
    const int lane = tid & 63;
    const int wid  = tid >> 6;
    const int hc0  = blockIdx.x * 32;
    const int wr = (wid >> 1) * 64;
    const int wc = (wid & 1) * 64;

    const __hip_bfloat16* aptr[4];
    const __hip_bfloat16* bptr[4];
    int ldsoff[4];
#pragma unroll
    for (int s = 0; s < 4; ++s) {
        const int si = wid * 4 + s;
        const int o = si * 1024 + lane * 16;
        const int row = o >> 7;
        const int chunk = (o >> 4) & 7;
        const int sch = chunk ^ (row & 7);
        aptr[s] = hin + (size_t)row * HH + sch * 8;
        const int brow = (row >> 5) * 512 + hc0 + (row & 31);
        bptr[s] = whh + (size_t)brow * HH + sch * 8;
        ldsoff[s] = si * 512;
    }

    f32x4 acc[4][4];
#pragma unroll
    for (int i = 0; i < 4; ++i)
#pragma unroll
        for (int j = 0; j < 4; ++j) acc[i][j] = (f32x4){0.f, 0.f, 0.f, 0.f};

    const int rA = lane & 15;
    const int kgrp = lane >> 4;

    for (int kt = 0; kt < HH; kt += 64) {
#pragma unroll
        for (int s = 0; s < 4; ++s) gl_lds16(aptr[s] + kt, As + ldsoff[s]);
#pragma unroll
        for (int s = 0; s < 4; ++s) gl_lds16(bptr[s] + kt, Bs + ldsoff[s]);
        __syncthreads();
#pragma unroll
        for (int ks = 0; ks < 2; ++ks) {
            bf16x8 af[4], bfr[4];
#pragma unroll
            for (int fi = 0; fi < 4; ++fi) {
                const int r = wr + fi * 16 + rA;
                const int ch = (ks * 4 + kgrp) ^ (r & 7);
                af[fi] = *(const bf16x8*)(As + r * 64 + ch * 8);
            }
#pragma unroll
            for (int fj = 0; fj < 4; ++fj) {
                const int r = wc + fj * 16 + rA;
                const int ch = (ks * 4 + kgrp) ^ (r & 7);
                bfr[fj] = *(const bf16x8*)(Bs + r * 64 + ch * 8);
            }
#pragma unroll
            for (int fi = 0; fi < 4; ++fi)
#pragma unroll
                for (int fj = 0; fj < 4; ++fj)
                    acc[fi][fj] = __builtin_amdgcn_mfma_f32_16x16x32_bf16(
                        af[fi], bfr[fj], acc[fi][fj], 0, 0, 0);
        }
        __syncthreads();
    }

#pragma unroll
    for (int fi = 0; fi < 4; ++fi)
#pragma unroll
        for (int fj = 0; fj < 4; ++fj)
#pragma unroll
            for (int r = 0; r < 4; ++r)
                Gs[wr + fi * 16 + (lane >> 4) * 4 + r][wc + fj * 16 + (lane & 15)]
                    = acc[fi][fj][r];
    __syncthreads();

    const int j  = tid & 31;
    const int mg = tid >> 5;
#pragma unroll
    for (int mi = 0; mi < 16; ++mi) {
        const int m = mg * 16 + mi;
        const float* gxr = gx + ((size_t)m * TP1 + t) * G4 + hc0 + j;
        float iv = sigm(Gs[m][j]       + gxr[0]);
        float fv = sigm(Gs[m][32 + j]  + gxr[512]);
        float gv = fast_tanh(Gs[m][64 + j] + gxr[1024]);
        float ov = sigm(Gs[m][96 + j]  + gxr[1536]);
        const int ci = m * HH + hc0 + j;
        float cv = fv * cbuf[ci] + iv * gv;
        float hv = ov * fast_tanh(cv);
        cbuf[ci] = cv;
        hout[ci] = __float2bfloat16(hv);
        query[((size_t)m * TP1 + t) * HH + hc0 + j] = __float2bfloat16(hv);
    }
}

// -------------------- score[b,q,n] = sum_h v[h]*tanh(feat[b,n,h]+qw[b,q,h])
// wave-per-n: lane owns 8 h (one 16B bf16 load); butterfly reduce
__global__ __launch_bounds__(256)
void k_score(const __hip_bfloat16* __restrict__ feat, const float* __restrict__ qw,
             const float* __restrict__ v, const int* __restrict__ msz,
             float* __restrict__ score, int masked)
{
    const int wid  = threadIdx.x >> 6;
    const int lane = threadIdx.x & 63;
    const int n = blockIdx.x * 4 + wid;
    const int b = blockIdx.y;
    if (n >= NP1) return;
    const u16x8 fu = *(const u16x8*)((const unsigned short*)feat
                                     + ((size_t)b * NP1 + n) * HH + lane * 8);
    float f[8];
#pragma unroll
    for (int i = 0; i < 8; ++i) f[i] = bf2f(fu[i]);
    const float4* v4 = (const float4*)v;
    const float4 va = v4[lane * 2], vb = v4[lane * 2 + 1];
    const bool nmask = masked && (n > msz[b]);
    for (int q = 0; q < TP1; ++q) {
        const float4* q4 = (const float4*)(qw + ((size_t)b * TP1 + q) * HH);
        const float4 qa = q4[lane * 2], qb = q4[lane * 2 + 1];
        float s = va.x * fast_tanh(f[0] + qa.x) + va.y * fast_tanh(f[1] + qa.y)
                + va.z * fast_tanh(f[2] + qa.z) + va.w * fast_tanh(f[3] + qa.w)
                + vb.x * fast_tanh(f[4] + qb.x) + vb.y * fast_tanh(f[5] + qb.y)
                + vb.z * fast_tanh(f[6] + qb.z) + vb.w * fast_tanh(f[7] + qb.w);
#pragma unroll
        for (int off = 32; off; off >>= 1) s += __shfl_down(s, off);
        if (lane == 0)
            score[((size_t)b * TP1 + q) * NP1 + n] = nmask ? NEGF : s;
    }
}

// ------- softmax over n for all 9 q, then query2 = p @ feat (feat read ONCE)
// grid (B, 2): block owns batch b, column half ch. query2 out bf16.
__global__ __launch_bounds__(256)
void k_softpv(const float* __restrict__ score, const __hip_bfloat16* __restrict__ feat,
              __hip_bfloat16* __restrict__ outq)
{
    const int b   = blockIdx.x;
    const int ch  = blockIdx.y;
    const int tid = threadIdx.x;
    const int lane = tid & 63, wid = tid >> 6;
    __shared__ float p[TP1][NP1 + 3];
    __shared__ float comb[TP1][256];

    // phase 1: wave w computes softmax rows q = w, w+4, w+8
    const float* sb = score + (size_t)b * TP1 * NP1;
    for (int q = wid; q < TP1; q += 4) {
        const float* srow = sb + q * NP1;
        float mx = NEGF;
        for (int n = lane; n < NP1; n += 64) mx = fmaxf(mx, srow[n]);
#pragma unroll
        for (int off = 32; off; off >>= 1) mx = fmaxf(mx, __shfl_xor(mx, off));
        float sum = 0.f;
        for (int n = lane; n < NP1; n += 64) {
            float e = __builtin_amdgcn_exp2f((srow[n] - mx) * 1.4426950408889634f);
            p[q][n] = e;
            sum += e;
        }
#pragma unroll
        for (int off = 32; off; off >>= 1) sum += __shfl_xor(sum, off);
        float inv = 1.f / sum;
        for (int n = lane; n < NP1; n += 64) p[q][n] *= inv;
    }
    __syncthreads();

    // phase 2: thread owns 2 cols, n split 2-way across thread halves
    const int ng = tid >> 7;
    const int tc = tid & 127;
    const int col = ch * 256 + tc * 2;
    const unsigned short* fb = (const unsigned short*)feat + (size_t)b * NP1 * HH + col;
    float a0[TP1] = {}, a1[TP1] = {};
    for (int n = ng; n < NP1; n += 2) {
        const unsigned int u = *(const unsigned int*)(fb + (size_t)n * HH);
        const float f0 = bf2f((unsigned short)(u & 0xffffu));
        const float f1 = bf2f((unsigned short)(u >> 16));
#pragma unroll
        for (int q = 0; q < TP1; ++q) {
            const float pq = p[q][n];
            a0[q] += pq * f0;
            a1[q] += pq * f1;
        }
    }
    if (ng == 1) {
#pragma unroll
        for (int q = 0; q < TP1; ++q) {
            comb[q][tc * 2]     = a0[q];
            comb[q][tc * 2 + 1] = a1[q];
        }
    }
    __syncthreads();
    if (ng == 0) {
        __hip_bfloat16* oq = outq + (size_t)(b * TP1) * HH + col;
#pragma unroll
        for (int q = 0; q < TP1; ++q) {
            oq[(size_t)q * HH]     = __float2bfloat16(a0[q] + comb[q][tc * 2]);
            oq[(size_t)q * HH + 1] = __float2bfloat16(a1[q] + comb[q][tc * 2 + 1]);
        }
    }
}

// ===========================================================================
extern "C" void kernel_launch(void* const* d_in, const int* in_sizes, int n_in,
                              void* d_out, int out_size, void* d_ws, size_t ws_size,
                              hipStream_t stream)
{
    const float* attn_mem  = (const float*)d_in[0];
    const float* lstm_in   = (const float*)d_in[1];
    const int*   mem_sizes = (const int*)d_in[2];
    const float* init_h    = (const float*)d_in[3];
    const float* init_c    = (const float*)d_in[4];
    const float* init_i    = (const float*)d_in[5];
    const float* stop      = (const float*)d_in[6];
    const float* w_ih      = (const float*)d_in[7];
    const float* w_hh      = (const float*)d_in[8];
    const float* b_ih      = (const float*)d_in[9];
    const float* b_hh      = (const float*)d_in[10];
    const float* attn_wm   = (const float*)d_in[11];
    const float* attn_wq   = (const float*)d_in[12];
    const float* attn_v    = (const float*)d_in[13];
    const float* hop_wm    = (const float*)d_in[14];
    const float* hop_wq    = (const float*)d_in[15];
    const float* hop_v     = (const float*)d_in[16];
    float* out = (float*)d_out;

    char* w = (char*)d_ws;
    __hip_bfloat16* Abf    = (__hip_bfloat16*)w;  w += (size_t)MTOT * DD * 2;   // 33.7 MB
    __hip_bfloat16* feat   = (__hip_bfloat16*)w;  w += (size_t)MTOT * HH * 2;   // 33.7 MB
    __hip_bfloat16* Xbf    = (__hip_bfloat16*)w;  w += (size_t)BB * TP1 * DD * 2;
    __hip_bfloat16* WtH    = (__hip_bfloat16*)w;  w += (size_t)DD * HH * 2;
    __hip_bfloat16* WtA    = (__hip_bfloat16*)w;  w += (size_t)DD * HH * 2;
    __hip_bfloat16* WqtH   = (__hip_bfloat16*)w;  w += (size_t)HH * HH * 2;
    __hip_bfloat16* WqtA   = (__hip_bfloat16*)w;  w += (size_t)HH * HH * 2;
    __hip_bfloat16* wih_bf = (__hip_bfloat16*)w;  w += (size_t)G4 * DD * 2;
    __hip_bfloat16* whh_bf = (__hip_bfloat16*)w;  w += (size_t)G4 * HH * 2;
    __hip_bfloat16* h_a    = (__hip_bfloat16*)w;  w += (size_t)BB * HH * 2;
    __hip_bfloat16* h_b    = (__hip_bfloat16*)w;  w += (size_t)BB * HH * 2;
    __hip_bfloat16* query  = (__hip_bfloat16*)w;  w += (size_t)BB * TP1 * HH * 2;
    __hip_bfloat16* query2 = (__hip_bfloat16*)w;  w += (size_t)BB * TP1 * HH * 2;
    float* gatesx  = (float*)w;  w += (size_t)BB * TP1 * G4 * 4;                // 9.4 MB
    float* qw      = (float*)w;  w += (size_t)BB * TP1 * HH * 4;
    float* score   = (float*)w;  w += (size_t)BB * TP1 * NP1 * 4;
    float* cbuf    = (float*)w;  w += (size_t)BB * HH * 4;
    float* stopm_h = (float*)w;  w += HH * 4;
    float* stopm_a = (float*)w;  w += HH * 4;
    float* bsum    = (float*)w;  w += G4 * 4;

    // precompute: bf16 operands + stop projections + bias sum
    k_cvtA<<<dim3(MTOT), dim3(256), 0, stream>>>(attn_mem, Abf);
    k_cvtX<<<dim3(BB * TP1), dim3(256), 0, stream>>>(lstm_in, init_i, Xbf);
    k_cvtW<<<dim3(512, 2), dim3(256), 0, stream>>>(hop_wm, attn_wm, WtH, WtA);
    k_cvtW<<<dim3(512, 2), dim3(256), 0, stream>>>(hop_wq, attn_wq, WqtH, WqtA);
    k_cvt1m<<<dim3(4096), dim3(256), 0, stream>>>(w_ih, wih_bf);
    k_cvt1m<<<dim3(4096), dim3(256), 0, stream>>>(w_hh, whh_bf);
    k_bias<<<dim3(8), dim3(256), 0, stream>>>(b_ih, b_hh, bsum);
    k_stopm<<<dim3(4), dim3(256), 0, stream>>>(stop, hop_wm, attn_wm, stopm_h, stopm_a);

    // hop_feat (MFMA, bf16 out)
    k_feat_mfma<<<dim3(257, 4), dim3(256), 0, stream>>>(Abf, WtH, stopm_h, mem_sizes, feat);

    // LSTM: MFMA input-gates + 9 fused MFMA steps
    k_gemm_bt<<<dim3(9, 16), dim3(256), 0, stream>>>(Xbf, wih_bf, bsum, gatesx, G4);
    k_init<<<dim3(256), dim3(256), 0, stream>>>(init_h, init_c, h_a, cbuf);
    for (int t = 0; t < TP1; ++t) {
        const __hip_bfloat16* hin = (t & 1) ? h_b : h_a;
        __hip_bfloat16*      hout = (t & 1) ? h_a : h_b;
        k_lstm<<<dim3(16), dim3(256), 0, stream>>>(hin, whh_bf, gatesx, cbuf, hout, query, t);
    }

    // hop attention (masked) -> query2 (bf16)
    k_gemm_bt<<<dim3(9, 4), dim3(256), 0, stream>>>(query, WqtH, nullptr, qw, HH);
    k_score<<<dim3(65, 128), dim3(256), 0, stream>>>(feat, qw, hop_v, mem_sizes, score, 1);
    k_softpv<<<dim3(128, 2), dim3(256), 0, stream>>>(score, feat, query2);

    // final pointer scores (unmasked) -> d_out
    k_gemm_bt<<<dim3(9, 4), dim3(256), 0, stream>>>(query2, WqtA, nullptr, qw, HH);
    k_feat_mfma<<<dim3(257, 4), dim3(256), 0, stream>>>(Abf, WtA, stopm_a, mem_sizes, feat);
    k_score<<<dim3(65, 128), dim3(256), 0, stream>>>(feat, qw, attn_v, mem_sizes, out, 0);
}

// Round 5
// 375.409 us; speedup vs baseline: 3.8527x; 1.1691x over previous
//
#include <hip/hip_runtime.h>
#include <hip/hip_bf16.h>
#include <math.h>

#define BB   128
#define NPTS 256
#define NP1  257
#define DD   512
#define HH   512
#define G4   2048
#define TP1  9
#define NEGF -1e18f
#define MTOT (BB * NP1)   // 32896
#define CSC  2.8853900817779268f   // 2*log2(e): tanh(x) = 1 - 2/(exp2(CSC*x)+1)
#define L2E  1.4426950408889634f

typedef __attribute__((ext_vector_type(8))) short bf16x8;
typedef __attribute__((ext_vector_type(8))) unsigned short u16x8;
typedef __attribute__((ext_vector_type(4))) float f32x4;

__device__ __forceinline__ float bf2f(unsigned short u)
{
    union { unsigned int i; float f; } x;
    x.i = (unsigned int)u << 16;
    return x.f;
}

__device__ __forceinline__ float sigm(float x)
{
    return __builtin_amdgcn_rcpf(1.0f + __builtin_amdgcn_exp2f(-x * L2E));
}

__device__ __forceinline__ float fast_tanh(float x)
{
    float e = __builtin_amdgcn_exp2f(x * CSC);
    return 1.0f - 2.0f * __builtin_amdgcn_rcpf(e + 1.0f);
}

__device__ __forceinline__ void gl_lds16(const __hip_bfloat16* g, __hip_bfloat16* l)
{
    __builtin_amdgcn_global_load_lds(
        (const __attribute__((address_space(1))) void*)g,
        (__attribute__((address_space(3))) void*)l, 16, 0, 0);
}

// ---------------------------------------------------------------- prep (all small conversions)
// blocks: [0,1024) Wt2 | [1024,2048) Wqt | [2048,4096) wih | [4096,6144) whh
//         [6144] bsum | [6145,6149) stopm2 | [6149,7301) Xbf | [7301,7557) init h,c
__global__ __launch_bounds__(256)
void k_prep(const float* __restrict__ hop_wm, const float* __restrict__ attn_wm,
            const float* __restrict__ hop_wq, const float* __restrict__ attn_wq,
            const float* __restrict__ w_ih, const float* __restrict__ w_hh,
            const float* __restrict__ b_ih, const float* __restrict__ b_hh,
            const float* __restrict__ stop, const float* __restrict__ lstm_in,
            const float* __restrict__ init_i, const float* __restrict__ init_h,
            const float* __restrict__ init_c,
            __hip_bfloat16* __restrict__ Wt2, __hip_bfloat16* __restrict__ WqtH,
            __hip_bfloat16* __restrict__ WqtA, __hip_bfloat16* __restrict__ wih_bf,
            __hip_bfloat16* __restrict__ whh_bf, float* __restrict__ bsum,
            float* __restrict__ stopm2, __hip_bfloat16* __restrict__ Xbf,
            __hip_bfloat16* __restrict__ h_a, float* __restrict__ cbuf)
{
    const int x = blockIdx.x, t = threadIdx.x;
    if (x < 1024) {                       // Wt2[n][k] = CSC * wm[k][n]
        const float* W = (x < 512) ? hop_wm : attn_wm;
        const int col = x & 511;
        Wt2[(size_t)x * DD + t]       = __float2bfloat16(CSC * W[(size_t)t * HH + col]);
        Wt2[(size_t)x * DD + t + 256] = __float2bfloat16(CSC * W[(size_t)(t + 256) * HH + col]);
    } else if (x < 2048) {                // WqtH (xCSC) / WqtA (no scale)
        const int j = x - 1024;
        if (j < 512) {
            WqtH[(size_t)j * DD + t]       = __float2bfloat16(CSC * hop_wq[(size_t)t * HH + j]);
            WqtH[(size_t)j * DD + t + 256] = __float2bfloat16(CSC * hop_wq[(size_t)(t + 256) * HH + j]);
        } else {
            const int jj = j - 512;
            WqtA[(size_t)jj * DD + t]       = __float2bfloat16(attn_wq[(size_t)t * HH + jj]);
            WqtA[(size_t)jj * DD + t + 256] = __float2bfloat16(attn_wq[(size_t)(t + 256) * HH + jj]);
        }
    } else if (x < 4096) {                // wih bf16
        const size_t r = (size_t)(x - 2048) * DD;
        wih_bf[r + t]       = __float2bfloat16(w_ih[r + t]);
        wih_bf[r + t + 256] = __float2bfloat16(w_ih[r + t + 256]);
    } else if (x < 6144) {                // whh bf16
        const size_t r = (size_t)(x - 4096) * DD;
        whh_bf[r + t]       = __float2bfloat16(w_hh[r + t]);
        whh_bf[r + t + 256] = __float2bfloat16(w_hh[r + t + 256]);
    } else if (x == 6144) {               // bias sum
#pragma unroll
        for (int i = 0; i < 8; ++i) {
            const int idx = t + 256 * i;
            bsum[idx] = b_ih[idx] + b_hh[idx];
        }
    } else if (x < 6149) {                // stopm2[h] = CSC * stop @ wm[:,h]
        const int h = (x - 6145) * 256 + t;
        const float* W = (h < 512) ? hop_wm : attn_wm;
        const int col = h & 511;
        float a = 0.f;
        for (int k = 0; k < DD; ++k) a += stop[k] * W[(size_t)k * HH + col];
        stopm2[h] = CSC * a;
    } else if (x < 7301) {                // Xbf rows
        const int m = x - 6149;
        const int bb = m / TP1, tt = m - bb * TP1;
        const float* src = (tt == 0) ? init_i : (lstm_in + (size_t)(bb * 8 + tt - 1) * DD);
        float2 vv = *(const float2*)(src + 2 * t);
        __hip_bfloat16* o = Xbf + (size_t)m * DD + 2 * t;
        o[0] = __float2bfloat16(vv.x);
        o[1] = __float2bfloat16(vv.y);
    } else {                              // init h, c
        const int idx = (x - 7301) * 256 + t;
        h_a[idx]  = __float2bfloat16(init_h[idx & (HH - 1)]);
        cbuf[idx] = init_c[idx & (HH - 1)];
    }
}

// ------------------------------------- attn_mem (+zero stop row) -> bf16
__global__ void k_cvtA(const float* __restrict__ Amem,
                       __hip_bfloat16* __restrict__ Abf)
{
    const int m = blockIdx.x;
    const int b = m / NP1;
    const int n = m - b * NP1;
    const int t = threadIdx.x;
    float2 v = make_float2(0.f, 0.f);
    if (n < NPTS)
        v = *(const float2*)(Amem + ((size_t)(b * NPTS + n)) * DD + 2 * t);
    __hip_bfloat16* o = Abf + (size_t)m * DD + 2 * t;
    o[0] = __float2bfloat16(v.x);
    o[1] = __float2bfloat16(v.y);
}

// ------------------- E2[m][h] = exp2(CSC*feat)  (merged hop|attn, MFMA bf16)
// A [32896][512] bf16, Wt2 [1024][512] bf16 (pre-scaled), E2 [32896][1024] bf16
__global__ __launch_bounds__(256)
void k_feat2(const __hip_bfloat16* __restrict__ A,
             const __hip_bfloat16* __restrict__ Bt,
             const float* __restrict__ stopm2,
             const int* __restrict__ msz,
             __hip_bfloat16* __restrict__ E2)
{
    __shared__ __align__(16) __hip_bfloat16 As[128 * 64];
    __shared__ __align__(16) __hip_bfloat16 Bs[128 * 64];
    const int tid  = threadIdx.x;
    const int lane = tid & 63;
    const int wid  = tid >> 6;
    const int n0 = blockIdx.x * 128;      // 0..896 over stacked 1024 cols
    const int m0 = blockIdx.y * 128;
    const int wr = (wid >> 1) * 64;
    const int wc = (wid & 1) * 64;

    const __hip_bfloat16* aptr[4];
    const __hip_bfloat16* bptr[4];
    int ldsoff[4];
#pragma unroll
    for (int s = 0; s < 4; ++s) {
        const int si = wid * 4 + s;
        const int o = si * 1024 + lane * 16;
        const int row = o >> 7;
        const int chunk = (o >> 4) & 7;
        const int sch = chunk ^ (row & 7);
        aptr[s] = A + (size_t)(m0 + row) * DD + sch * 8;
        bptr[s] = Bt + (size_t)(n0 + row) * DD + sch * 8;
        ldsoff[s] = si * 512;
    }

    f32x4 acc[4][4];
#pragma unroll
    for (int i = 0; i < 4; ++i)
#pragma unroll
        for (int j = 0; j < 4; ++j) acc[i][j] = (f32x4){0.f, 0.f, 0.f, 0.f};

    const int rA = lane & 15;
    const int kgrp = lane >> 4;

    for (int kt = 0; kt < DD; kt += 64) {
#pragma unroll
        for (int s = 0; s < 4; ++s) gl_lds16(aptr[s] + kt, As + ldsoff[s]);
#pragma unroll
        for (int s = 0; s < 4; ++s) gl_lds16(bptr[s] + kt, Bs + ldsoff[s]);
        __syncthreads();
#pragma unroll
        for (int ks = 0; ks < 2; ++ks) {
            bf16x8 af[4], bfr[4];
#pragma unroll
            for (int fi = 0; fi < 4; ++fi) {
                const int r = wr + fi * 16 + rA;
                const int ch = (ks * 4 + kgrp) ^ (r & 7);
                af[fi] = *(const bf16x8*)(As + r * 64 + ch * 8);
            }
#pragma unroll
            for (int fj = 0; fj < 4; ++fj) {
                const int r = wc + fj * 16 + rA;
                const int ch = (ks * 4 + kgrp) ^ (r & 7);
                bfr[fj] = *(const bf16x8*)(Bs + r * 64 + ch * 8);
            }
#pragma unroll
            for (int fi = 0; fi < 4; ++fi)
#pragma unroll
                for (int fj = 0; fj < 4; ++fj)
                    acc[fi][fj] = __builtin_amdgcn_mfma_f32_16x16x32_bf16(
                        af[fi], bfr[fj], acc[fi][fj], 0, 0, 0);
        }
        __syncthreads();
    }

#pragma unroll
    for (int fi = 0; fi < 4; ++fi) {
#pragma unroll
        for (int r = 0; r < 4; ++r) {
            const int m = m0 + wr + fi * 16 + (lane >> 4) * 4 + r;
            const int b = m / NP1;
            const int n = m - b * NP1;
            const bool addstop = (n == msz[b]);
#pragma unroll
            for (int fj = 0; fj < 4; ++fj) {
                const int h = n0 + wc + fj * 16 + (lane & 15);
                float v = acc[fi][fj][r];
                if (addstop) v += stopm2[h];
                E2[(size_t)m * 1024 + h] = __float2bfloat16(__builtin_amdgcn_exp2f(v));
            }
        }
    }
}

// ---------------------------- generic C = A @ Bt^T (MFMA bf16, fp32 out)
// expout: C = exp2(acc)   (used for E_q precompute)
__global__ __launch_bounds__(256)
void k_gemm_bt(const __hip_bfloat16* __restrict__ A,
               const __hip_bfloat16* __restrict__ Bt,
               const float* __restrict__ bias,
               float* __restrict__ C, int ldc, int expout)
{
    __shared__ __align__(16) __hip_bfloat16 As[128 * 64];
    __shared__ __align__(16) __hip_bfloat16 Bs[128 * 64];
    const int tid  = threadIdx.x;
    const int lane = tid & 63;
    const int wid  = tid >> 6;
    const int m0 = blockIdx.x * 128;
    const int n0 = blockIdx.y * 128;
    const int wr = (wid >> 1) * 64;
    const int wc = (wid & 1) * 64;

    const __hip_bfloat16* aptr[4];
    const __hip_bfloat16* bptr[4];
    int ldsoff[4];
#pragma unroll
    for (int s = 0; s < 4; ++s) {
        const int si = wid * 4 + s;
        const int o = si * 1024 + lane * 16;
        const int row = o >> 7;
        const int chunk = (o >> 4) & 7;
        const int sch = chunk ^ (row & 7);
        aptr[s] = A + (size_t)(m0 + row) * DD + sch * 8;
        bptr[s] = Bt + (size_t)(n0 + row) * DD + sch * 8;
        ldsoff[s] = si * 512;
    }

    f32x4 acc[4][4];
#pragma unroll
    for (int i = 0; i < 4; ++i)
#pragma unroll
        for (int j = 0; j < 4; ++j) acc[i][j] = (f32x4){0.f, 0.f, 0.f, 0.f};

    const int rA = lane & 15;
    const int kgrp = lane >> 4;

    for (int kt = 0; kt < DD; kt += 64) {
#pragma unroll
        for (int s = 0; s < 4; ++s) gl_lds16(aptr[s] + kt, As + ldsoff[s]);
#pragma unroll
        for (int s = 0; s < 4; ++s) gl_lds16(bptr[s] + kt, Bs + ldsoff[s]);
        __syncthreads();
#pragma unroll
        for (int ks = 0; ks < 2; ++ks) {
            bf16x8 af[4], bfr[4];
#pragma unroll
            for (int fi = 0; fi < 4; ++fi) {
                const int r = wr + fi * 16 + rA;
                const int ch = (ks * 4 + kgrp) ^ (r & 7);
                af[fi] = *(const bf16x8*)(As + r * 64 + ch * 8);
            }
#pragma unroll
            for (int fj = 0; fj < 4; ++fj) {
                const int r = wc + fj * 16 + rA;
                const int ch = (ks * 4 + kgrp) ^ (r & 7);
                bfr[fj] = *(const bf16x8*)(Bs + r * 64 + ch * 8);
            }
#pragma unroll
            for (int fi = 0; fi < 4; ++fi)
#pragma unroll
                for (int fj = 0; fj < 4; ++fj)
                    acc[fi][fj] = __builtin_amdgcn_mfma_f32_16x16x32_bf16(
                        af[fi], bfr[fj], acc[fi][fj], 0, 0, 0);
        }
        __syncthreads();
    }

#pragma unroll
    for (int fi = 0; fi < 4; ++fi) {
#pragma unroll
        for (int r = 0; r < 4; ++r) {
            const int m = m0 + wr + fi * 16 + (lane >> 4) * 4 + r;
#pragma unroll
            for (int fj = 0; fj < 4; ++fj) {
                const int h = n0 + wc + fj * 16 + (lane & 15);
                float v = acc[fi][fj][r];
                if (bias) v += bias[h];
                if (expout) v = __builtin_amdgcn_exp2f(v);
                C[(size_t)m * ldc + h] = v;
            }
        }
    }
}

// ---------------- fused LSTM step: g = h@w_hh^T (MFMA) + gx; cell; h out
__global__ __launch_bounds__(256)
void k_lstm(const __hip_bfloat16* __restrict__ hin,
            const __hip_bfloat16* __restrict__ whh,
            const float* __restrict__ gx,
            float* __restrict__ cbuf,
            __hip_bfloat16* __restrict__ hout,
            __hip_bfloat16* __restrict__ query,
            int t)
{
    __shared__ __align__(16) __hip_bfloat16 As[128 * 64];
    __shared__ __align__(16) __hip_bfloat16 Bs[128 * 64];
    __shared__ float Gs[128][132];
    const int tid  = threadIdx.x;
    const int lane = tid & 63;
    const int wid  = tid >> 6;
    const int hc0  = blockIdx.x * 32;
    const int wr = (wid >> 1) * 64;
    const int wc = (wid & 1) * 64;

    const __hip_bfloat16* aptr[4];
    const __hip_bfloat16* bptr[4];
    int ldsoff[4];
#pragma unroll
    for (int s = 0; s < 4; ++s) {
        const int si = wid * 4 + s;
        const int o = si * 1024 + lane * 16;
        const int row = o >> 7;
        const int chunk = (o >> 4) & 7;
        const int sch = chunk ^ (row & 7);
        aptr[s] = hin + (size_t)row * HH + sch * 8;
        const int brow = (row >> 5) * 512 + hc0 + (row & 31);
        bptr[s] = whh + (size_t)brow * HH + sch * 8;
        ldsoff[s] = si * 512;
    }

    f32x4 acc[4][4];
#pragma unroll
    for (int i = 0; i < 4; ++i)
#pragma unroll
        for (int j = 0; j < 4; ++j) acc[i][j] = (f32x4){0.f, 0.f, 0.f, 0.f};

    const int rA = lane & 15;
    const int kgrp = lane >> 4;

    for (int kt = 0; kt < HH; kt += 64) {
#pragma unroll
        for (int s = 0; s < 4; ++s) gl_lds16(aptr[s] + kt, As + ldsoff[s]);
#pragma unroll
        for (int s = 0; s < 4; ++s) gl_lds16(bptr[s] + kt, Bs + ldsoff[s]);
        __syncthreads();
#pragma unroll
        for (int ks = 0; ks < 2; ++ks) {
            bf16x8 af[4], bfr[4];
#pragma unroll
            for (int fi = 0; fi < 4; ++fi) {
                const int r = wr + fi * 16 + rA;
                const int ch = (ks * 4 + kgrp) ^ (r & 7);
                af[fi] = *(const bf16x8*)(As + r * 64 + ch * 8);
            }
#pragma unroll
            for (int fj = 0; fj < 4; ++fj) {
                const int r = wc + fj * 16 + rA;
                const int ch = (ks * 4 + kgrp) ^ (r & 7);
                bfr[fj] = *(const bf16x8*)(Bs + r * 64 + ch * 8);
            }
#pragma unroll
            for (int fi = 0; fi < 4; ++fi)
#pragma unroll
                for (int fj = 0; fj < 4; ++fj)
                    acc[fi][fj] = __builtin_amdgcn_mfma_f32_16x16x32_bf16(
                        af[fi], bfr[fj], acc[fi][fj], 0, 0, 0);
        }
        __syncthreads();
    }

#pragma unroll
    for (int fi = 0; fi < 4; ++fi)
#pragma unroll
        for (int fj = 0; fj < 4; ++fj)
#pragma unroll
            for (int r = 0; r < 4; ++r)
                Gs[wr + fi * 16 + (lane >> 4) * 4 + r][wc + fj * 16 + (lane & 15)]
                    = acc[fi][fj][r];
    __syncthreads();

    const int j  = tid & 31;
    const int mg = tid >> 5;
#pragma unroll
    for (int mi = 0; mi < 16; ++mi) {
        const int m = mg * 16 + mi;
        const float* gxr = gx + ((size_t)m * TP1 + t) * G4 + hc0 + j;
        float iv = sigm(Gs[m][j]       + gxr[0]);
        float fv = sigm(Gs[m][32 + j]  + gxr[512]);
        float gv = fast_tanh(Gs[m][64 + j] + gxr[1024]);
        float ov = sigm(Gs[m][96 + j]  + gxr[1536]);
        const int ci = m * HH + hc0 + j;
        float cv = fv * cbuf[ci] + iv * gv;
        float hv = ov * fast_tanh(cv);
        cbuf[ci] = cv;
        hout[ci] = __float2bfloat16(hv);
        query[((size_t)m * TP1 + t) * HH + hc0 + j] = __float2bfloat16(hv);
    }
}

// ---- score[b,q,n] = Vsum - sum_h 2*v_h / (E_f[n,h]*E_q[q,h] + 1)
// wave-per-n; 3 VALU ops per element (fma, rcp, fma)
__global__ __launch_bounds__(256)
void k_score(const __hip_bfloat16* __restrict__ E2, int efoff,
             const float* __restrict__ Eq,
             const float* __restrict__ v, const int* __restrict__ msz,
             float* __restrict__ score, int masked)
{
    const int wid  = threadIdx.x >> 6;
    const int lane = threadIdx.x & 63;
    const int n = blockIdx.x * 4 + wid;
    const int b = blockIdx.y;
    if (n >= NP1) return;
    float* sp = score + (size_t)b * TP1 * NP1 + n;
    if (masked && n > msz[b]) {
        if (lane == 0)
#pragma unroll
            for (int q = 0; q < TP1; ++q) sp[q * NP1] = NEGF;
        return;
    }
    const u16x8 fu = *(const u16x8*)((const unsigned short*)E2
                                     + ((size_t)b * NP1 + n) * 1024 + efoff + lane * 8);
    float ef[8];
#pragma unroll
    for (int i = 0; i < 8; ++i) ef[i] = bf2f(fu[i]);
    const float4* v4 = (const float4*)v;
    const float4 va = v4[lane * 2], vb = v4[lane * 2 + 1];
    const float vs8 = va.x + va.y + va.z + va.w + vb.x + vb.y + vb.z + vb.w;
    float v2[8] = {2.f*va.x, 2.f*va.y, 2.f*va.z, 2.f*va.w,
                   2.f*vb.x, 2.f*vb.y, 2.f*vb.z, 2.f*vb.w};
    for (int q = 0; q < TP1; ++q) {
        const float4* q4 = (const float4*)(Eq + ((size_t)b * TP1 + q) * HH);
        const float4 qa = q4[lane * 2], qb = q4[lane * 2 + 1];
        float eq[8] = {qa.x, qa.y, qa.z, qa.w, qb.x, qb.y, qb.z, qb.w};
        float acc = 0.f;
#pragma unroll
        for (int i = 0; i < 8; ++i)
            acc = fmaf(v2[i], __builtin_amdgcn_rcpf(fmaf(ef[i], eq[i], 1.0f)), acc);
        float s = vs8 - acc;
#pragma unroll
        for (int off = 32; off; off >>= 1) s += __shfl_down(s, off);
        if (lane == 0) sp[q * NP1] = s;
    }
}

// ------- softmax over n<=msz for all 9 q, then query2 = p @ featS (featS = log2(E2_hop))
__global__ __launch_bounds__(256)
void k_softpv(const float* __restrict__ score, const __hip_bfloat16* __restrict__ E2,
              const int* __restrict__ msz, __hip_bfloat16* __restrict__ outq)
{
    const int b   = blockIdx.x;
    const int ch  = blockIdx.y;
    const int tid = threadIdx.x;
    const int lane = tid & 63, wid = tid >> 6;
    __shared__ float p[TP1][NP1 + 3];
    __shared__ float comb[TP1][256];
    const int nlim = msz[b] + 1;          // valid rows: n <= msz

    const float* sb = score + (size_t)b * TP1 * NP1;
    for (int q = wid; q < TP1; q += 4) {
        const float* srow = sb + q * NP1;
        float mx = NEGF;
        for (int n = lane; n < nlim; n += 64) mx = fmaxf(mx, srow[n]);
#pragma unroll
        for (int off = 32; off; off >>= 1) mx = fmaxf(mx, __shfl_xor(mx, off));
        float sum = 0.f;
        for (int n = lane; n < nlim; n += 64) {
            float e = __builtin_amdgcn_exp2f((srow[n] - mx) * L2E);
            p[q][n] = e;
            sum += e;
        }
#pragma unroll
        for (int off = 32; off; off >>= 1) sum += __shfl_xor(sum, off);
        float inv = 1.f / sum;
        for (int n = lane; n < nlim; n += 64) p[q][n] *= inv;
    }
    __syncthreads();

    const int ng = tid >> 7;
    const int tc = tid & 127;
    const int col = ch * 256 + tc * 2;
    const unsigned short* fb = (const unsigned short*)E2 + (size_t)b * NP1 * 1024 + col;
    float a0[TP1] = {}, a1[TP1] = {};
    for (int n = ng; n < nlim; n += 2) {
        const unsigned int u = *(const unsigned int*)(fb + (size_t)n * 1024);
        const float f0 = __builtin_amdgcn_logf(bf2f((unsigned short)(u & 0xffffu)));
        const float f1 = __builtin_amdgcn_logf(bf2f((unsigned short)(u >> 16)));
#pragma unroll
        for (int q = 0; q < TP1; ++q) {
            const float pq = p[q][n];
            a0[q] += pq * f0;
            a1[q] += pq * f1;
        }
    }
    if (ng == 1) {
#pragma unroll
        for (int q = 0; q < TP1; ++q) {
            comb[q][tc * 2]     = a0[q];
            comb[q][tc * 2 + 1] = a1[q];
        }
    }
    __syncthreads();
    if (ng == 0) {
        __hip_bfloat16* oq = outq + (size_t)(b * TP1) * HH + col;
#pragma unroll
        for (int q = 0; q < TP1; ++q) {
            oq[(size_t)q * HH]     = __float2bfloat16(a0[q] + comb[q][tc * 2]);
            oq[(size_t)q * HH + 1] = __float2bfloat16(a1[q] + comb[q][tc * 2 + 1]);
        }
    }
}

// ===========================================================================
extern "C" void kernel_launch(void* const* d_in, const int* in_sizes, int n_in,
                              void* d_out, int out_size, void* d_ws, size_t ws_size,
                              hipStream_t stream)
{
    const float* attn_mem  = (const float*)d_in[0];
    const float* lstm_in   = (const float*)d_in[1];
    const int*   mem_sizes = (const int*)d_in[2];
    const float* init_h    = (const float*)d_in[3];
    const float* init_c    = (const float*)d_in[4];
    const float* init_i    = (const float*)d_in[5];
    const float* stop      = (const float*)d_in[6];
    const float* w_ih      = (const float*)d_in[7];
    const float* w_hh      = (const float*)d_in[8];
    const float* b_ih      = (const float*)d_in[9];
    const float* b_hh      = (const float*)d_in[10];
    const float* attn_wm   = (const float*)d_in[11];
    const float* attn_wq   = (const float*)d_in[12];
    const float* attn_v    = (const float*)d_in[13];
    const float* hop_wm    = (const float*)d_in[14];
    const float* hop_wq    = (const float*)d_in[15];
    const float* hop_v     = (const float*)d_in[16];
    float* out = (float*)d_out;

    char* w = (char*)d_ws;
    __hip_bfloat16* Abf    = (__hip_bfloat16*)w;  w += (size_t)MTOT * DD * 2;    // 33.7 MB
    __hip_bfloat16* E2     = (__hip_bfloat16*)w;  w += (size_t)MTOT * 1024 * 2;  // 67.4 MB
    __hip_bfloat16* Xbf    = (__hip_bfloat16*)w;  w += (size_t)BB * TP1 * DD * 2;
    __hip_bfloat16* Wt2    = (__hip_bfloat16*)w;  w += (size_t)1024 * DD * 2;
    __hip_bfloat16* WqtH   = (__hip_bfloat16*)w;  w += (size_t)HH * HH * 2;
    __hip_bfloat16* WqtA   = (__hip_bfloat16*)w;  w += (size_t)HH * HH * 2;
    __hip_bfloat16* wih_bf = (__hip_bfloat16*)w;  w += (size_t)G4 * DD * 2;
    __hip_bfloat16* whh_bf = (__hip_bfloat16*)w;  w += (size_t)G4 * HH * 2;
    __hip_bfloat16* h_a    = (__hip_bfloat16*)w;  w += (size_t)BB * HH * 2;
    __hip_bfloat16* h_b    = (__hip_bfloat16*)w;  w += (size_t)BB * HH * 2;
    __hip_bfloat16* query  = (__hip_bfloat16*)w;  w += (size_t)BB * TP1 * HH * 2;
    __hip_bfloat16* query2 = (__hip_bfloat16*)w;  w += (size_t)BB * TP1 * HH * 2;
    float* gatesx  = (float*)w;  w += (size_t)BB * TP1 * G4 * 4;                 // 9.4 MB
    float* eq      = (float*)w;  w += (size_t)BB * TP1 * HH * 4;                 // shared E_q buffer
    float* score   = (float*)w;  w += (size_t)BB * TP1 * NP1 * 4;
    float* cbuf    = (float*)w;  w += (size_t)BB * HH * 4;
    float* stopm2  = (float*)w;  w += 1024 * 4;
    float* bsum    = (float*)w;  w += G4 * 4;

    // precompute: all conversions + scaled weights + stop projections in 2 kernels
    k_cvtA<<<dim3(MTOT), dim3(256), 0, stream>>>(attn_mem, Abf);
    k_prep<<<dim3(7557), dim3(256), 0, stream>>>(
        hop_wm, attn_wm, hop_wq, attn_wq, w_ih, w_hh, b_ih, b_hh,
        stop, lstm_in, init_i, init_h, init_c,
        Wt2, WqtH, WqtA, wih_bf, whh_bf, bsum, stopm2, Xbf, h_a, cbuf);

    // merged feat GEMM -> E2 = exp2(scaled feat), hop cols 0-511 | attn cols 512-1023
    k_feat2<<<dim3(8, 257), dim3(256), 0, stream>>>(Abf, Wt2, stopm2, mem_sizes, E2);

    // LSTM: MFMA input-gates + 9 fused MFMA steps
    k_gemm_bt<<<dim3(9, 16), dim3(256), 0, stream>>>(Xbf, wih_bf, bsum, gatesx, G4, 0);
    for (int t = 0; t < TP1; ++t) {
        const __hip_bfloat16* hin = (t & 1) ? h_b : h_a;
        __hip_bfloat16*      hout = (t & 1) ? h_a : h_b;
        k_lstm<<<dim3(16), dim3(256), 0, stream>>>(hin, whh_bf, gatesx, cbuf, hout, query, t);
    }

    // hop attention (masked): E_q = exp2(query@WqtH), score, softmax+PV -> query2
    k_gemm_bt<<<dim3(9, 4), dim3(256), 0, stream>>>(query, WqtH, nullptr, eq, HH, 1);
    k_score<<<dim3(65, 128), dim3(256), 0, stream>>>(E2, 0, eq, hop_v, mem_sizes, score, 1);
    k_softpv<<<dim3(128, 2), dim3(256), 0, stream>>>(score, E2, mem_sizes, query2);

    // final pointer scores (unmasked) -> d_out
    k_gemm_bt<<<dim3(9, 4), dim3(256), 0, stream>>>(query2, WqtA, nullptr, eq, HH, 1);
    k_score<<<dim3(65, 128), dim3(256), 0, stream>>>(E2, 512, eq, attn_v, mem_sizes, out, 0);
}

// Round 6
// 284.413 us; speedup vs baseline: 5.0854x; 1.3199x over previous
//
#include <hip/hip_runtime.h>
#include <hip/hip_bf16.h>
#include <math.h>

#define BB   128
#define NPTS 256
#define NP1  257
#define DD   512
#define HH   512
#define G4   2048
#define TP1  9
#define NEGF -1e18f
#define MTOT (BB * NP1)   // 32896
#define CSC  2.8853900817779268f   // 2*log2(e): tanh(x) = 1 - 2/(exp2(CSC*x)+1)
#define L2E  1.4426950408889634f

typedef __attribute__((ext_vector_type(8))) short bf16x8;
typedef __attribute__((ext_vector_type(8))) unsigned short u16x8;
typedef __attribute__((ext_vector_type(4))) float f32x4;

__device__ __forceinline__ float bf2f(unsigned short u)
{
    union { unsigned int i; float f; } x;
    x.i = (unsigned int)u << 16;
    return x.f;
}

__device__ __forceinline__ float sigm(float x)
{
    return __builtin_amdgcn_rcpf(1.0f + __builtin_amdgcn_exp2f(-x * L2E));
}

__device__ __forceinline__ float fast_tanh(float x)
{
    float e = __builtin_amdgcn_exp2f(x * CSC);
    return 1.0f - 2.0f * __builtin_amdgcn_rcpf(e + 1.0f);
}

__device__ __forceinline__ void gl_lds16(const __hip_bfloat16* g, __hip_bfloat16* l)
{
    __builtin_amdgcn_global_load_lds(
        (const __attribute__((address_space(1))) void*)g,
        (__attribute__((address_space(3))) void*)l, 16, 0, 0);
}

// ------------------------------------------- prep (all conversions, one kernel)
// blocks: [0,1024) Wt2 | [1024,2048) Wqt | [2048,4096) wih | [4096,6144) whh
//   [6144] bsum | [6145,6149) stopm2 | [6149,7301) Xbf | [7301,7557) init h,c
//   [7557,24005) attn_mem -> Abf (2 rows/block, float4)
__global__ __launch_bounds__(256)
void k_prep(const float* __restrict__ hop_wm, const float* __restrict__ attn_wm,
            const float* __restrict__ hop_wq, const float* __restrict__ attn_wq,
            const float* __restrict__ w_ih, const float* __restrict__ w_hh,
            const float* __restrict__ b_ih, const float* __restrict__ b_hh,
            const float* __restrict__ stop, const float* __restrict__ lstm_in,
            const float* __restrict__ init_i, const float* __restrict__ init_h,
            const float* __restrict__ init_c, const float* __restrict__ Amem,
            __hip_bfloat16* __restrict__ Wt2, __hip_bfloat16* __restrict__ WqtH,
            __hip_bfloat16* __restrict__ WqtA, __hip_bfloat16* __restrict__ wih_bf,
            __hip_bfloat16* __restrict__ whh_bf, float* __restrict__ bsum,
            float* __restrict__ stopm2, __hip_bfloat16* __restrict__ Xbf,
            __hip_bfloat16* __restrict__ h_a, float* __restrict__ cbuf,
            __hip_bfloat16* __restrict__ Abf)
{
    const int x = blockIdx.x, t = threadIdx.x;
    if (x < 1024) {                       // Wt2[n][k] = CSC * wm[k][n]
        const float* W = (x < 512) ? hop_wm : attn_wm;
        const int col = x & 511;
        Wt2[(size_t)x * DD + t]       = __float2bfloat16(CSC * W[(size_t)t * HH + col]);
        Wt2[(size_t)x * DD + t + 256] = __float2bfloat16(CSC * W[(size_t)(t + 256) * HH + col]);
    } else if (x < 2048) {                // WqtH (xCSC) / WqtA (no scale)
        const int j = x - 1024;
        if (j < 512) {
            WqtH[(size_t)j * DD + t]       = __float2bfloat16(CSC * hop_wq[(size_t)t * HH + j]);
            WqtH[(size_t)j * DD + t + 256] = __float2bfloat16(CSC * hop_wq[(size_t)(t + 256) * HH + j]);
        } else {
            const int jj = j - 512;
            WqtA[(size_t)jj * DD + t]       = __float2bfloat16(attn_wq[(size_t)t * HH + jj]);
            WqtA[(size_t)jj * DD + t + 256] = __float2bfloat16(attn_wq[(size_t)(t + 256) * HH + jj]);
        }
    } else if (x < 4096) {                // wih bf16
        const size_t r = (size_t)(x - 2048) * DD;
        wih_bf[r + t]       = __float2bfloat16(w_ih[r + t]);
        wih_bf[r + t + 256] = __float2bfloat16(w_ih[r + t + 256]);
    } else if (x < 6144) {                // whh bf16
        const size_t r = (size_t)(x - 4096) * DD;
        whh_bf[r + t]       = __float2bfloat16(w_hh[r + t]);
        whh_bf[r + t + 256] = __float2bfloat16(w_hh[r + t + 256]);
    } else if (x == 6144) {               // bias sum
#pragma unroll
        for (int i = 0; i < 8; ++i) {
            const int idx = t + 256 * i;
            bsum[idx] = b_ih[idx] + b_hh[idx];
        }
    } else if (x < 6149) {                // stopm2[h] = CSC * stop @ wm[:,h]
        const int h = (x - 6145) * 256 + t;
        const float* W = (h < 512) ? hop_wm : attn_wm;
        const int col = h & 511;
        float a = 0.f;
        for (int k = 0; k < DD; ++k) a += stop[k] * W[(size_t)k * HH + col];
        stopm2[h] = CSC * a;
    } else if (x < 7301) {                // Xbf rows
        const int m = x - 6149;
        const int bb = m / TP1, tt = m - bb * TP1;
        const float* src = (tt == 0) ? init_i : (lstm_in + (size_t)(bb * 8 + tt - 1) * DD);
        float2 vv = *(const float2*)(src + 2 * t);
        __hip_bfloat16* o = Xbf + (size_t)m * DD + 2 * t;
        o[0] = __float2bfloat16(vv.x);
        o[1] = __float2bfloat16(vv.y);
    } else if (x < 7557) {                // init h, c
        const int idx = (x - 7301) * 256 + t;
        h_a[idx]  = __float2bfloat16(init_h[idx & (HH - 1)]);
        cbuf[idx] = init_c[idx & (HH - 1)];
    } else {                              // attn_mem (+zero stop row) -> bf16
        const int m = (x - 7557) * 2 + (t >> 7);   // row in [0, 32896)
        const int b = m / NP1;
        const int n = m - b * NP1;
        const int c4 = (t & 127) * 4;
        float4 v = make_float4(0.f, 0.f, 0.f, 0.f);
        if (n < NPTS)
            v = *(const float4*)(Amem + ((size_t)(b * NPTS + n)) * DD + c4);
        __hip_bfloat16* o = Abf + (size_t)m * DD + c4;
        o[0] = __float2bfloat16(v.x);
        o[1] = __float2bfloat16(v.y);
        o[2] = __float2bfloat16(v.z);
        o[3] = __float2bfloat16(v.w);
    }
}

// ------------------- E2[m][h] = exp2(CSC*feat)  (merged hop|attn, MFMA bf16)
// 1D grid 2056 with bijective XCD remap: blocks sharing an A-panel land on
// the SAME XCD consecutively (A-panel L2 reuse).
__global__ __launch_bounds__(256)
void k_feat2(const __hip_bfloat16* __restrict__ A,
             const __hip_bfloat16* __restrict__ Bt,
             const float* __restrict__ stopm2,
             const int* __restrict__ msz,
             __hip_bfloat16* __restrict__ E2)
{
    const int orig = blockIdx.x;                  // 0..2055 (= 8*257)
    const int wgid = (orig & 7) * 257 + (orig >> 3);
    const int m0 = (wgid >> 3) * 128;
    const int n0 = (wgid & 7) * 128;

    __shared__ __align__(16) __hip_bfloat16 As[128 * 64];
    __shared__ __align__(16) __hip_bfloat16 Bs[128 * 64];
    const int tid  = threadIdx.x;
    const int lane = tid & 63;
    const int wid  = tid >> 6;
    const int wr = (wid >> 1) * 64;
    const int wc = (wid & 1) * 64;

    const __hip_bfloat16* aptr[4];
    const __hip_bfloat16* bptr[4];
    int ldsoff[4];
#pragma unroll
    for (int s = 0; s < 4; ++s) {
        const int si = wid * 4 + s;
        const int o = si * 1024 + lane * 16;
        const int row = o >> 7;
        const int chunk = (o >> 4) & 7;
        const int sch = chunk ^ (row & 7);
        aptr[s] = A + (size_t)(m0 + row) * DD + sch * 8;
        bptr[s] = Bt + (size_t)(n0 + row) * DD + sch * 8;
        ldsoff[s] = si * 512;
    }

    f32x4 acc[4][4];
#pragma unroll
    for (int i = 0; i < 4; ++i)
#pragma unroll
        for (int j = 0; j < 4; ++j) acc[i][j] = (f32x4){0.f, 0.f, 0.f, 0.f};

    const int rA = lane & 15;
    const int kgrp = lane >> 4;

    for (int kt = 0; kt < DD; kt += 64) {
#pragma unroll
        for (int s = 0; s < 4; ++s) gl_lds16(aptr[s] + kt, As + ldsoff[s]);
#pragma unroll
        for (int s = 0; s < 4; ++s) gl_lds16(bptr[s] + kt, Bs + ldsoff[s]);
        __syncthreads();
#pragma unroll
        for (int ks = 0; ks < 2; ++ks) {
            bf16x8 af[4], bfr[4];
#pragma unroll
            for (int fi = 0; fi < 4; ++fi) {
                const int r = wr + fi * 16 + rA;
                const int ch = (ks * 4 + kgrp) ^ (r & 7);
                af[fi] = *(const bf16x8*)(As + r * 64 + ch * 8);
            }
#pragma unroll
            for (int fj = 0; fj < 4; ++fj) {
                const int r = wc + fj * 16 + rA;
                const int ch = (ks * 4 + kgrp) ^ (r & 7);
                bfr[fj] = *(const bf16x8*)(Bs + r * 64 + ch * 8);
            }
#pragma unroll
            for (int fi = 0; fi < 4; ++fi)
#pragma unroll
                for (int fj = 0; fj < 4; ++fj)
                    acc[fi][fj] = __builtin_amdgcn_mfma_f32_16x16x32_bf16(
                        af[fi], bfr[fj], acc[fi][fj], 0, 0, 0);
        }
        __syncthreads();
    }

#pragma unroll
    for (int fi = 0; fi < 4; ++fi) {
#pragma unroll
        for (int r = 0; r < 4; ++r) {
            const int m = m0 + wr + fi * 16 + (lane >> 4) * 4 + r;
            const int b = m / NP1;
            const int n = m - b * NP1;
            const bool addstop = (n == msz[b]);
#pragma unroll
            for (int fj = 0; fj < 4; ++fj) {
                const int h = n0 + wc + fj * 16 + (lane & 15);
                float v = acc[fi][fj][r];
                if (addstop) v += stopm2[h];
                E2[(size_t)m * 1024 + h] = __float2bfloat16(__builtin_amdgcn_exp2f(v));
            }
        }
    }
}

// ---------------------------- generic C = A @ Bt^T (MFMA bf16, fp32 out)
__global__ __launch_bounds__(256)
void k_gemm_bt(const __hip_bfloat16* __restrict__ A,
               const __hip_bfloat16* __restrict__ Bt,
               const float* __restrict__ bias,
               float* __restrict__ C, int ldc, int expout)
{
    __shared__ __align__(16) __hip_bfloat16 As[128 * 64];
    __shared__ __align__(16) __hip_bfloat16 Bs[128 * 64];
    const int tid  = threadIdx.x;
    const int lane = tid & 63;
    const int wid  = tid >> 6;
    const int m0 = blockIdx.x * 128;
    const int n0 = blockIdx.y * 128;
    const int wr = (wid >> 1) * 64;
    const int wc = (wid & 1) * 64;

    const __hip_bfloat16* aptr[4];
    const __hip_bfloat16* bptr[4];
    int ldsoff[4];
#pragma unroll
    for (int s = 0; s < 4; ++s) {
        const int si = wid * 4 + s;
        const int o = si * 1024 + lane * 16;
        const int row = o >> 7;
        const int chunk = (o >> 4) & 7;
        const int sch = chunk ^ (row & 7);
        aptr[s] = A + (size_t)(m0 + row) * DD + sch * 8;
        bptr[s] = Bt + (size_t)(n0 + row) * DD + sch * 8;
        ldsoff[s] = si * 512;
    }

    f32x4 acc[4][4];
#pragma unroll
    for (int i = 0; i < 4; ++i)
#pragma unroll
        for (int j = 0; j < 4; ++j) acc[i][j] = (f32x4){0.f, 0.f, 0.f, 0.f};

    const int rA = lane & 15;
    const int kgrp = lane >> 4;

    for (int kt = 0; kt < DD; kt += 64) {
#pragma unroll
        for (int s = 0; s < 4; ++s) gl_lds16(aptr[s] + kt, As + ldsoff[s]);
#pragma unroll
        for (int s = 0; s < 4; ++s) gl_lds16(bptr[s] + kt, Bs + ldsoff[s]);
        __syncthreads();
#pragma unroll
        for (int ks = 0; ks < 2; ++ks) {
            bf16x8 af[4], bfr[4];
#pragma unroll
            for (int fi = 0; fi < 4; ++fi) {
                const int r = wr + fi * 16 + rA;
                const int ch = (ks * 4 + kgrp) ^ (r & 7);
                af[fi] = *(const bf16x8*)(As + r * 64 + ch * 8);
            }
#pragma unroll
            for (int fj = 0; fj < 4; ++fj) {
                const int r = wc + fj * 16 + rA;
                const int ch = (ks * 4 + kgrp) ^ (r & 7);
                bfr[fj] = *(const bf16x8*)(Bs + r * 64 + ch * 8);
            }
#pragma unroll
            for (int fi = 0; fi < 4; ++fi)
#pragma unroll
                for (int fj = 0; fj < 4; ++fj)
                    acc[fi][fj] = __builtin_amdgcn_mfma_f32_16x16x32_bf16(
                        af[fi], bfr[fj], acc[fi][fj], 0, 0, 0);
        }
        __syncthreads();
    }

#pragma unroll
    for (int fi = 0; fi < 4; ++fi) {
#pragma unroll
        for (int r = 0; r < 4; ++r) {
            const int m = m0 + wr + fi * 16 + (lane >> 4) * 4 + r;
#pragma unroll
            for (int fj = 0; fj < 4; ++fj) {
                const int h = n0 + wc + fj * 16 + (lane & 15);
                float v = acc[fi][fj][r];
                if (bias) v += bias[h];
                if (expout) v = __builtin_amdgcn_exp2f(v);
                C[(size_t)m * ldc + h] = v;
            }
        }
    }
}

// ------- fused LSTM step, latency-optimized: full operand panels resident
// in LDS, ALL loads issued upfront, ONE barrier, 16 barrier-free K-steps.
// grid (2, 64): m0 = bx*64, hc0 = by*8 (block covers 64 m x 4gates x 8 hcols)
__global__ __launch_bounds__(256)
void k_lstm2(const __hip_bfloat16* __restrict__ hin,   // [128][512]
             const __hip_bfloat16* __restrict__ whh,   // [2048][512]
             const float* __restrict__ gx,             // [1152][2048]
             float* __restrict__ cbuf,                 // [128][512]
             __hip_bfloat16* __restrict__ hout,        // [128][512]
             __hip_bfloat16* __restrict__ query,       // [1152][512] bf16
             int t)
{
    __shared__ __align__(16) __hip_bfloat16 As[64 * 512];   // 64 KB, [8][64][64]
    __shared__ __align__(16) __hip_bfloat16 Bs[32 * 512];   // 32 KB, [8][32][64]
    __shared__ float Gs[64][36];
    const int tid  = threadIdx.x;
    const int lane = tid & 63;
    const int wid  = tid >> 6;
    const int m0  = blockIdx.x * 64;
    const int hc0 = blockIdx.y * 8;
    const int wy = wid >> 1, wx = wid & 1;        // wave tile 32(m) x 16(n)

    // stage A (hin panel 64x512): 16 insts, linear LDS dst, swizzled source
#pragma unroll
    for (int i = 0; i < 16; ++i) {
        const int o = (i * 256 + tid) * 16;       // byte offset (linear dst)
        const int c = o >> 13;                    // 8KB K-chunk
        const int oc = o & 8191;
        const int row = oc >> 7;
        const int ch = (oc >> 4) & 7;
        const int sch = ch ^ (row & 7);
        gl_lds16(hin + (size_t)(m0 + row) * HH + c * 64 + sch * 8, As + (o >> 1));
    }
    // stage B (whh gate-strip panel 32x512): 8 insts
#pragma unroll
    for (int i = 0; i < 8; ++i) {
        const int o = (i * 256 + tid) * 16;
        const int c = o >> 12;                    // 4KB K-chunk
        const int oc = o & 4095;
        const int row = oc >> 7;                  // 0..31
        const int ch = (oc >> 4) & 7;
        const int sch = ch ^ (row & 7);
        const int brow = (row >> 3) * 512 + hc0 + (row & 7);
        gl_lds16(whh + (size_t)brow * HH + c * 64 + sch * 8, Bs + (o >> 1));
    }
    __syncthreads();                              // single drain for all 24 loads

    f32x4 acc[2];
    acc[0] = (f32x4){0.f, 0.f, 0.f, 0.f};
    acc[1] = (f32x4){0.f, 0.f, 0.f, 0.f};
    const int rr = lane & 15;
    const int kg = lane >> 4;

#pragma unroll
    for (int ks = 0; ks < 16; ++ks) {
        const int c = ks >> 1, sub = ks & 1;
        const __hip_bfloat16* Ab = As + c * 4096;
        const __hip_bfloat16* Bb = Bs + c * 2048;
        const int rb = wx * 16 + rr;
        const bf16x8 bfr = *(const bf16x8*)(Bb + rb * 64 + (((sub * 4 + kg) ^ (rb & 7)) * 8));
#pragma unroll
        for (int fi = 0; fi < 2; ++fi) {
            const int ra = wy * 32 + fi * 16 + rr;
            const bf16x8 af = *(const bf16x8*)(Ab + ra * 64 + (((sub * 4 + kg) ^ (ra & 7)) * 8));
            acc[fi] = __builtin_amdgcn_mfma_f32_16x16x32_bf16(af, bfr, acc[fi], 0, 0, 0);
        }
    }

#pragma unroll
    for (int fi = 0; fi < 2; ++fi)
#pragma unroll
        for (int r = 0; r < 4; ++r)
            Gs[wy * 32 + fi * 16 + (lane >> 4) * 4 + r][wx * 16 + (lane & 15)] = acc[fi][r];
    __syncthreads();

    // gate phase: 64 m-rows x 8 h-cols; thread -> (j, 2 rows)
    const int j  = tid & 7;
    const int mg = tid >> 3;
#pragma unroll
    for (int mi = 0; mi < 2; ++mi) {
        const int m = mg * 2 + mi;
        const float* gxr = gx + ((size_t)(m0 + m) * TP1 + t) * G4 + hc0 + j;
        float iv = sigm(Gs[m][j]      + gxr[0]);
        float fv = sigm(Gs[m][8 + j]  + gxr[512]);
        float gv = fast_tanh(Gs[m][16 + j] + gxr[1024]);
        float ov = sigm(Gs[m][24 + j] + gxr[1536]);
        const int ci = (m0 + m) * HH + hc0 + j;
        float cv = fv * cbuf[ci] + iv * gv;
        float hv = ov * fast_tanh(cv);
        cbuf[ci] = cv;
        hout[ci] = __float2bfloat16(hv);
        query[((size_t)(m0 + m) * TP1 + t) * HH + hc0 + j] = __float2bfloat16(hv);
    }
}

// ---- score[b,q,n] = Vsum - sum_h 2*v_h / (E_f[n,h]*E_q[q,h] + 1)
__global__ __launch_bounds__(256)
void k_score(const __hip_bfloat16* __restrict__ E2, int efoff,
             const float* __restrict__ Eq,
             const float* __restrict__ v, const int* __restrict__ msz,
             float* __restrict__ score, int masked)
{
    const int wid  = threadIdx.x >> 6;
    const int lane = threadIdx.x & 63;
    const int n = blockIdx.x * 4 + wid;
    const int b = blockIdx.y;
    if (n >= NP1) return;
    float* sp = score + (size_t)b * TP1 * NP1 + n;
    if (masked && n > msz[b]) {
        if (lane == 0)
#pragma unroll
            for (int q = 0; q < TP1; ++q) sp[q * NP1] = NEGF;
        return;
    }
    const u16x8 fu = *(const u16x8*)((const unsigned short*)E2
                                     + ((size_t)b * NP1 + n) * 1024 + efoff + lane * 8);
    float ef[8];
#pragma unroll
    for (int i = 0; i < 8; ++i) ef[i] = bf2f(fu[i]);
    const float4* v4 = (const float4*)v;
    const float4 va = v4[lane * 2], vb = v4[lane * 2 + 1];
    const float vs8 = va.x + va.y + va.z + va.w + vb.x + vb.y + vb.z + vb.w;
    float v2[8] = {2.f*va.x, 2.f*va.y, 2.f*va.z, 2.f*va.w,
                   2.f*vb.x, 2.f*vb.y, 2.f*vb.z, 2.f*vb.w};
    for (int q = 0; q < TP1; ++q) {
        const float4* q4 = (const float4*)(Eq + ((size_t)b * TP1 + q) * HH);
        const float4 qa = q4[lane * 2], qb = q4[lane * 2 + 1];
        float eq[8] = {qa.x, qa.y, qa.z, qa.w, qb.x, qb.y, qb.z, qb.w};
        float acc = 0.f;
#pragma unroll
        for (int i = 0; i < 8; ++i)
            acc = fmaf(v2[i], __builtin_amdgcn_rcpf(fmaf(ef[i], eq[i], 1.0f)), acc);
        float s = vs8 - acc;
#pragma unroll
        for (int off = 32; off; off >>= 1) s += __shfl_down(s, off);
        if (lane == 0) sp[q * NP1] = s;
    }
}

// ------- softmax over n<=msz for all 9 q, then query2 = p @ featS
__global__ __launch_bounds__(256)
void k_softpv(const float* __restrict__ score, const __hip_bfloat16* __restrict__ E2,
              const int* __restrict__ msz, __hip_bfloat16* __restrict__ outq)
{
    const int b   = blockIdx.x;
    const int ch  = blockIdx.y;
    const int tid = threadIdx.x;
    const int lane = tid & 63, wid = tid >> 6;
    __shared__ float p[TP1][NP1 + 3];
    __shared__ float comb[TP1][256];
    const int nlim = msz[b] + 1;

    const float* sb = score + (size_t)b * TP1 * NP1;
    for (int q = wid; q < TP1; q += 4) {
        const float* srow = sb + q * NP1;
        float mx = NEGF;
        for (int n = lane; n < nlim; n += 64) mx = fmaxf(mx, srow[n]);
#pragma unroll
        for (int off = 32; off; off >>= 1) mx = fmaxf(mx, __shfl_xor(mx, off));
        float sum = 0.f;
        for (int n = lane; n < nlim; n += 64) {
            float e = __builtin_amdgcn_exp2f((srow[n] - mx) * L2E);
            p[q][n] = e;
            sum += e;
        }
#pragma unroll
        for (int off = 32; off; off >>= 1) sum += __shfl_xor(sum, off);
        float inv = 1.f / sum;
        for (int n = lane; n < nlim; n += 64) p[q][n] *= inv;
    }
    __syncthreads();

    const int ng = tid >> 7;
    const int tc = tid & 127;
    const int col = ch * 256 + tc * 2;
    const unsigned short* fb = (const unsigned short*)E2 + (size_t)b * NP1 * 1024 + col;
    float a0[TP1] = {}, a1[TP1] = {};
    for (int n = ng; n < nlim; n += 2) {
        const unsigned int u = *(const unsigned int*)(fb + (size_t)n * 1024);
        const float f0 = __builtin_amdgcn_logf(bf2f((unsigned short)(u & 0xffffu)));
        const float f1 = __builtin_amdgcn_logf(bf2f((unsigned short)(u >> 16)));
#pragma unroll
        for (int q = 0; q < TP1; ++q) {
            const float pq = p[q][n];
            a0[q] += pq * f0;
            a1[q] += pq * f1;
        }
    }
    if (ng == 1) {
#pragma unroll
        for (int q = 0; q < TP1; ++q) {
            comb[q][tc * 2]     = a0[q];
            comb[q][tc * 2 + 1] = a1[q];
        }
    }
    __syncthreads();
    if (ng == 0) {
        __hip_bfloat16* oq = outq + (size_t)(b * TP1) * HH + col;
#pragma unroll
        for (int q = 0; q < TP1; ++q) {
            oq[(size_t)q * HH]     = __float2bfloat16(a0[q] + comb[q][tc * 2]);
            oq[(size_t)q * HH + 1] = __float2bfloat16(a1[q] + comb[q][tc * 2 + 1]);
        }
    }
}

// ===========================================================================
extern "C" void kernel_launch(void* const* d_in, const int* in_sizes, int n_in,
                              void* d_out, int out_size, void* d_ws, size_t ws_size,
                              hipStream_t stream)
{
    const float* attn_mem  = (const float*)d_in[0];
    const float* lstm_in   = (const float*)d_in[1];
    const int*   mem_sizes = (const int*)d_in[2];
    const float* init_h    = (const float*)d_in[3];
    const float* init_c    = (const float*)d_in[4];
    const float* init_i    = (const float*)d_in[5];
    const float* stop      = (const float*)d_in[6];
    const float* w_ih      = (const float*)d_in[7];
    const float* w_hh      = (const float*)d_in[8];
    const float* b_ih      = (const float*)d_in[9];
    const float* b_hh      = (const float*)d_in[10];
    const float* attn_wm   = (const float*)d_in[11];
    const float* attn_wq   = (const float*)d_in[12];
    const float* attn_v    = (const float*)d_in[13];
    const float* hop_wm    = (const float*)d_in[14];
    const float* hop_wq    = (const float*)d_in[15];
    const float* hop_v     = (const float*)d_in[16];
    float* out = (float*)d_out;

    char* w = (char*)d_ws;
    __hip_bfloat16* Abf    = (__hip_bfloat16*)w;  w += (size_t)MTOT * DD * 2;    // 33.7 MB
    __hip_bfloat16* E2     = (__hip_bfloat16*)w;  w += (size_t)MTOT * 1024 * 2;  // 67.4 MB
    __hip_bfloat16* Xbf    = (__hip_bfloat16*)w;  w += (size_t)BB * TP1 * DD * 2;
    __hip_bfloat16* Wt2    = (__hip_bfloat16*)w;  w += (size_t)1024 * DD * 2;
    __hip_bfloat16* WqtH   = (__hip_bfloat16*)w;  w += (size_t)HH * HH * 2;
    __hip_bfloat16* WqtA   = (__hip_bfloat16*)w;  w += (size_t)HH * HH * 2;
    __hip_bfloat16* wih_bf = (__hip_bfloat16*)w;  w += (size_t)G4 * DD * 2;
    __hip_bfloat16* whh_bf = (__hip_bfloat16*)w;  w += (size_t)G4 * HH * 2;
    __hip_bfloat16* h_a    = (__hip_bfloat16*)w;  w += (size_t)BB * HH * 2;
    __hip_bfloat16* h_b    = (__hip_bfloat16*)w;  w += (size_t)BB * HH * 2;
    __hip_bfloat16* query  = (__hip_bfloat16*)w;  w += (size_t)BB * TP1 * HH * 2;
    __hip_bfloat16* query2 = (__hip_bfloat16*)w;  w += (size_t)BB * TP1 * HH * 2;
    float* gatesx  = (float*)w;  w += (size_t)BB * TP1 * G4 * 4;                 // 9.4 MB
    float* eq      = (float*)w;  w += (size_t)BB * TP1 * HH * 4;
    float* score   = (float*)w;  w += (size_t)BB * TP1 * NP1 * 4;
    float* cbuf    = (float*)w;  w += (size_t)BB * HH * 4;
    float* stopm2  = (float*)w;  w += 1024 * 4;
    float* bsum    = (float*)w;  w += G4 * 4;

    // all conversions + scaled weights + stop projections + A->bf16, one kernel
    k_prep<<<dim3(24005), dim3(256), 0, stream>>>(
        hop_wm, attn_wm, hop_wq, attn_wq, w_ih, w_hh, b_ih, b_hh,
        stop, lstm_in, init_i, init_h, init_c, attn_mem,
        Wt2, WqtH, WqtA, wih_bf, whh_bf, bsum, stopm2, Xbf, h_a, cbuf, Abf);

    // merged feat GEMM -> E2 (hop cols 0-511 | attn cols 512-1023), XCD-remapped
    k_feat2<<<dim3(2056), dim3(256), 0, stream>>>(Abf, Wt2, stopm2, mem_sizes, E2);

    // LSTM: MFMA input-gates + 9 latency-optimized fused steps
    k_gemm_bt<<<dim3(9, 16), dim3(256), 0, stream>>>(Xbf, wih_bf, bsum, gatesx, G4, 0);
    for (int t = 0; t < TP1; ++t) {
        const __hip_bfloat16* hin = (t & 1) ? h_b : h_a;
        __hip_bfloat16*      hout = (t & 1) ? h_a : h_b;
        k_lstm2<<<dim3(2, 64), dim3(256), 0, stream>>>(hin, whh_bf, gatesx, cbuf, hout, query, t);
    }

    // hop attention (masked): E_q, score, softmax+PV -> query2
    k_gemm_bt<<<dim3(9, 4), dim3(256), 0, stream>>>(query, WqtH, nullptr, eq, HH, 1);
    k_score<<<dim3(65, 128), dim3(256), 0, stream>>>(E2, 0, eq, hop_v, mem_sizes, score, 1);
    k_softpv<<<dim3(128, 2), dim3(256), 0, stream>>>(score, E2, mem_sizes, query2);

    // final pointer scores (unmasked) -> d_out
    k_gemm_bt<<<dim3(9, 4), dim3(256), 0, stream>>>(query2, WqtA, nullptr, eq, HH, 1);
    k_score<<<dim3(65, 128), dim3(256), 0, stream>>>(E2, 512, eq, attn_v, mem_sizes, out, 0);
}

// Round 7
// 274.579 us; speedup vs baseline: 5.2675x; 1.0358x over previous
//
#include <hip/hip_runtime.h>
#include <hip/hip_bf16.h>
#include <math.h>

#define BB   128
#define NPTS 256
#define NP1  257
#define DD   512
#define HH   512
#define G4   2048
#define TP1  9
#define NEGF -1e18f
#define MTOT (BB * NP1)   // 32896
#define CSC  2.8853900817779268f   // 2*log2(e): tanh(x) = 1 - 2/(exp2(CSC*x)+1)
#define L2E  1.4426950408889634f

typedef __attribute__((ext_vector_type(8))) short bf16x8;
typedef __attribute__((ext_vector_type(8))) unsigned short u16x8;
typedef __attribute__((ext_vector_type(4))) float f32x4;

__device__ __forceinline__ float bf2f(unsigned short u)
{
    union { unsigned int i; float f; } x;
    x.i = (unsigned int)u << 16;
    return x.f;
}

__device__ __forceinline__ float sigm(float x)
{
    return __builtin_amdgcn_rcpf(1.0f + __builtin_amdgcn_exp2f(-x * L2E));
}

__device__ __forceinline__ float fast_tanh(float x)
{
    float e = __builtin_amdgcn_exp2f(x * CSC);
    return 1.0f - 2.0f * __builtin_amdgcn_rcpf(e + 1.0f);
}

__device__ __forceinline__ void gl_lds16(const __hip_bfloat16* g, __hip_bfloat16* l)
{
    __builtin_amdgcn_global_load_lds(
        (const __attribute__((address_space(1))) void*)g,
        (__attribute__((address_space(3))) void*)l, 16, 0, 0);
}

// ---- shared GEMM helpers: swizzled-LDS 128x64 tile, 16x16x32 MFMA ----
__device__ __forceinline__ void stage8(const __hip_bfloat16* const* aptr,
                                       const __hip_bfloat16* const* bptr,
                                       const int* ldsoff,
                                       __hip_bfloat16* A_, __hip_bfloat16* B_, int kt)
{
#pragma unroll
    for (int s = 0; s < 4; ++s) gl_lds16(aptr[s] + kt, A_ + ldsoff[s]);
#pragma unroll
    for (int s = 0; s < 4; ++s) gl_lds16(bptr[s] + kt, B_ + ldsoff[s]);
}

__device__ __forceinline__ void gemm_step(const __hip_bfloat16* A_,
                                          const __hip_bfloat16* B_,
                                          f32x4 (&acc)[4][4],
                                          int wr, int wc, int rA, int kgrp)
{
#pragma unroll
    for (int ks = 0; ks < 2; ++ks) {
        bf16x8 af[4], bfr[4];
#pragma unroll
        for (int fi = 0; fi < 4; ++fi) {
            const int r = wr + fi * 16 + rA;
            const int ch = (ks * 4 + kgrp) ^ (r & 7);
            af[fi] = *(const bf16x8*)(A_ + r * 64 + ch * 8);
        }
#pragma unroll
        for (int fj = 0; fj < 4; ++fj) {
            const int r = wc + fj * 16 + rA;
            const int ch = (ks * 4 + kgrp) ^ (r & 7);
            bfr[fj] = *(const bf16x8*)(B_ + r * 64 + ch * 8);
        }
#pragma unroll
        for (int fi = 0; fi < 4; ++fi)
#pragma unroll
            for (int fj = 0; fj < 4; ++fj)
                acc[fi][fj] = __builtin_amdgcn_mfma_f32_16x16x32_bf16(
                    af[fi], bfr[fj], acc[fi][fj], 0, 0, 0);
    }
}

// ------------------------------------------- prep (all conversions, one kernel)
__global__ __launch_bounds__(256)
void k_prep(const float* __restrict__ hop_wm, const float* __restrict__ attn_wm,
            const float* __restrict__ hop_wq, const float* __restrict__ attn_wq,
            const float* __restrict__ w_ih, const float* __restrict__ w_hh,
            const float* __restrict__ b_ih, const float* __restrict__ b_hh,
            const float* __restrict__ stop, const float* __restrict__ lstm_in,
            const float* __restrict__ init_i, const float* __restrict__ init_h,
            const float* __restrict__ init_c, const float* __restrict__ Amem,
            __hip_bfloat16* __restrict__ Wt2, __hip_bfloat16* __restrict__ WqtH,
            __hip_bfloat16* __restrict__ WqtA, __hip_bfloat16* __restrict__ wih_bf,
            __hip_bfloat16* __restrict__ whh_bf, float* __restrict__ bsum,
            float* __restrict__ stopm2, __hip_bfloat16* __restrict__ Xbf,
            __hip_bfloat16* __restrict__ h_a, float* __restrict__ cbuf,
            __hip_bfloat16* __restrict__ Abf)
{
    const int x = blockIdx.x, t = threadIdx.x;
    if (x < 1024) {                       // Wt2[n][k] = CSC * wm[k][n]
        const float* W = (x < 512) ? hop_wm : attn_wm;
        const int col = x & 511;
        Wt2[(size_t)x * DD + t]       = __float2bfloat16(CSC * W[(size_t)t * HH + col]);
        Wt2[(size_t)x * DD + t + 256] = __float2bfloat16(CSC * W[(size_t)(t + 256) * HH + col]);
    } else if (x < 2048) {                // WqtH (xCSC) / WqtA (no scale)
        const int j = x - 1024;
        if (j < 512) {
            WqtH[(size_t)j * DD + t]       = __float2bfloat16(CSC * hop_wq[(size_t)t * HH + j]);
            WqtH[(size_t)j * DD + t + 256] = __float2bfloat16(CSC * hop_wq[(size_t)(t + 256) * HH + j]);
        } else {
            const int jj = j - 512;
            WqtA[(size_t)jj * DD + t]       = __float2bfloat16(attn_wq[(size_t)t * HH + jj]);
            WqtA[(size_t)jj * DD + t + 256] = __float2bfloat16(attn_wq[(size_t)(t + 256) * HH + jj]);
        }
    } else if (x < 4096) {                // wih bf16
        const size_t r = (size_t)(x - 2048) * DD;
        wih_bf[r + t]       = __float2bfloat16(w_ih[r + t]);
        wih_bf[r + t + 256] = __float2bfloat16(w_ih[r + t + 256]);
    } else if (x < 6144) {                // whh bf16
        const size_t r = (size_t)(x - 4096) * DD;
        whh_bf[r + t]       = __float2bfloat16(w_hh[r + t]);
        whh_bf[r + t + 256] = __float2bfloat16(w_hh[r + t + 256]);
    } else if (x == 6144) {               // bias sum
#pragma unroll
        for (int i = 0; i < 8; ++i) {
            const int idx = t + 256 * i;
            bsum[idx] = b_ih[idx] + b_hh[idx];
        }
    } else if (x < 6149) {                // stopm2[h] = CSC * stop @ wm[:,h]
        const int h = (x - 6145) * 256 + t;
        const float* W = (h < 512) ? hop_wm : attn_wm;
        const int col = h & 511;
        float a = 0.f;
        for (int k = 0; k < DD; ++k) a += stop[k] * W[(size_t)k * HH + col];
        stopm2[h] = CSC * a;
    } else if (x < 7301) {                // Xbf rows
        const int m = x - 6149;
        const int bb = m / TP1, tt = m - bb * TP1;
        const float* src = (tt == 0) ? init_i : (lstm_in + (size_t)(bb * 8 + tt - 1) * DD);
        float2 vv = *(const float2*)(src + 2 * t);
        __hip_bfloat16* o = Xbf + (size_t)m * DD + 2 * t;
        o[0] = __float2bfloat16(vv.x);
        o[1] = __float2bfloat16(vv.y);
    } else if (x < 7557) {                // init h, c
        const int idx = (x - 7301) * 256 + t;
        h_a[idx]  = __float2bfloat16(init_h[idx & (HH - 1)]);
        cbuf[idx] = init_c[idx & (HH - 1)];
    } else {                              // attn_mem (+zero stop row) -> bf16
        const int m = (x - 7557) * 2 + (t >> 7);   // row in [0, 32896)
        const int b = m / NP1;
        const int n = m - b * NP1;
        const int c4 = (t & 127) * 4;
        float4 v = make_float4(0.f, 0.f, 0.f, 0.f);
        if (n < NPTS)
            v = *(const float4*)(Amem + ((size_t)(b * NPTS + n)) * DD + c4);
        __hip_bfloat16* o = Abf + (size_t)m * DD + c4;
        o[0] = __float2bfloat16(v.x);
        o[1] = __float2bfloat16(v.y);
        o[2] = __float2bfloat16(v.z);
        o[3] = __float2bfloat16(v.w);
    }
}

// ------------------- E2[m][h] = exp2(CSC*feat)  (merged hop|attn, MFMA bf16)
// XCD-remapped grid + 2-phase double-buffered pipeline (stage-next || compute-cur)
__global__ __launch_bounds__(256)
void k_feat2(const __hip_bfloat16* __restrict__ A,
             const __hip_bfloat16* __restrict__ Bt,
             const float* __restrict__ stopm2,
             const int* __restrict__ msz,
             __hip_bfloat16* __restrict__ E2)
{
    const int orig = blockIdx.x;                  // 0..2055 (= 8*257)
    const int wgid = (orig & 7) * 257 + (orig >> 3);
    const int m0 = (wgid >> 3) * 128;
    const int n0 = (wgid & 7) * 128;

    __shared__ __align__(16) __hip_bfloat16 SM[4][128 * 64];   // As0|Bs0|As1|Bs1
    __hip_bfloat16* As0 = SM[0];
    __hip_bfloat16* Bs0 = SM[1];
    __hip_bfloat16* As1 = SM[2];
    __hip_bfloat16* Bs1 = SM[3];
    const int tid  = threadIdx.x;
    const int lane = tid & 63;
    const int wid  = tid >> 6;
    const int wr = (wid >> 1) * 64;
    const int wc = (wid & 1) * 64;

    const __hip_bfloat16* aptr[4];
    const __hip_bfloat16* bptr[4];
    int ldsoff[4];
#pragma unroll
    for (int s = 0; s < 4; ++s) {
        const int si = wid * 4 + s;
        const int o = si * 1024 + lane * 16;
        const int row = o >> 7;
        const int chunk = (o >> 4) & 7;
        const int sch = chunk ^ (row & 7);
        aptr[s] = A + (size_t)(m0 + row) * DD + sch * 8;
        bptr[s] = Bt + (size_t)(n0 + row) * DD + sch * 8;
        ldsoff[s] = si * 512;
    }

    f32x4 acc[4][4];
#pragma unroll
    for (int i = 0; i < 4; ++i)
#pragma unroll
        for (int j = 0; j < 4; ++j) acc[i][j] = (f32x4){0.f, 0.f, 0.f, 0.f};

    const int rA = lane & 15;
    const int kgrp = lane >> 4;

    stage8(aptr, bptr, ldsoff, As0, Bs0, 0);
    __syncthreads();
    for (int kt = 0; kt < DD; kt += 128) {
        stage8(aptr, bptr, ldsoff, As1, Bs1, kt + 64);
        gemm_step(As0, Bs0, acc, wr, wc, rA, kgrp);
        __syncthreads();                          // drains As1/Bs1 loads (flew under compute)
        if (kt + 128 < DD) stage8(aptr, bptr, ldsoff, As0, Bs0, kt + 128);
        gemm_step(As1, Bs1, acc, wr, wc, rA, kgrp);
        __syncthreads();
    }

#pragma unroll
    for (int fi = 0; fi < 4; ++fi) {
#pragma unroll
        for (int r = 0; r < 4; ++r) {
            const int m = m0 + wr + fi * 16 + (lane >> 4) * 4 + r;
            const int b = m / NP1;
            const int n = m - b * NP1;
            const bool addstop = (n == msz[b]);
#pragma unroll
            for (int fj = 0; fj < 4; ++fj) {
                const int h = n0 + wc + fj * 16 + (lane & 15);
                float v = acc[fi][fj][r];
                if (addstop) v += stopm2[h];
                E2[(size_t)m * 1024 + h] = __float2bfloat16(__builtin_amdgcn_exp2f(v));
            }
        }
    }
}

// ---------------------------- generic C = A @ Bt^T (MFMA bf16, fp32 out)
// 2-phase double-buffered pipeline
__global__ __launch_bounds__(256)
void k_gemm_bt(const __hip_bfloat16* __restrict__ A,
               const __hip_bfloat16* __restrict__ Bt,
               const float* __restrict__ bias,
               float* __restrict__ C, int ldc, int expout)
{
    __shared__ __align__(16) __hip_bfloat16 SM[4][128 * 64];
    __hip_bfloat16* As0 = SM[0];
    __hip_bfloat16* Bs0 = SM[1];
    __hip_bfloat16* As1 = SM[2];
    __hip_bfloat16* Bs1 = SM[3];
    const int tid  = threadIdx.x;
    const int lane = tid & 63;
    const int wid  = tid >> 6;
    const int m0 = blockIdx.x * 128;
    const int n0 = blockIdx.y * 128;
    const int wr = (wid >> 1) * 64;
    const int wc = (wid & 1) * 64;

    const __hip_bfloat16* aptr[4];
    const __hip_bfloat16* bptr[4];
    int ldsoff[4];
#pragma unroll
    for (int s = 0; s < 4; ++s) {
        const int si = wid * 4 + s;
        const int o = si * 1024 + lane * 16;
        const int row = o >> 7;
        const int chunk = (o >> 4) & 7;
        const int sch = chunk ^ (row & 7);
        aptr[s] = A + (size_t)(m0 + row) * DD + sch * 8;
        bptr[s] = Bt + (size_t)(n0 + row) * DD + sch * 8;
        ldsoff[s] = si * 512;
    }

    f32x4 acc[4][4];
#pragma unroll
    for (int i = 0; i < 4; ++i)
#pragma unroll
        for (int j = 0; j < 4; ++j) acc[i][j] = (f32x4){0.f, 0.f, 0.f, 0.f};

    const int rA = lane & 15;
    const int kgrp = lane >> 4;

    stage8(aptr, bptr, ldsoff, As0, Bs0, 0);
    __syncthreads();
    for (int kt = 0; kt < DD; kt += 128) {
        stage8(aptr, bptr, ldsoff, As1, Bs1, kt + 64);
        gemm_step(As0, Bs0, acc, wr, wc, rA, kgrp);
        __syncthreads();
        if (kt + 128 < DD) stage8(aptr, bptr, ldsoff, As0, Bs0, kt + 128);
        gemm_step(As1, Bs1, acc, wr, wc, rA, kgrp);
        __syncthreads();
    }

#pragma unroll
    for (int fi = 0; fi < 4; ++fi) {
#pragma unroll
        for (int r = 0; r < 4; ++r) {
            const int m = m0 + wr + fi * 16 + (lane >> 4) * 4 + r;
#pragma unroll
            for (int fj = 0; fj < 4; ++fj) {
                const int h = n0 + wc + fj * 16 + (lane & 15);
                float v = acc[fi][fj][r];
                if (bias) v += bias[h];
                if (expout) v = __builtin_amdgcn_exp2f(v);
                C[(size_t)m * ldc + h] = v;
            }
        }
    }
}

// ------- fused LSTM step, latency-optimized: full operand panels resident
// in LDS, ALL loads issued upfront, ONE barrier, 16 barrier-free K-steps.
__global__ __launch_bounds__(256)
void k_lstm2(const __hip_bfloat16* __restrict__ hin,   // [128][512]
             const __hip_bfloat16* __restrict__ whh,   // [2048][512]
             const float* __restrict__ gx,             // [1152][2048]
             float* __restrict__ cbuf,                 // [128][512]
             __hip_bfloat16* __restrict__ hout,        // [128][512]
             __hip_bfloat16* __restrict__ query,       // [1152][512] bf16
             int t)
{
    __shared__ __align__(16) __hip_bfloat16 As[64 * 512];   // 64 KB
    __shared__ __align__(16) __hip_bfloat16 Bs[32 * 512];   // 32 KB
    __shared__ float Gs[64][36];
    const int tid  = threadIdx.x;
    const int lane = tid & 63;
    const int wid  = tid >> 6;
    const int m0  = blockIdx.x * 64;
    const int hc0 = blockIdx.y * 8;
    const int wy = wid >> 1, wx = wid & 1;

#pragma unroll
    for (int i = 0; i < 16; ++i) {
        const int o = (i * 256 + tid) * 16;
        const int c = o >> 13;
        const int oc = o & 8191;
        const int row = oc >> 7;
        const int ch = (oc >> 4) & 7;
        const int sch = ch ^ (row & 7);
        gl_lds16(hin + (size_t)(m0 + row) * HH + c * 64 + sch * 8, As + (o >> 1));
    }
#pragma unroll
    for (int i = 0; i < 8; ++i) {
        const int o = (i * 256 + tid) * 16;
        const int c = o >> 12;
        const int oc = o & 4095;
        const int row = oc >> 7;
        const int ch = (oc >> 4) & 7;
        const int sch = ch ^ (row & 7);
        const int brow = (row >> 3) * 512 + hc0 + (row & 7);
        gl_lds16(whh + (size_t)brow * HH + c * 64 + sch * 8, Bs + (o >> 1));
    }
    __syncthreads();

    f32x4 acc[2];
    acc[0] = (f32x4){0.f, 0.f, 0.f, 0.f};
    acc[1] = (f32x4){0.f, 0.f, 0.f, 0.f};
    const int rr = lane & 15;
    const int kg = lane >> 4;

#pragma unroll
    for (int ks = 0; ks < 16; ++ks) {
        const int c = ks >> 1, sub = ks & 1;
        const __hip_bfloat16* Ab = As + c * 4096;
        const __hip_bfloat16* Bb = Bs + c * 2048;
        const int rb = wx * 16 + rr;
        const bf16x8 bfr = *(const bf16x8*)(Bb + rb * 64 + (((sub * 4 + kg) ^ (rb & 7)) * 8));
#pragma unroll
        for (int fi = 0; fi < 2; ++fi) {
            const int ra = wy * 32 + fi * 16 + rr;
            const bf16x8 af = *(const bf16x8*)(Ab + ra * 64 + (((sub * 4 + kg) ^ (ra & 7)) * 8));
            acc[fi] = __builtin_amdgcn_mfma_f32_16x16x32_bf16(af, bfr, acc[fi], 0, 0, 0);
        }
    }

#pragma unroll
    for (int fi = 0; fi < 2; ++fi)
#pragma unroll
        for (int r = 0; r < 4; ++r)
            Gs[wy * 32 + fi * 16 + (lane >> 4) * 4 + r][wx * 16 + (lane & 15)] = acc[fi][r];
    __syncthreads();

    const int j  = tid & 7;
    const int mg = tid >> 3;
#pragma unroll
    for (int mi = 0; mi < 2; ++mi) {
        const int m = mg * 2 + mi;
        const float* gxr = gx + ((size_t)(m0 + m) * TP1 + t) * G4 + hc0 + j;
        float iv = sigm(Gs[m][j]      + gxr[0]);
        float fv = sigm(Gs[m][8 + j]  + gxr[512]);
        float gv = fast_tanh(Gs[m][16 + j] + gxr[1024]);
        float ov = sigm(Gs[m][24 + j] + gxr[1536]);
        const int ci = (m0 + m) * HH + hc0 + j;
        float cv = fv * cbuf[ci] + iv * gv;
        float hv = ov * fast_tanh(cv);
        cbuf[ci] = cv;
        hout[ci] = __float2bfloat16(hv);
        query[((size_t)(m0 + m) * TP1 + t) * HH + hc0 + j] = __float2bfloat16(hv);
    }
}

// ---- score[b,q,n] = Vsum - sum_h 2*v_h / (E_f[n,h]*E_q[q,h] + 1)
__global__ __launch_bounds__(256)
void k_score(const __hip_bfloat16* __restrict__ E2, int efoff,
             const float* __restrict__ Eq,
             const float* __restrict__ v, const int* __restrict__ msz,
             float* __restrict__ score, int masked)
{
    const int wid  = threadIdx.x >> 6;
    const int lane = threadIdx.x & 63;
    const int n = blockIdx.x * 4 + wid;
    const int b = blockIdx.y;
    if (n >= NP1) return;
    float* sp = score + (size_t)b * TP1 * NP1 + n;
    if (masked && n > msz[b]) {
        if (lane == 0)
#pragma unroll
            for (int q = 0; q < TP1; ++q) sp[q * NP1] = NEGF;
        return;
    }
    const u16x8 fu = *(const u16x8*)((const unsigned short*)E2
                                     + ((size_t)b * NP1 + n) * 1024 + efoff + lane * 8);
    float ef[8];
#pragma unroll
    for (int i = 0; i < 8; ++i) ef[i] = bf2f(fu[i]);
    const float4* v4 = (const float4*)v;
    const float4 va = v4[lane * 2], vb = v4[lane * 2 + 1];
    const float vs8 = va.x + va.y + va.z + va.w + vb.x + vb.y + vb.z + vb.w;
    float v2[8] = {2.f*va.x, 2.f*va.y, 2.f*va.z, 2.f*va.w,
                   2.f*vb.x, 2.f*vb.y, 2.f*vb.z, 2.f*vb.w};
    for (int q = 0; q < TP1; ++q) {
        const float4* q4 = (const float4*)(Eq + ((size_t)b * TP1 + q) * HH);
        const float4 qa = q4[lane * 2], qb = q4[lane * 2 + 1];
        float eq[8] = {qa.x, qa.y, qa.z, qa.w, qb.x, qb.y, qb.z, qb.w};
        float acc = 0.f;
#pragma unroll
        for (int i = 0; i < 8; ++i)
            acc = fmaf(v2[i], __builtin_amdgcn_rcpf(fmaf(ef[i], eq[i], 1.0f)), acc);
        float s = vs8 - acc;
#pragma unroll
        for (int off = 32; off; off >>= 1) s += __shfl_down(s, off);
        if (lane == 0) sp[q * NP1] = s;
    }
}

// ------- softmax over n<=msz for all 9 q, then query2 = p @ featS
__global__ __launch_bounds__(256)
void k_softpv(const float* __restrict__ score, const __hip_bfloat16* __restrict__ E2,
              const int* __restrict__ msz, __hip_bfloat16* __restrict__ outq)
{
    const int b   = blockIdx.x;
    const int ch  = blockIdx.y;
    const int tid = threadIdx.x;
    const int lane = tid & 63, wid = tid >> 6;
    __shared__ float p[TP1][NP1 + 3];
    __shared__ float comb[TP1][256];
    const int nlim = msz[b] + 1;

    const float* sb = score + (size_t)b * TP1 * NP1;
    for (int q = wid; q < TP1; q += 4) {
        const float* srow = sb + q * NP1;
        float mx = NEGF;
        for (int n = lane; n < nlim; n += 64) mx = fmaxf(mx, srow[n]);
#pragma unroll
        for (int off = 32; off; off >>= 1) mx = fmaxf(mx, __shfl_xor(mx, off));
        float sum = 0.f;
        for (int n = lane; n < nlim; n += 64) {
            float e = __builtin_amdgcn_exp2f((srow[n] - mx) * L2E);
            p[q][n] = e;
            sum += e;
        }
#pragma unroll
        for (int off = 32; off; off >>= 1) sum += __shfl_xor(sum, off);
        float inv = 1.f / sum;
        for (int n = lane; n < nlim; n += 64) p[q][n] *= inv;
    }
    __syncthreads();

    const int ng = tid >> 7;
    const int tc = tid & 127;
    const int col = ch * 256 + tc * 2;
    const unsigned short* fb = (const unsigned short*)E2 + (size_t)b * NP1 * 1024 + col;
    float a0[TP1] = {}, a1[TP1] = {};
    for (int n = ng; n < nlim; n += 2) {
        const unsigned int u = *(const unsigned int*)(fb + (size_t)n * 1024);
        const float f0 = __builtin_amdgcn_logf(bf2f((unsigned short)(u & 0xffffu)));
        const float f1 = __builtin_amdgcn_logf(bf2f((unsigned short)(u >> 16)));
#pragma unroll
        for (int q = 0; q < TP1; ++q) {
            const float pq = p[q][n];
            a0[q] += pq * f0;
            a1[q] += pq * f1;
        }
    }
    if (ng == 1) {
#pragma unroll
        for (int q = 0; q < TP1; ++q) {
            comb[q][tc * 2]     = a0[q];
            comb[q][tc * 2 + 1] = a1[q];
        }
    }
    __syncthreads();
    if (ng == 0) {
        __hip_bfloat16* oq = outq + (size_t)(b * TP1) * HH + col;
#pragma unroll
        for (int q = 0; q < TP1; ++q) {
            oq[(size_t)q * HH]     = __float2bfloat16(a0[q] + comb[q][tc * 2]);
            oq[(size_t)q * HH + 1] = __float2bfloat16(a1[q] + comb[q][tc * 2 + 1]);
        }
    }
}

// ===========================================================================
extern "C" void kernel_launch(void* const* d_in, const int* in_sizes, int n_in,
                              void* d_out, int out_size, void* d_ws, size_t ws_size,
                              hipStream_t stream)
{
    const float* attn_mem  = (const float*)d_in[0];
    const float* lstm_in   = (const float*)d_in[1];
    const int*   mem_sizes = (const int*)d_in[2];
    const float* init_h    = (const float*)d_in[3];
    const float* init_c    = (const float*)d_in[4];
    const float* init_i    = (const float*)d_in[5];
    const float* stop      = (const float*)d_in[6];
    const float* w_ih      = (const float*)d_in[7];
    const float* w_hh      = (const float*)d_in[8];
    const float* b_ih      = (const float*)d_in[9];
    const float* b_hh      = (const float*)d_in[10];
    const float* attn_wm   = (const float*)d_in[11];
    const float* attn_wq   = (const float*)d_in[12];
    const float* attn_v    = (const float*)d_in[13];
    const float* hop_wm    = (const float*)d_in[14];
    const float* hop_wq    = (const float*)d_in[15];
    const float* hop_v     = (const float*)d_in[16];
    float* out = (float*)d_out;

    char* w = (char*)d_ws;
    __hip_bfloat16* Abf    = (__hip_bfloat16*)w;  w += (size_t)MTOT * DD * 2;    // 33.7 MB
    __hip_bfloat16* E2     = (__hip_bfloat16*)w;  w += (size_t)MTOT * 1024 * 2;  // 67.4 MB
    __hip_bfloat16* Xbf    = (__hip_bfloat16*)w;  w += (size_t)BB * TP1 * DD * 2;
    __hip_bfloat16* Wt2    = (__hip_bfloat16*)w;  w += (size_t)1024 * DD * 2;
    __hip_bfloat16* WqtH   = (__hip_bfloat16*)w;  w += (size_t)HH * HH * 2;
    __hip_bfloat16* WqtA   = (__hip_bfloat16*)w;  w += (size_t)HH * HH * 2;
    __hip_bfloat16* wih_bf = (__hip_bfloat16*)w;  w += (size_t)G4 * DD * 2;
    __hip_bfloat16* whh_bf = (__hip_bfloat16*)w;  w += (size_t)G4 * HH * 2;
    __hip_bfloat16* h_a    = (__hip_bfloat16*)w;  w += (size_t)BB * HH * 2;
    __hip_bfloat16* h_b    = (__hip_bfloat16*)w;  w += (size_t)BB * HH * 2;
    __hip_bfloat16* query  = (__hip_bfloat16*)w;  w += (size_t)BB * TP1 * HH * 2;
    __hip_bfloat16* query2 = (__hip_bfloat16*)w;  w += (size_t)BB * TP1 * HH * 2;
    float* gatesx  = (float*)w;  w += (size_t)BB * TP1 * G4 * 4;                 // 9.4 MB
    float* eq      = (float*)w;  w += (size_t)BB * TP1 * HH * 4;
    float* score   = (float*)w;  w += (size_t)BB * TP1 * NP1 * 4;
    float* cbuf    = (float*)w;  w += (size_t)BB * HH * 4;
    float* stopm2  = (float*)w;  w += 1024 * 4;
    float* bsum    = (float*)w;  w += G4 * 4;

    // all conversions + scaled weights + stop projections + A->bf16, one kernel
    k_prep<<<dim3(24005), dim3(256), 0, stream>>>(
        hop_wm, attn_wm, hop_wq, attn_wq, w_ih, w_hh, b_ih, b_hh,
        stop, lstm_in, init_i, init_h, init_c, attn_mem,
        Wt2, WqtH, WqtA, wih_bf, whh_bf, bsum, stopm2, Xbf, h_a, cbuf, Abf);

    // merged feat GEMM -> E2 (hop cols 0-511 | attn cols 512-1023), XCD-remapped, dbuf
    k_feat2<<<dim3(2056), dim3(256), 0, stream>>>(Abf, Wt2, stopm2, mem_sizes, E2);

    // LSTM: MFMA input-gates (dbuf) + 9 latency-optimized fused steps
    k_gemm_bt<<<dim3(9, 16), dim3(256), 0, stream>>>(Xbf, wih_bf, bsum, gatesx, G4, 0);
    for (int t = 0; t < TP1; ++t) {
        const __hip_bfloat16* hin = (t & 1) ? h_b : h_a;
        __hip_bfloat16*      hout = (t & 1) ? h_a : h_b;
        k_lstm2<<<dim3(2, 64), dim3(256), 0, stream>>>(hin, whh_bf, gatesx, cbuf, hout, query, t);
    }

    // hop attention (masked): E_q, score, softmax+PV -> query2
    k_gemm_bt<<<dim3(9, 4), dim3(256), 0, stream>>>(query, WqtH, nullptr, eq, HH, 1);
    k_score<<<dim3(65, 128), dim3(256), 0, stream>>>(E2, 0, eq, hop_v, mem_sizes, score, 1);
    k_softpv<<<dim3(128, 2), dim3(256), 0, stream>>>(score, E2, mem_sizes, query2);

    // final pointer scores (unmasked) -> d_out
    k_gemm_bt<<<dim3(9, 4), dim3(256), 0, stream>>>(query2, WqtA, nullptr, eq, HH, 1);
    k_score<<<dim3(65, 128), dim3(256), 0, stream>>>(E2, 512, eq, attn_v, mem_sizes, out, 0);
}

// Round 8
// 264.612 us; speedup vs baseline: 5.4659x; 1.0377x over previous
//
#include <hip/hip_runtime.h>
#include <hip/hip_bf16.h>
#include <math.h>

#define BB   128
#define NPTS 256
#define NP1  257
#define DD   512
#define HH   512
#define G4   2048
#define TP1  9
#define NEGF -1e18f
#define MTOT (BB * NP1)   // 32896
#define CSC  2.8853900817779268f   // 2*log2(e): tanh(x) = 1 - 2/(exp2(CSC*x)+1)
#define L2E  1.4426950408889634f

typedef __attribute__((ext_vector_type(8))) short bf16x8;
typedef __attribute__((ext_vector_type(8))) unsigned short u16x8;
typedef __attribute__((ext_vector_type(4))) float f32x4;

__device__ __forceinline__ float bf2f(unsigned short u)
{
    union { unsigned int i; float f; } x;
    x.i = (unsigned int)u << 16;
    return x.f;
}

__device__ __forceinline__ float sigm(float x)
{
    return __builtin_amdgcn_rcpf(1.0f + __builtin_amdgcn_exp2f(-x * L2E));
}

__device__ __forceinline__ float fast_tanh(float x)
{
    float e = __builtin_amdgcn_exp2f(x * CSC);
    return 1.0f - 2.0f * __builtin_amdgcn_rcpf(e + 1.0f);
}

__device__ __forceinline__ void gl_lds16(const __hip_bfloat16* g, __hip_bfloat16* l)
{
    __builtin_amdgcn_global_load_lds(
        (const __attribute__((address_space(1))) void*)g,
        (__attribute__((address_space(3))) void*)l, 16, 0, 0);
}

// ---- shared GEMM helpers: swizzled-LDS 128x64 tile, 16x16x32 MFMA ----
__device__ __forceinline__ void stage8(const __hip_bfloat16* const* aptr,
                                       const __hip_bfloat16* const* bptr,
                                       const int* ldsoff,
                                       __hip_bfloat16* A_, __hip_bfloat16* B_, int kt)
{
#pragma unroll
    for (int s = 0; s < 4; ++s) gl_lds16(aptr[s] + kt, A_ + ldsoff[s]);
#pragma unroll
    for (int s = 0; s < 4; ++s) gl_lds16(bptr[s] + kt, B_ + ldsoff[s]);
}

__device__ __forceinline__ void gemm_step(const __hip_bfloat16* A_,
                                          const __hip_bfloat16* B_,
                                          f32x4 (&acc)[4][4],
                                          int wr, int wc, int rA, int kgrp)
{
#pragma unroll
    for (int ks = 0; ks < 2; ++ks) {
        bf16x8 af[4], bfr[4];
#pragma unroll
        for (int fi = 0; fi < 4; ++fi) {
            const int r = wr + fi * 16 + rA;
            const int ch = (ks * 4 + kgrp) ^ (r & 7);
            af[fi] = *(const bf16x8*)(A_ + r * 64 + ch * 8);
        }
#pragma unroll
        for (int fj = 0; fj < 4; ++fj) {
            const int r = wc + fj * 16 + rA;
            const int ch = (ks * 4 + kgrp) ^ (r & 7);
            bfr[fj] = *(const bf16x8*)(B_ + r * 64 + ch * 8);
        }
#pragma unroll
        for (int fi = 0; fi < 4; ++fi)
#pragma unroll
            for (int fj = 0; fj < 4; ++fj)
                acc[fi][fj] = __builtin_amdgcn_mfma_f32_16x16x32_bf16(
                    af[fi], bfr[fj], acc[fi][fj], 0, 0, 0);
    }
}

// counted-vmcnt 2-buffer K-pipeline: never drains vmcnt to 0 in steady state.
// iter I: stage(I+1) | s_waitcnt vmcnt(N) [own tile-I landed] | s_barrier
//         [all waves' tile-I landed] | MFMA(buf I) | s_barrier [buf reuse safe]
#define PIPE_ITER(I, NW, Acur, Bcur, Anxt, Bnxt)                              \
    if ((I) < 7) stage8(aptr, bptr, ldsoff, Anxt, Bnxt, ((I) + 1) * 64);      \
    asm volatile("s_waitcnt vmcnt(" NW ")" ::: "memory");                     \
    __builtin_amdgcn_s_barrier();                                             \
    asm volatile("" ::: "memory");                                            \
    gemm_step(Acur, Bcur, acc, wr, wc, rA, kgrp);                             \
    __builtin_amdgcn_s_barrier();                                             \
    asm volatile("" ::: "memory");

#define PIPE_RUN()                                                            \
    stage8(aptr, bptr, ldsoff, As0, Bs0, 0);                                  \
    PIPE_ITER(0, "8", As0, Bs0, As1, Bs1)                                     \
    PIPE_ITER(1, "8", As1, Bs1, As0, Bs0)                                     \
    PIPE_ITER(2, "8", As0, Bs0, As1, Bs1)                                     \
    PIPE_ITER(3, "8", As1, Bs1, As0, Bs0)                                     \
    PIPE_ITER(4, "8", As0, Bs0, As1, Bs1)                                     \
    PIPE_ITER(5, "8", As1, Bs1, As0, Bs0)                                     \
    PIPE_ITER(6, "8", As0, Bs0, As1, Bs1)                                     \
    PIPE_ITER(7, "0", As1, Bs1, As0, Bs0)

// ------------------------------------------- prep (all conversions, one kernel)
// blocks: [0,256) weight transposes (LDS-tiled) | [256] bsum | [257,261) stopm2
//   [261,1413) Xbf | [1413,1669) init h,c | [1669,3717) wih | [3717,5765) whh
//   [5765,22213) attn_mem -> Abf
__global__ __launch_bounds__(256)
void k_prep(const float* __restrict__ hop_wm, const float* __restrict__ attn_wm,
            const float* __restrict__ hop_wq, const float* __restrict__ attn_wq,
            const float* __restrict__ w_ih, const float* __restrict__ w_hh,
            const float* __restrict__ b_ih, const float* __restrict__ b_hh,
            const float* __restrict__ stop, const float* __restrict__ lstm_in,
            const float* __restrict__ init_i, const float* __restrict__ init_h,
            const float* __restrict__ init_c, const float* __restrict__ Amem,
            __hip_bfloat16* __restrict__ Wt2, __hip_bfloat16* __restrict__ WqtH,
            __hip_bfloat16* __restrict__ WqtA, __hip_bfloat16* __restrict__ wih_bf,
            __hip_bfloat16* __restrict__ whh_bf, float* __restrict__ bsum,
            float* __restrict__ stopm2, __hip_bfloat16* __restrict__ Xbf,
            __hip_bfloat16* __restrict__ h_a, float* __restrict__ cbuf,
            __hip_bfloat16* __restrict__ Abf)
{
    const int x = blockIdx.x, t = threadIdx.x;
    if (x < 256) {                        // 64x64 LDS-tiled weight transpose
        __shared__ float S[64][69];
        const int mat  = x >> 6;          // 0 hop_wm | 1 attn_wm | 2 hop_wq | 3 attn_wq
        const int tile = x & 63;
        const int tr = tile >> 3, tc = tile & 7;
        const float* W = (mat == 0) ? hop_wm : (mat == 1) ? attn_wm
                       : (mat == 2) ? hop_wq : attn_wq;
        __hip_bfloat16* O = (mat == 0) ? Wt2 : (mat == 1) ? (Wt2 + (size_t)512 * DD)
                          : (mat == 2) ? WqtH : WqtA;
        const float scale = (mat == 3) ? 1.0f : CSC;
#pragma unroll
        for (int k = 0; k < 4; ++k) {     // coalesced float4 row reads
            const int r = (t >> 4) + k * 16;
            const int c4 = (t & 15) * 4;
            const float4 v = *(const float4*)(W + (size_t)(tr * 64 + r) * 512 + tc * 64 + c4);
            S[r][c4] = v.x; S[r][c4 + 1] = v.y; S[r][c4 + 2] = v.z; S[r][c4 + 3] = v.w;
        }
        __syncthreads();
        const int oc = tc * 64 + (t >> 2);          // output row (W column)
        const int j0 = (t & 3) * 16;
        __hip_bfloat16 tmp[16];
#pragma unroll
        for (int j = 0; j < 16; ++j)
            tmp[j] = __float2bfloat16(scale * S[j0 + j][t >> 2]);
        *(bf16x8*)(O + (size_t)oc * 512 + tr * 64 + j0)     = *(bf16x8*)&tmp[0];
        *(bf16x8*)(O + (size_t)oc * 512 + tr * 64 + j0 + 8) = *(bf16x8*)&tmp[8];
    } else if (x == 256) {                // bias sum
#pragma unroll
        for (int i = 0; i < 8; ++i) {
            const int idx = t + 256 * i;
            bsum[idx] = b_ih[idx] + b_hh[idx];
        }
    } else if (x < 261) {                 // stopm2[h] = CSC * stop @ wm[:,h]
        const int h = (x - 257) * 256 + t;
        const float* W = (h < 512) ? hop_wm : attn_wm;
        const int col = h & 511;
        float a = 0.f;
        for (int k = 0; k < DD; ++k) a += stop[k] * W[(size_t)k * HH + col];
        stopm2[h] = CSC * a;
    } else if (x < 1413) {                // Xbf rows
        const int m = x - 261;
        const int bb = m / TP1, tt = m - bb * TP1;
        const float* src = (tt == 0) ? init_i : (lstm_in + (size_t)(bb * 8 + tt - 1) * DD);
        float2 vv = *(const float2*)(src + 2 * t);
        __hip_bfloat16* o = Xbf + (size_t)m * DD + 2 * t;
        o[0] = __float2bfloat16(vv.x);
        o[1] = __float2bfloat16(vv.y);
    } else if (x < 1669) {                // init h, c
        const int idx = (x - 1413) * 256 + t;
        h_a[idx]  = __float2bfloat16(init_h[idx & (HH - 1)]);
        cbuf[idx] = init_c[idx & (HH - 1)];
    } else if (x < 3717) {                // wih bf16 (row-major copy)
        const size_t r = (size_t)(x - 1669) * DD;
        wih_bf[r + t]       = __float2bfloat16(w_ih[r + t]);
        wih_bf[r + t + 256] = __float2bfloat16(w_ih[r + t + 256]);
    } else if (x < 5765) {                // whh bf16
        const size_t r = (size_t)(x - 3717) * DD;
        whh_bf[r + t]       = __float2bfloat16(w_hh[r + t]);
        whh_bf[r + t + 256] = __float2bfloat16(w_hh[r + t + 256]);
    } else {                              // attn_mem (+zero stop row) -> bf16
        const int m = (x - 5765) * 2 + (t >> 7);   // row in [0, 32896)
        const int b = m / NP1;
        const int n = m - b * NP1;
        const int c4 = (t & 127) * 4;
        float4 v = make_float4(0.f, 0.f, 0.f, 0.f);
        if (n < NPTS)
            v = *(const float4*)(Amem + ((size_t)(b * NPTS + n)) * DD + c4);
        __hip_bfloat16* o = Abf + (size_t)m * DD + c4;
        o[0] = __float2bfloat16(v.x);
        o[1] = __float2bfloat16(v.y);
        o[2] = __float2bfloat16(v.z);
        o[3] = __float2bfloat16(v.w);
    }
}

// ------------------- E2[m][h] = exp2(CSC*feat)  (merged hop|attn, MFMA bf16)
// XCD-remapped grid + counted-vmcnt 2-buffer pipeline
__global__ __launch_bounds__(256)
void k_feat2(const __hip_bfloat16* __restrict__ A,
             const __hip_bfloat16* __restrict__ Bt,
             const float* __restrict__ stopm2,
             const int* __restrict__ msz,
             __hip_bfloat16* __restrict__ E2)
{
    const int orig = blockIdx.x;                  // 0..2055 (= 8*257)
    const int wgid = (orig & 7) * 257 + (orig >> 3);
    const int m0 = (wgid >> 3) * 128;
    const int n0 = (wgid & 7) * 128;

    __shared__ __align__(16) __hip_bfloat16 SM[4][128 * 64];   // As0|Bs0|As1|Bs1
    __hip_bfloat16* As0 = SM[0];
    __hip_bfloat16* Bs0 = SM[1];
    __hip_bfloat16* As1 = SM[2];
    __hip_bfloat16* Bs1 = SM[3];
    const int tid  = threadIdx.x;
    const int lane = tid & 63;
    const int wid  = tid >> 6;
    const int wr = (wid >> 1) * 64;
    const int wc = (wid & 1) * 64;

    const __hip_bfloat16* aptr[4];
    const __hip_bfloat16* bptr[4];
    int ldsoff[4];
#pragma unroll
    for (int s = 0; s < 4; ++s) {
        const int si = wid * 4 + s;
        const int o = si * 1024 + lane * 16;
        const int row = o >> 7;
        const int chunk = (o >> 4) & 7;
        const int sch = chunk ^ (row & 7);
        aptr[s] = A + (size_t)(m0 + row) * DD + sch * 8;
        bptr[s] = Bt + (size_t)(n0 + row) * DD + sch * 8;
        ldsoff[s] = si * 512;
    }

    f32x4 acc[4][4];
#pragma unroll
    for (int i = 0; i < 4; ++i)
#pragma unroll
        for (int j = 0; j < 4; ++j) acc[i][j] = (f32x4){0.f, 0.f, 0.f, 0.f};

    const int rA = lane & 15;
    const int kgrp = lane >> 4;

    PIPE_RUN()

#pragma unroll
    for (int fi = 0; fi < 4; ++fi) {
#pragma unroll
        for (int r = 0; r < 4; ++r) {
            const int m = m0 + wr + fi * 16 + (lane >> 4) * 4 + r;
            const int b = m / NP1;
            const int n = m - b * NP1;
            const bool addstop = (n == msz[b]);
#pragma unroll
            for (int fj = 0; fj < 4; ++fj) {
                const int h = n0 + wc + fj * 16 + (lane & 15);
                float v = acc[fi][fj][r];
                if (addstop) v += stopm2[h];
                E2[(size_t)m * 1024 + h] = __float2bfloat16(__builtin_amdgcn_exp2f(v));
            }
        }
    }
}

// ---------------------------- generic C = A @ Bt^T (MFMA bf16, fp32 out)
// counted-vmcnt 2-buffer pipeline
__global__ __launch_bounds__(256)
void k_gemm_bt(const __hip_bfloat16* __restrict__ A,
               const __hip_bfloat16* __restrict__ Bt,
               const float* __restrict__ bias,
               float* __restrict__ C, int ldc, int expout)
{
    __shared__ __align__(16) __hip_bfloat16 SM[4][128 * 64];
    __hip_bfloat16* As0 = SM[0];
    __hip_bfloat16* Bs0 = SM[1];
    __hip_bfloat16* As1 = SM[2];
    __hip_bfloat16* Bs1 = SM[3];
    const int tid  = threadIdx.x;
    const int lane = tid & 63;
    const int wid  = tid >> 6;
    const int m0 = blockIdx.x * 128;
    const int n0 = blockIdx.y * 128;
    const int wr = (wid >> 1) * 64;
    const int wc = (wid & 1) * 64;

    const __hip_bfloat16* aptr[4];
    const __hip_bfloat16* bptr[4];
    int ldsoff[4];
#pragma unroll
    for (int s = 0; s < 4; ++s) {
        const int si = wid * 4 + s;
        const int o = si * 1024 + lane * 16;
        const int row = o >> 7;
        const int chunk = (o >> 4) & 7;
        const int sch = chunk ^ (row & 7);
        aptr[s] = A + (size_t)(m0 + row) * DD + sch * 8;
        bptr[s] = Bt + (size_t)(n0 + row) * DD + sch * 8;
        ldsoff[s] = si * 512;
    }

    f32x4 acc[4][4];
#pragma unroll
    for (int i = 0; i < 4; ++i)
#pragma unroll
        for (int j = 0; j < 4; ++j) acc[i][j] = (f32x4){0.f, 0.f, 0.f, 0.f};

    const int rA = lane & 15;
    const int kgrp = lane >> 4;

    PIPE_RUN()

#pragma unroll
    for (int fi = 0; fi < 4; ++fi) {
#pragma unroll
        for (int r = 0; r < 4; ++r) {
            const int m = m0 + wr + fi * 16 + (lane >> 4) * 4 + r;
#pragma unroll
            for (int fj = 0; fj < 4; ++fj) {
                const int h = n0 + wc + fj * 16 + (lane & 15);
                float v = acc[fi][fj][r];
                if (bias) v += bias[h];
                if (expout) v = __builtin_amdgcn_exp2f(v);
                C[(size_t)m * ldc + h] = v;
            }
        }
    }
}

// ------- fused LSTM step, latency-optimized: full operand panels resident
// in LDS, ALL loads issued upfront, ONE barrier, 16 barrier-free K-steps.
__global__ __launch_bounds__(256)
void k_lstm2(const __hip_bfloat16* __restrict__ hin,   // [128][512]
             const __hip_bfloat16* __restrict__ whh,   // [2048][512]
             const float* __restrict__ gx,             // [1152][2048]
             float* __restrict__ cbuf,                 // [128][512]
             __hip_bfloat16* __restrict__ hout,        // [128][512]
             __hip_bfloat16* __restrict__ query,       // [1152][512] bf16
             int t)
{
    __shared__ __align__(16) __hip_bfloat16 As[64 * 512];   // 64 KB
    __shared__ __align__(16) __hip_bfloat16 Bs[32 * 512];   // 32 KB
    __shared__ float Gs[64][36];
    const int tid  = threadIdx.x;
    const int lane = tid & 63;
    const int wid  = tid >> 6;
    const int m0  = blockIdx.x * 64;
    const int hc0 = blockIdx.y * 8;
    const int wy = wid >> 1, wx = wid & 1;

#pragma unroll
    for (int i = 0; i < 16; ++i) {
        const int o = (i * 256 + tid) * 16;
        const int c = o >> 13;
        const int oc = o & 8191;
        const int row = oc >> 7;
        const int ch = (oc >> 4) & 7;
        const int sch = ch ^ (row & 7);
        gl_lds16(hin + (size_t)(m0 + row) * HH + c * 64 + sch * 8, As + (o >> 1));
    }
#pragma unroll
    for (int i = 0; i < 8; ++i) {
        const int o = (i * 256 + tid) * 16;
        const int c = o >> 12;
        const int oc = o & 4095;
        const int row = oc >> 7;
        const int ch = (oc >> 4) & 7;
        const int sch = ch ^ (row & 7);
        const int brow = (row >> 3) * 512 + hc0 + (row & 7);
        gl_lds16(whh + (size_t)brow * HH + c * 64 + sch * 8, Bs + (o >> 1));
    }
    __syncthreads();

    f32x4 acc[2];
    acc[0] = (f32x4){0.f, 0.f, 0.f, 0.f};
    acc[1] = (f32x4){0.f, 0.f, 0.f, 0.f};
    const int rr = lane & 15;
    const int kg = lane >> 4;

#pragma unroll
    for (int ks = 0; ks < 16; ++ks) {
        const int c = ks >> 1, sub = ks & 1;
        const __hip_bfloat16* Ab = As + c * 4096;
        const __hip_bfloat16* Bb = Bs + c * 2048;
        const int rb = wx * 16 + rr;
        const bf16x8 bfr = *(const bf16x8*)(Bb + rb * 64 + (((sub * 4 + kg) ^ (rb & 7)) * 8));
#pragma unroll
        for (int fi = 0; fi < 2; ++fi) {
            const int ra = wy * 32 + fi * 16 + rr;
            const bf16x8 af = *(const bf16x8*)(Ab + ra * 64 + (((sub * 4 + kg) ^ (ra & 7)) * 8));
            acc[fi] = __builtin_amdgcn_mfma_f32_16x16x32_bf16(af, bfr, acc[fi], 0, 0, 0);
        }
    }

#pragma unroll
    for (int fi = 0; fi < 2; ++fi)
#pragma unroll
        for (int r = 0; r < 4; ++r)
            Gs[wy * 32 + fi * 16 + (lane >> 4) * 4 + r][wx * 16 + (lane & 15)] = acc[fi][r];
    __syncthreads();

    const int j  = tid & 7;
    const int mg = tid >> 3;
#pragma unroll
    for (int mi = 0; mi < 2; ++mi) {
        const int m = mg * 2 + mi;
        const float* gxr = gx + ((size_t)(m0 + m) * TP1 + t) * G4 + hc0 + j;
        float iv = sigm(Gs[m][j]      + gxr[0]);
        float fv = sigm(Gs[m][8 + j]  + gxr[512]);
        float gv = fast_tanh(Gs[m][16 + j] + gxr[1024]);
        float ov = sigm(Gs[m][24 + j] + gxr[1536]);
        const int ci = (m0 + m) * HH + hc0 + j;
        float cv = fv * cbuf[ci] + iv * gv;
        float hv = ov * fast_tanh(cv);
        cbuf[ci] = cv;
        hout[ci] = __float2bfloat16(hv);
        query[((size_t)(m0 + m) * TP1 + t) * HH + hc0 + j] = __float2bfloat16(hv);
    }
}

// ---- score[b,q,n] = Vsum - sum_h 2*v_h / (E_f[n,h]*E_q[q,h] + 1)
__global__ __launch_bounds__(256)
void k_score(const __hip_bfloat16* __restrict__ E2, int efoff,
             const float* __restrict__ Eq,
             const float* __restrict__ v, const int* __restrict__ msz,
             float* __restrict__ score, int masked)
{
    const int wid  = threadIdx.x >> 6;
    const int lane = threadIdx.x & 63;
    const int n = blockIdx.x * 4 + wid;
    const int b = blockIdx.y;
    if (n >= NP1) return;
    float* sp = score + (size_t)b * TP1 * NP1 + n;
    if (masked && n > msz[b]) {
        if (lane == 0)
#pragma unroll
            for (int q = 0; q < TP1; ++q) sp[q * NP1] = NEGF;
        return;
    }
    const u16x8 fu = *(const u16x8*)((const unsigned short*)E2
                                     + ((size_t)b * NP1 + n) * 1024 + efoff + lane * 8);
    float ef[8];
#pragma unroll
    for (int i = 0; i < 8; ++i) ef[i] = bf2f(fu[i]);
    const float4* v4 = (const float4*)v;
    const float4 va = v4[lane * 2], vb = v4[lane * 2 + 1];
    const float vs8 = va.x + va.y + va.z + va.w + vb.x + vb.y + vb.z + vb.w;
    float v2[8] = {2.f*va.x, 2.f*va.y, 2.f*va.z, 2.f*va.w,
                   2.f*vb.x, 2.f*vb.y, 2.f*vb.z, 2.f*vb.w};
    for (int q = 0; q < TP1; ++q) {
        const float4* q4 = (const float4*)(Eq + ((size_t)b * TP1 + q) * HH);
        const float4 qa = q4[lane * 2], qb = q4[lane * 2 + 1];
        float eq[8] = {qa.x, qa.y, qa.z, qa.w, qb.x, qb.y, qb.z, qb.w};
        float acc = 0.f;
#pragma unroll
        for (int i = 0; i < 8; ++i)
            acc = fmaf(v2[i], __builtin_amdgcn_rcpf(fmaf(ef[i], eq[i], 1.0f)), acc);
        float s = vs8 - acc;
#pragma unroll
        for (int off = 32; off; off >>= 1) s += __shfl_down(s, off);
        if (lane == 0) sp[q * NP1] = s;
    }
}

// ------- softmax over n<=msz for all 9 q, then query2 = p @ featS
__global__ __launch_bounds__(256)
void k_softpv(const float* __restrict__ score, const __hip_bfloat16* __restrict__ E2,
              const int* __restrict__ msz, __hip_bfloat16* __restrict__ outq)
{
    const int b   = blockIdx.x;
    const int ch  = blockIdx.y;
    const int tid = threadIdx.x;
    const int lane = tid & 63, wid = tid >> 6;
    __shared__ float p[TP1][NP1 + 3];
    __shared__ float comb[TP1][256];
    const int nlim = msz[b] + 1;

    const float* sb = score + (size_t)b * TP1 * NP1;
    for (int q = wid; q < TP1; q += 4) {
        const float* srow = sb + q * NP1;
        float mx = NEGF;
        for (int n = lane; n < nlim; n += 64) mx = fmaxf(mx, srow[n]);
#pragma unroll
        for (int off = 32; off; off >>= 1) mx = fmaxf(mx, __shfl_xor(mx, off));
        float sum = 0.f;
        for (int n = lane; n < nlim; n += 64) {
            float e = __builtin_amdgcn_exp2f((srow[n] - mx) * L2E);
            p[q][n] = e;
            sum += e;
        }
#pragma unroll
        for (int off = 32; off; off >>= 1) sum += __shfl_xor(sum, off);
        float inv = 1.f / sum;
        for (int n = lane; n < nlim; n += 64) p[q][n] *= inv;
    }
    __syncthreads();

    const int ng = tid >> 7;
    const int tc = tid & 127;
    const int col = ch * 256 + tc * 2;
    const unsigned short* fb = (const unsigned short*)E2 + (size_t)b * NP1 * 1024 + col;
    float a0[TP1] = {}, a1[TP1] = {};
    for (int n = ng; n < nlim; n += 2) {
        const unsigned int u = *(const unsigned int*)(fb + (size_t)n * 1024);
        const float f0 = __builtin_amdgcn_logf(bf2f((unsigned short)(u & 0xffffu)));
        const float f1 = __builtin_amdgcn_logf(bf2f((unsigned short)(u >> 16)));
#pragma unroll
        for (int q = 0; q < TP1; ++q) {
            const float pq = p[q][n];
            a0[q] += pq * f0;
            a1[q] += pq * f1;
        }
    }
    if (ng == 1) {
#pragma unroll
        for (int q = 0; q < TP1; ++q) {
            comb[q][tc * 2]     = a0[q];
            comb[q][tc * 2 + 1] = a1[q];
        }
    }
    __syncthreads();
    if (ng == 0) {
        __hip_bfloat16* oq = outq + (size_t)(b * TP1) * HH + col;
#pragma unroll
        for (int q = 0; q < TP1; ++q) {
            oq[(size_t)q * HH]     = __float2bfloat16(a0[q] + comb[q][tc * 2]);
            oq[(size_t)q * HH + 1] = __float2bfloat16(a1[q] + comb[q][tc * 2 + 1]);
        }
    }
}

// ===========================================================================
extern "C" void kernel_launch(void* const* d_in, const int* in_sizes, int n_in,
                              void* d_out, int out_size, void* d_ws, size_t ws_size,
                              hipStream_t stream)
{
    const float* attn_mem  = (const float*)d_in[0];
    const float* lstm_in   = (const float*)d_in[1];
    const int*   mem_sizes = (const int*)d_in[2];
    const float* init_h    = (const float*)d_in[3];
    const float* init_c    = (const float*)d_in[4];
    const float* init_i    = (const float*)d_in[5];
    const float* stop      = (const float*)d_in[6];
    const float* w_ih      = (const float*)d_in[7];
    const float* w_hh      = (const float*)d_in[8];
    const float* b_ih      = (const float*)d_in[9];
    const float* b_hh      = (const float*)d_in[10];
    const float* attn_wm   = (const float*)d_in[11];
    const float* attn_wq   = (const float*)d_in[12];
    const float* attn_v    = (const float*)d_in[13];
    const float* hop_wm    = (const float*)d_in[14];
    const float* hop_wq    = (const float*)d_in[15];
    const float* hop_v     = (const float*)d_in[16];
    float* out = (float*)d_out;

    char* w = (char*)d_ws;
    __hip_bfloat16* Abf    = (__hip_bfloat16*)w;  w += (size_t)MTOT * DD * 2;    // 33.7 MB
    __hip_bfloat16* E2     = (__hip_bfloat16*)w;  w += (size_t)MTOT * 1024 * 2;  // 67.4 MB
    __hip_bfloat16* Xbf    = (__hip_bfloat16*)w;  w += (size_t)BB * TP1 * DD * 2;
    __hip_bfloat16* Wt2    = (__hip_bfloat16*)w;  w += (size_t)1024 * DD * 2;
    __hip_bfloat16* WqtH   = (__hip_bfloat16*)w;  w += (size_t)HH * HH * 2;
    __hip_bfloat16* WqtA   = (__hip_bfloat16*)w;  w += (size_t)HH * HH * 2;
    __hip_bfloat16* wih_bf = (__hip_bfloat16*)w;  w += (size_t)G4 * DD * 2;
    __hip_bfloat16* whh_bf = (__hip_bfloat16*)w;  w += (size_t)G4 * HH * 2;
    __hip_bfloat16* h_a    = (__hip_bfloat16*)w;  w += (size_t)BB * HH * 2;
    __hip_bfloat16* h_b    = (__hip_bfloat16*)w;  w += (size_t)BB * HH * 2;
    __hip_bfloat16* query  = (__hip_bfloat16*)w;  w += (size_t)BB * TP1 * HH * 2;
    __hip_bfloat16* query2 = (__hip_bfloat16*)w;  w += (size_t)BB * TP1 * HH * 2;
    float* gatesx  = (float*)w;  w += (size_t)BB * TP1 * G4 * 4;                 // 9.4 MB
    float* eq      = (float*)w;  w += (size_t)BB * TP1 * HH * 4;
    float* score   = (float*)w;  w += (size_t)BB * TP1 * NP1 * 4;
    float* cbuf    = (float*)w;  w += (size_t)BB * HH * 4;
    float* stopm2  = (float*)w;  w += 1024 * 4;
    float* bsum    = (float*)w;  w += G4 * 4;

    // all conversions + scaled weight transposes + stop projections, one kernel
    k_prep<<<dim3(22213), dim3(256), 0, stream>>>(
        hop_wm, attn_wm, hop_wq, attn_wq, w_ih, w_hh, b_ih, b_hh,
        stop, lstm_in, init_i, init_h, init_c, attn_mem,
        Wt2, WqtH, WqtA, wih_bf, whh_bf, bsum, stopm2, Xbf, h_a, cbuf, Abf);

    // merged feat GEMM -> E2 (hop cols 0-511 | attn cols 512-1023)
    k_feat2<<<dim3(2056), dim3(256), 0, stream>>>(Abf, Wt2, stopm2, mem_sizes, E2);

    // LSTM: MFMA input-gates + 9 latency-optimized fused steps
    k_gemm_bt<<<dim3(9, 16), dim3(256), 0, stream>>>(Xbf, wih_bf, bsum, gatesx, G4, 0);
    for (int t = 0; t < TP1; ++t) {
        const __hip_bfloat16* hin = (t & 1) ? h_b : h_a;
        __hip_bfloat16*      hout = (t & 1) ? h_a : h_b;
        k_lstm2<<<dim3(2, 64), dim3(256), 0, stream>>>(hin, whh_bf, gatesx, cbuf, hout, query, t);
    }

    // hop attention (masked): E_q, score, softmax+PV -> query2
    k_gemm_bt<<<dim3(9, 4), dim3(256), 0, stream>>>(query, WqtH, nullptr, eq, HH, 1);
    k_score<<<dim3(65, 128), dim3(256), 0, stream>>>(E2, 0, eq, hop_v, mem_sizes, score, 1);
    k_softpv<<<dim3(128, 2), dim3(256), 0, stream>>>(score, E2, mem_sizes, query2);

    // final pointer scores (unmasked) -> d_out
    k_gemm_bt<<<dim3(9, 4), dim3(256), 0, stream>>>(query2, WqtA, nullptr, eq, HH, 1);
    k_score<<<dim3(65, 128), dim3(256), 0, stream>>>(E2, 512, eq, attn_v, mem_sizes, out, 0);
}